// Round 1
// baseline (2351.149 us; speedup 1.0000x reference)
//
#include <hip/hip_runtime.h>
#include <stdint.h>
#include <stddef.h>

// ---------------- problem constants ----------------
constexpr int kH = 496, kW = 432;
constexpr int HWSZ = kH * kW;          // 214272
constexpr int NANCH = HWSZ * 6;        // 1285632 anchors
constexpr int NPRE = 4096;             // nms_pre
constexpr int MAXNUM = 500;
constexpr int CAND_CAP = 8192;
constexpr float SCORE_THR_F = 0.1f;
constexpr float PIF  = 3.14159265358979323846f;  // rounds to f32 pi
constexpr float HPIF = 1.57079632679489661923f;  // rounds to f32 pi/2

// ---------------- workspace layout (bytes) ----------------
constexpr size_t HIST_OFF  = 0;                                   // u32[65536]
constexpr size_t MISC_OFF  = 262144;                              // u32[64]: [0]=cand_cnt [1]=binB [2]=count_above
constexpr size_t ZERO_BYTES= 262144 + 256;
constexpr size_t MS_OFF    = 262400;                              // f32[NANCH]
constexpr size_t CAND_OFF  = MS_OFF + sizeof(float) * (size_t)NANCH;   // u64[8192]
constexpr size_t SEL_OFF   = CAND_OFF + 8ull * CAND_CAP;          // u32[NPRE]
constexpr size_t SC3_OFF   = SEL_OFF + 4ull * NPRE;               // f32[NPRE*3]
constexpr size_t DSC_OFF   = SC3_OFF + 4ull * NPRE * 3;           // u32[NPRE]
constexpr size_t BB7_OFF   = DSC_OFF + 4ull * NPRE;               // f32[NPRE*7]
constexpr size_t BOX4_OFF  = BB7_OFF + 4ull * NPRE * 7;           // f32[NPRE*4]
constexpr size_t AREA_OFF  = BOX4_OFF + 4ull * NPRE * 4;          // f32[NPRE]
constexpr size_t ORD_OFF   = AREA_OFF + 4ull * NPRE;              // u32[3*NPRE]
constexpr size_t VW_OFF    = ORD_OFF + 4ull * 3 * NPRE;           // u64[3*64]
constexpr size_t PMASK_OFF = VW_OFF + 8ull * 3 * 64;              // u64[3*NPRE*64]  (6 MB)
constexpr size_t KEEPW_OFF = PMASK_OFF + 8ull * 3 * NPRE * 64;    // u64[3*64]
constexpr size_t OUTK_OFF  = KEEPW_OFF + 8ull * 3 * 64;           // u64[3*MAXNUM]
// total ~12.1 MB of d_ws

// ---------------- helpers ----------------
__device__ __forceinline__ float sigmoidf_(float x) { return 1.0f / (1.0f + expf(-x)); }

__device__ __forceinline__ uint64_t readlane64(uint64_t v, int lane) {
  uint32_t lo = (uint32_t)__builtin_amdgcn_readlane((int)(uint32_t)(v & 0xffffffffull), lane);
  uint32_t hi = (uint32_t)__builtin_amdgcn_readlane((int)(uint32_t)(v >> 32), lane);
  return (((uint64_t)hi) << 32) | (uint64_t)lo;
}

// ascending bitonic sort of NTOT u64 keys in LDS, NTHR threads
template <int NTOT, int NTHR>
__device__ void bitonic_sort_lds(uint64_t* s) {
  const int tid = threadIdx.x;
  for (int k = 2; k <= NTOT; k <<= 1) {
    for (int j = k >> 1; j > 0; j >>= 1) {
      __syncthreads();
      for (int idx = tid; idx < NTOT; idx += NTHR) {
        int ixj = idx ^ j;
        if (ixj > idx) {
          uint64_t a = s[idx], b = s[ixj];
          bool up = ((idx & k) == 0);
          if ((a > b) == up) { s[idx] = b; s[ixj] = a; }
        }
      }
    }
  }
  __syncthreads();
}

// ---------------- kernels ----------------

// 1) per-anchor max-of-3-sigmoids + bit-pattern histogram (bins = bits>>15)
__global__ void k_score(const float* __restrict__ cls, float* __restrict__ ms,
                        uint32_t* __restrict__ hist) {
  int p = blockIdx.x * 256 + threadIdx.x;
  if (p >= HWSZ) return;
#pragma unroll
  for (int k = 0; k < 6; ++k) {
    float s0 = sigmoidf_(cls[(k * 3 + 0) * HWSZ + p]);
    float s1 = sigmoidf_(cls[(k * 3 + 1) * HWSZ + p]);
    float s2 = sigmoidf_(cls[(k * 3 + 2) * HWSZ + p]);
    float m = fmaxf(s0, fmaxf(s1, s2));
    ms[p * 6 + k] = m;
    atomicAdd(&hist[__float_as_uint(m) >> 15], 1u);
  }
}

// 2) find threshold bin B such that count(bin > B) < 4096 <= count(bin >= B)
__global__ void k_scanhist(const uint32_t* __restrict__ hist, uint32_t* __restrict__ misc) {
  __shared__ uint32_t part[256];
  __shared__ uint32_t suf[257];
  int t = threadIdx.x;
  int base = t * 256;
  uint32_t s = 0;
  for (int b = 0; b < 256; ++b) s += hist[base + b];
  part[t] = s;
  __syncthreads();
  if (t == 0) {
    uint32_t acc = 0;
    suf[256] = 0;
    for (int q = 255; q >= 0; --q) { suf[q] = acc + part[q]; acc = suf[q]; }
  }
  __syncthreads();
  uint32_t above = suf[t + 1];  // count in chunks with higher bins
  if (above < (uint32_t)NPRE && above + part[t] >= (uint32_t)NPRE) {
    uint32_t acc = above;
    for (int b = base + 255; b >= base; --b) {
      uint32_t h = hist[b];
      if (acc + h >= (uint32_t)NPRE) { misc[1] = (uint32_t)b; misc[2] = acc; break; }
      acc += h;
    }
  }
}

// 3) compact all anchors with bin >= B as sort keys (~score desc, idx asc)
__global__ void k_compact(const float* __restrict__ ms, uint32_t* __restrict__ misc,
                          uint64_t* __restrict__ cand) {
  int a = blockIdx.x * 256 + threadIdx.x;
  if (a >= NANCH) return;
  uint32_t bits = __float_as_uint(ms[a]);
  uint32_t B = misc[1];
  if ((bits >> 15) >= B) {
    uint32_t slot = atomicAdd(&misc[0], 1u);
    if (slot < (uint32_t)CAND_CAP)
      cand[slot] = (((uint64_t)(~bits)) << 32) | (uint32_t)a;
  }
}

// 4) sort candidates, take top-4096 => exact lax.top_k set & order
__global__ void k_sortcand(const uint64_t* __restrict__ cand, const uint32_t* __restrict__ misc,
                           uint32_t* __restrict__ sel) {
  __shared__ uint64_t sh[CAND_CAP];  // 64 KB
  int t = threadIdx.x;
  uint32_t cnt = misc[0];
  if (cnt > (uint32_t)CAND_CAP) cnt = CAND_CAP;
  for (int i = t; i < CAND_CAP; i += 1024) sh[i] = (i < (int)cnt) ? cand[i] : ~0ull;
  bitonic_sort_lds<CAND_CAP, 1024>(sh);
  for (int i = t; i < NPRE; i += 1024) sel[i] = (uint32_t)sh[i];
}

// 5) gather per-anchor data + decode boxes
__global__ void k_gather(const uint32_t* __restrict__ sel, const float* __restrict__ cls,
                         const float* __restrict__ bbp, const float* __restrict__ dirp,
                         const float* __restrict__ priors, float* __restrict__ sc3,
                         uint32_t* __restrict__ dsc, float* __restrict__ bb7,
                         float* __restrict__ box4, float* __restrict__ areaA) {
  int i = blockIdx.x * 256 + threadIdx.x;
  if (i >= NPRE) return;
  uint32_t a = sel[i];
  uint32_t p = a / 6u;
  uint32_t k = a - p * 6u;
#pragma unroll
  for (int c = 0; c < 3; ++c) sc3[i * 3 + c] = sigmoidf_(cls[(k * 3 + c) * HWSZ + p]);
  float d0 = dirp[(k * 2 + 0) * HWSZ + p];
  float d1 = dirp[(k * 2 + 1) * HWSZ + p];
  dsc[i] = (d1 > d0) ? 1u : 0u;  // jnp.argmax first-max semantics
  float dt[7], pr[7];
#pragma unroll
  for (int q = 0; q < 7; ++q) dt[q] = bbp[(k * 7 + q) * HWSZ + p];
#pragma unroll
  for (int q = 0; q < 7; ++q) pr[q] = priors[(size_t)a * 7 + q];
  // decode (mirrors reference op-for-op)
  float za = pr[2] + pr[5] * 0.5f;
  float diag = sqrtf(pr[4] * pr[4] + pr[3] * pr[3]);
  float xg = dt[0] * diag + pr[0];
  float yg = dt[1] * diag + pr[1];
  float zg = dt[2] * pr[5] + za;
  float wg = expf(dt[3]) * pr[3];
  float lg = expf(dt[4]) * pr[4];
  float hg = expf(dt[5]) * pr[5];
  float rg = dt[6] + pr[6];
  zg = zg - hg * 0.5f;
  bb7[i * 7 + 0] = xg; bb7[i * 7 + 1] = yg; bb7[i * 7 + 2] = zg;
  bb7[i * 7 + 3] = wg; bb7[i * 7 + 4] = lg; bb7[i * 7 + 5] = hg; bb7[i * 7 + 6] = rg;
  float x1 = xg - wg * 0.5f, y1 = yg - lg * 0.5f;
  float x2 = xg + wg * 0.5f, y2 = yg + lg * 0.5f;
  box4[i * 4 + 0] = x1; box4[i * 4 + 1] = y1; box4[i * 4 + 2] = x2; box4[i * 4 + 3] = y2;
  areaA[i] = (x2 - x1 + 1.0f) * (y2 - y1 + 1.0f);
}

// 6) per-class sort by (score desc, pos asc); also build valid bitset in sorted space
__global__ void k_sortclass(const float* __restrict__ sc3, uint32_t* __restrict__ ord,
                            uint64_t* __restrict__ vwords) {
  __shared__ uint64_t sh[NPRE];  // 32 KB
  int c = blockIdx.x, t = threadIdx.x;
  for (int i = t; i < NPRE; i += 1024) {
    uint32_t sb = __float_as_uint(sc3[i * 3 + c]);
    sh[i] = (((uint64_t)(~sb)) << 32) | (uint32_t)i;
  }
  bitonic_sort_lds<NPRE, 1024>(sh);
  for (int i = t; i < NPRE; i += 1024) ord[c * NPRE + i] = (uint32_t)sh[i];
  if (t < 64) {
    uint64_t w = 0;
    for (int b = 0; b < 64; ++b) {
      uint32_t pos = (uint32_t)sh[t * 64 + b];
      w |= ((uint64_t)(sc3[pos * 3 + c] > SCORE_THR_F)) << b;
    }
    vwords[c * 64 + t] = w;
  }
}

// 7) suppression bitmask in per-class sorted order: bit j of pmask[c][i][jt] = iou>thr
__global__ void k_mask(const uint32_t* __restrict__ ord, const float* __restrict__ box4,
                       const float* __restrict__ areaA, uint64_t* __restrict__ pmask) {
  int c = blockIdx.z, it = blockIdx.y, jt = blockIdx.x, t = threadIdx.x;
  __shared__ float jx1[64], jy1[64], jx2[64], jy2[64], jar[64];
  int j = ord[c * NPRE + jt * 64 + t];
  jx1[t] = box4[j * 4 + 0]; jy1[t] = box4[j * 4 + 1];
  jx2[t] = box4[j * 4 + 2]; jy2[t] = box4[j * 4 + 3];
  jar[t] = areaA[j];
  __syncthreads();
  int I = it * 64 + t;
  int i = ord[c * NPRE + I];
  float x1 = box4[i * 4 + 0], y1 = box4[i * 4 + 1];
  float x2 = box4[i * 4 + 2], y2 = box4[i * 4 + 3];
  float ar = areaA[i];
  uint64_t bits = 0;
  for (int b = 0; b < 64; ++b) {
    float xx1 = fmaxf(x1, jx1[b]), yy1 = fmaxf(y1, jy1[b]);
    float xx2 = fminf(x2, jx2[b]), yy2 = fminf(y2, jy2[b]);
    float iw = fmaxf(0.0f, xx2 - xx1 + 1.0f);
    float ih = fmaxf(0.0f, yy2 - yy1 + 1.0f);
    float inter = iw * ih;
    float iou = inter / (ar + jar[b] - inter);
    bits |= ((uint64_t)(iou > 0.5f)) << b;
  }
  pmask[((size_t)(c * NPRE + I)) * 64 + (size_t)jt] = bits;
}

// 8) serial greedy NMS cascade: one wave per class; lane t owns bitset word t.
//    avail = valid & ~suppressed; decision per row is one uniform readlane.
__global__ void k_nms(const uint64_t* __restrict__ pmask, const uint64_t* __restrict__ vwords,
                      uint64_t* __restrict__ keepw) {
  int c = blockIdx.x;
  int t = threadIdx.x;  // 0..63
  const uint64_t* pm = pmask + (size_t)c * NPRE * 64;
  uint64_t avail = vwords[c * 64 + t];
  uint64_t keepbits = 0;
  uint64_t buf[8];
#pragma unroll
  for (int u = 0; u < 8; ++u) buf[u] = pm[(size_t)u * 64 + t];
  for (int ib = 0; ib < NPRE; ib += 8) {
#pragma unroll
    for (int u = 0; u < 8; ++u) {
      int i = ib + u;
      uint64_t cur = buf[u];
      int nx = i + 8;
      if (nx < NPRE) buf[u] = pm[(size_t)nx * 64 + t];  // prefetch: off the serial chain
      int Wd = i >> 6, bi = i & 63;
      uint64_t av = readlane64(avail, Wd);  // uniform broadcast
      bool kp = ((av >> bi) & 1ull) != 0ull;
      if (kp) avail &= ~cur;  // kp is wave-uniform
      if (Wd == t) keepbits |= ((uint64_t)kp) << bi;
    }
  }
  keepw[c * 64 + t] = keepbits;
}

// 9) stable-compact first <=500 kept per class (sorted order == score-descending)
__global__ void k_collect(const uint64_t* __restrict__ keepw, const uint32_t* __restrict__ ord,
                          const float* __restrict__ sc3, uint64_t* __restrict__ outk) {
  int c = blockIdx.x, t = threadIdx.x;
  __shared__ uint32_t ps[1024];
  uint32_t bits4 = 0;
#pragma unroll
  for (int q = 0; q < 4; ++q) {
    int i = t * 4 + q;
    uint32_t b = (uint32_t)((keepw[c * 64 + (i >> 6)] >> (i & 63)) & 1ull);
    bits4 |= b << q;
  }
  uint32_t cnt = __popc(bits4);
  ps[t] = cnt;
  __syncthreads();
  for (int off = 1; off < 1024; off <<= 1) {
    uint32_t v = (t >= off) ? ps[t - off] : 0;
    __syncthreads();
    ps[t] += v;
    __syncthreads();
  }
  uint32_t excl = ps[t] - cnt;
  if (t < MAXNUM) outk[c * MAXNUM + t] = ~0ull;  // pad
  __syncthreads();
  uint32_t r = excl;
#pragma unroll
  for (int q = 0; q < 4; ++q) {
    if ((bits4 >> q) & 1u) {
      int i = t * 4 + q;
      if (r < (uint32_t)MAXNUM) {
        uint32_t pos = ord[c * NPRE + i];
        uint32_t sb = __float_as_uint(sc3[pos * 3 + c]);
        outk[c * MAXNUM + r] = (((uint64_t)(~sb)) << 32) | (uint32_t)(c * NPRE + pos);
      }
      ++r;
    }
  }
}

// 10) merge-sort the <=1500 union, emit top-500 boxes/scores/labels
__global__ void k_final(const uint64_t* __restrict__ outk, const float* __restrict__ bb7,
                        const uint32_t* __restrict__ dsc, float* __restrict__ out) {
  __shared__ uint64_t sh[2048];  // 16 KB
  int t = threadIdx.x;
  for (int i = t; i < 2048; i += 1024) sh[i] = (i < 3 * MAXNUM) ? outk[i] : ~0ull;
  bitonic_sort_lds<2048, 1024>(sh);
  if (t < MAXNUM) {
    uint64_t key = sh[t];
    if (key != ~0ull) {
      uint32_t flat = (uint32_t)key;
      float score = __uint_as_float(~((uint32_t)(key >> 32)));
      int cc = (int)(flat >> 12);
      int pos = (int)(flat & 4095u);
      const float* b = bb7 + (size_t)pos * 7;
      float r = b[6];
      float dir_rot = r + HPIF - floorf(r + 0.5f) * PIF;
      float rr = dir_rot - HPIF + PIF * (float)dsc[pos];
#pragma unroll
      for (int q = 0; q < 6; ++q) out[t * 7 + q] = b[q];
      out[t * 7 + 6] = rr;
      out[7 * MAXNUM + t] = score;
      out[8 * MAXNUM + t] = (float)cc;
    } else {
#pragma unroll
      for (int q = 0; q < 7; ++q) out[t * 7 + q] = 0.0f;
      out[7 * MAXNUM + t] = 0.0f;
      out[8 * MAXNUM + t] = -1.0f;
    }
  }
}

// ---------------- launcher ----------------
extern "C" void kernel_launch(void* const* d_in, const int* in_sizes, int n_in,
                              void* d_out, int out_size, void* d_ws, size_t ws_size,
                              hipStream_t stream) {
  (void)in_sizes; (void)n_in; (void)out_size; (void)ws_size;
  const float* cls    = (const float*)d_in[0];
  const float* bbp    = (const float*)d_in[1];
  const float* dirp   = (const float*)d_in[2];
  const float* priors = (const float*)d_in[3];
  char* ws = (char*)d_ws;

  uint32_t* hist   = (uint32_t*)(ws + HIST_OFF);
  uint32_t* misc   = (uint32_t*)(ws + MISC_OFF);
  float*    ms     = (float*)(ws + MS_OFF);
  uint64_t* cand   = (uint64_t*)(ws + CAND_OFF);
  uint32_t* sel    = (uint32_t*)(ws + SEL_OFF);
  float*    sc3    = (float*)(ws + SC3_OFF);
  uint32_t* dsc    = (uint32_t*)(ws + DSC_OFF);
  float*    bb7    = (float*)(ws + BB7_OFF);
  float*    box4   = (float*)(ws + BOX4_OFF);
  float*    areaA  = (float*)(ws + AREA_OFF);
  uint32_t* ord    = (uint32_t*)(ws + ORD_OFF);
  uint64_t* vwords = (uint64_t*)(ws + VW_OFF);
  uint64_t* pmask  = (uint64_t*)(ws + PMASK_OFF);
  uint64_t* keepw  = (uint64_t*)(ws + KEEPW_OFF);
  uint64_t* outk   = (uint64_t*)(ws + OUTK_OFF);

  hipMemsetAsync(ws, 0, ZERO_BYTES, stream);
  k_score<<<HWSZ / 256, 256, 0, stream>>>(cls, ms, hist);
  k_scanhist<<<1, 256, 0, stream>>>(hist, misc);
  k_compact<<<NANCH / 256, 256, 0, stream>>>(ms, misc, cand);
  k_sortcand<<<1, 1024, 0, stream>>>(cand, misc, sel);
  k_gather<<<NPRE / 256, 256, 0, stream>>>(sel, cls, bbp, dirp, priors, sc3, dsc, bb7, box4, areaA);
  k_sortclass<<<3, 1024, 0, stream>>>(sc3, ord, vwords);
  k_mask<<<dim3(64, 64, 3), 64, 0, stream>>>(ord, box4, areaA, pmask);
  k_nms<<<3, 64, 0, stream>>>(pmask, vwords, keepw);
  k_collect<<<3, 1024, 0, stream>>>(keepw, ord, sc3, outk);
  k_final<<<1, 1024, 0, stream>>>(outk, bb7, dsc, (float*)d_out);
}

// Round 2
// 1241.224 us; speedup vs baseline: 1.8942x; 1.8942x over previous
//
#include <hip/hip_runtime.h>
#include <stdint.h>
#include <stddef.h>

// ---------------- problem constants ----------------
constexpr int kH = 496, kW = 432;
constexpr int HWSZ = kH * kW;          // 214272
constexpr int NANCH = HWSZ * 6;        // 1285632 anchors
constexpr int NPRE = 4096;             // nms_pre
constexpr int MAXNUM = 500;
constexpr int CAND_CAP = 8192;
constexpr float SCORE_THR_F = 0.1f;
constexpr float PIF  = 3.14159265358979323846f;  // rounds to f32 pi
constexpr float HPIF = 1.57079632679489661923f;  // rounds to f32 pi/2

// ---------------- workspace layout (bytes) ----------------
constexpr size_t HIST_OFF  = 0;                                   // u32[65536]
constexpr size_t MISC_OFF  = 262144;                              // u32[64]: [0]=cand_cnt [1]=binB [2]=count_above
constexpr size_t ZERO_BYTES= 262144 + 256;
constexpr size_t MS_OFF    = 262400;                              // f32[NANCH]
constexpr size_t CAND_OFF  = MS_OFF + sizeof(float) * (size_t)NANCH;   // u64[8192]
constexpr size_t SEL_OFF   = CAND_OFF + 8ull * CAND_CAP;          // u32[NPRE]
constexpr size_t SC3_OFF   = SEL_OFF + 4ull * NPRE;               // f32[NPRE*3]
constexpr size_t DSC_OFF   = SC3_OFF + 4ull * NPRE * 3;           // u32[NPRE]
constexpr size_t BB7_OFF   = DSC_OFF + 4ull * NPRE;               // f32[NPRE*7]
constexpr size_t BOX4_OFF  = BB7_OFF + 4ull * NPRE * 7;           // f32[NPRE*4]
constexpr size_t AREA_OFF  = BOX4_OFF + 4ull * NPRE * 4;          // f32[NPRE]
constexpr size_t ORD_OFF   = AREA_OFF + 4ull * NPRE;              // u32[3*NPRE]
constexpr size_t VW_OFF    = ORD_OFF + 4ull * 3 * NPRE;           // u64[3*64]
constexpr size_t PMASK_OFF = VW_OFF + 8ull * 3 * 64;              // u64[3*NPRE*64]  (6 MB)
constexpr size_t KEEPW_OFF = PMASK_OFF + 8ull * 3 * NPRE * 64;    // u64[3*64]
constexpr size_t OUTK_OFF  = KEEPW_OFF + 8ull * 3 * 64;           // u64[3*MAXNUM]
// total ~12.1 MB of d_ws

// ---------------- helpers ----------------
__device__ __forceinline__ float sigmoidf_(float x) { return 1.0f / (1.0f + expf(-x)); }

__device__ __forceinline__ uint64_t readlane64(uint64_t v, int lane) {
  uint32_t lo = (uint32_t)__builtin_amdgcn_readlane((int)(uint32_t)(v & 0xffffffffull), lane);
  uint32_t hi = (uint32_t)__builtin_amdgcn_readlane((int)(uint32_t)(v >> 32), lane);
  return (((uint64_t)hi) << 32) | (uint64_t)lo;
}

// ascending bitonic sort of NTOT u64 keys in LDS, NTHR threads
template <int NTOT, int NTHR>
__device__ void bitonic_sort_lds(uint64_t* s) {
  const int tid = threadIdx.x;
  for (int k = 2; k <= NTOT; k <<= 1) {
    for (int j = k >> 1; j > 0; j >>= 1) {
      __syncthreads();
      for (int idx = tid; idx < NTOT; idx += NTHR) {
        int ixj = idx ^ j;
        if (ixj > idx) {
          uint64_t a = s[idx], b = s[ixj];
          bool up = ((idx & k) == 0);
          if ((a > b) == up) { s[idx] = b; s[ixj] = a; }
        }
      }
    }
  }
  __syncthreads();
}

// ---------------- kernels ----------------

// 1) per-anchor max-of-3-sigmoids + bit-pattern histogram (bins = bits>>15)
__global__ void k_score(const float* __restrict__ cls, float* __restrict__ ms,
                        uint32_t* __restrict__ hist) {
  int p = blockIdx.x * 256 + threadIdx.x;
  if (p >= HWSZ) return;
#pragma unroll
  for (int k = 0; k < 6; ++k) {
    float s0 = sigmoidf_(cls[(k * 3 + 0) * HWSZ + p]);
    float s1 = sigmoidf_(cls[(k * 3 + 1) * HWSZ + p]);
    float s2 = sigmoidf_(cls[(k * 3 + 2) * HWSZ + p]);
    float m = fmaxf(s0, fmaxf(s1, s2));
    ms[p * 6 + k] = m;
    atomicAdd(&hist[__float_as_uint(m) >> 15], 1u);
  }
}

// 2) find threshold bin B such that count(bin > B) < 4096 <= count(bin >= B)
__global__ void k_scanhist(const uint32_t* __restrict__ hist, uint32_t* __restrict__ misc) {
  __shared__ uint32_t part[256];
  __shared__ uint32_t suf[257];
  int t = threadIdx.x;
  int base = t * 256;
  uint32_t s = 0;
  for (int b = 0; b < 256; ++b) s += hist[base + b];
  part[t] = s;
  __syncthreads();
  if (t == 0) {
    uint32_t acc = 0;
    suf[256] = 0;
    for (int q = 255; q >= 0; --q) { suf[q] = acc + part[q]; acc = suf[q]; }
  }
  __syncthreads();
  uint32_t above = suf[t + 1];  // count in chunks with higher bins
  if (above < (uint32_t)NPRE && above + part[t] >= (uint32_t)NPRE) {
    uint32_t acc = above;
    for (int b = base + 255; b >= base; --b) {
      uint32_t h = hist[b];
      if (acc + h >= (uint32_t)NPRE) { misc[1] = (uint32_t)b; misc[2] = acc; break; }
      acc += h;
    }
  }
}

// 3) compact all anchors with bin >= B as sort keys (~score desc, idx asc)
__global__ void k_compact(const float* __restrict__ ms, uint32_t* __restrict__ misc,
                          uint64_t* __restrict__ cand) {
  int a = blockIdx.x * 256 + threadIdx.x;
  if (a >= NANCH) return;
  uint32_t bits = __float_as_uint(ms[a]);
  uint32_t B = misc[1];
  if ((bits >> 15) >= B) {
    uint32_t slot = atomicAdd(&misc[0], 1u);
    if (slot < (uint32_t)CAND_CAP)
      cand[slot] = (((uint64_t)(~bits)) << 32) | (uint32_t)a;
  }
}

// 4) sort candidates, take top-4096 => exact lax.top_k set & order
__global__ void k_sortcand(const uint64_t* __restrict__ cand, const uint32_t* __restrict__ misc,
                           uint32_t* __restrict__ sel) {
  __shared__ uint64_t sh[CAND_CAP];  // 64 KB
  int t = threadIdx.x;
  uint32_t cnt = misc[0];
  if (cnt > (uint32_t)CAND_CAP) cnt = CAND_CAP;
  for (int i = t; i < CAND_CAP; i += 1024) sh[i] = (i < (int)cnt) ? cand[i] : ~0ull;
  bitonic_sort_lds<CAND_CAP, 1024>(sh);
  for (int i = t; i < NPRE; i += 1024) sel[i] = (uint32_t)sh[i];
}

// 5) gather per-anchor data + decode boxes
__global__ void k_gather(const uint32_t* __restrict__ sel, const float* __restrict__ cls,
                         const float* __restrict__ bbp, const float* __restrict__ dirp,
                         const float* __restrict__ priors, float* __restrict__ sc3,
                         uint32_t* __restrict__ dsc, float* __restrict__ bb7,
                         float* __restrict__ box4, float* __restrict__ areaA) {
  int i = blockIdx.x * 256 + threadIdx.x;
  if (i >= NPRE) return;
  uint32_t a = sel[i];
  uint32_t p = a / 6u;
  uint32_t k = a - p * 6u;
#pragma unroll
  for (int c = 0; c < 3; ++c) sc3[i * 3 + c] = sigmoidf_(cls[(k * 3 + c) * HWSZ + p]);
  float d0 = dirp[(k * 2 + 0) * HWSZ + p];
  float d1 = dirp[(k * 2 + 1) * HWSZ + p];
  dsc[i] = (d1 > d0) ? 1u : 0u;  // jnp.argmax first-max semantics
  float dt[7], pr[7];
#pragma unroll
  for (int q = 0; q < 7; ++q) dt[q] = bbp[(k * 7 + q) * HWSZ + p];
#pragma unroll
  for (int q = 0; q < 7; ++q) pr[q] = priors[(size_t)a * 7 + q];
  // decode (mirrors reference op-for-op)
  float za = pr[2] + pr[5] * 0.5f;
  float diag = sqrtf(pr[4] * pr[4] + pr[3] * pr[3]);
  float xg = dt[0] * diag + pr[0];
  float yg = dt[1] * diag + pr[1];
  float zg = dt[2] * pr[5] + za;
  float wg = expf(dt[3]) * pr[3];
  float lg = expf(dt[4]) * pr[4];
  float hg = expf(dt[5]) * pr[5];
  float rg = dt[6] + pr[6];
  zg = zg - hg * 0.5f;
  bb7[i * 7 + 0] = xg; bb7[i * 7 + 1] = yg; bb7[i * 7 + 2] = zg;
  bb7[i * 7 + 3] = wg; bb7[i * 7 + 4] = lg; bb7[i * 7 + 5] = hg; bb7[i * 7 + 6] = rg;
  float x1 = xg - wg * 0.5f, y1 = yg - lg * 0.5f;
  float x2 = xg + wg * 0.5f, y2 = yg + lg * 0.5f;
  box4[i * 4 + 0] = x1; box4[i * 4 + 1] = y1; box4[i * 4 + 2] = x2; box4[i * 4 + 3] = y2;
  areaA[i] = (x2 - x1 + 1.0f) * (y2 - y1 + 1.0f);
}

// 6) per-class sort by (score desc, pos asc); also build valid bitset in sorted space
__global__ void k_sortclass(const float* __restrict__ sc3, uint32_t* __restrict__ ord,
                            uint64_t* __restrict__ vwords) {
  __shared__ uint64_t sh[NPRE];  // 32 KB
  int c = blockIdx.x, t = threadIdx.x;
  for (int i = t; i < NPRE; i += 1024) {
    uint32_t sb = __float_as_uint(sc3[i * 3 + c]);
    sh[i] = (((uint64_t)(~sb)) << 32) | (uint32_t)i;
  }
  bitonic_sort_lds<NPRE, 1024>(sh);
  for (int i = t; i < NPRE; i += 1024) ord[c * NPRE + i] = (uint32_t)sh[i];
  if (t < 64) {
    uint64_t w = 0;
    for (int b = 0; b < 64; ++b) {
      uint32_t pos = (uint32_t)sh[t * 64 + b];
      w |= ((uint64_t)(sc3[pos * 3 + c] > SCORE_THR_F)) << b;
    }
    vwords[c * 64 + t] = w;
  }
}

// 7) suppression bitmask in per-class sorted order: bit j of pmask[c][i][jt] = iou>thr
__global__ void k_mask(const uint32_t* __restrict__ ord, const float* __restrict__ box4,
                       const float* __restrict__ areaA, uint64_t* __restrict__ pmask) {
  int c = blockIdx.z, it = blockIdx.y, jt = blockIdx.x, t = threadIdx.x;
  __shared__ float jx1[64], jy1[64], jx2[64], jy2[64], jar[64];
  int j = ord[c * NPRE + jt * 64 + t];
  jx1[t] = box4[j * 4 + 0]; jy1[t] = box4[j * 4 + 1];
  jx2[t] = box4[j * 4 + 2]; jy2[t] = box4[j * 4 + 3];
  jar[t] = areaA[j];
  __syncthreads();
  int I = it * 64 + t;
  int i = ord[c * NPRE + I];
  float x1 = box4[i * 4 + 0], y1 = box4[i * 4 + 1];
  float x2 = box4[i * 4 + 2], y2 = box4[i * 4 + 3];
  float ar = areaA[i];
  uint64_t bits = 0;
  for (int b = 0; b < 64; ++b) {
    float xx1 = fmaxf(x1, jx1[b]), yy1 = fmaxf(y1, jy1[b]);
    float xx2 = fminf(x2, jx2[b]), yy2 = fminf(y2, jy2[b]);
    float iw = fmaxf(0.0f, xx2 - xx1 + 1.0f);
    float ih = fmaxf(0.0f, yy2 - yy1 + 1.0f);
    float inter = iw * ih;
    float iou = inter / (ar + jar[b] - inter);
    bits |= ((uint64_t)(iou > 0.5f)) << b;
  }
  pmask[((size_t)(c * NPRE + I)) * 64 + (size_t)jt] = bits;
}

// 8) tiled serial greedy NMS cascade: one block (320 thr) per class.
//    Wave 0 runs the serial scan out of LDS; waves 1..4 double-buffer the next
//    64-row x 64-word pmask tile (32 KB) global->LDS, overlapping the scan.
//    Rows in tile T all decide from avail word T -> uniform scalar copy awT:
//    per row the chain is scalar test + (if kept) 2 readlanes + VALU and-not.
__global__ __launch_bounds__(320) void k_nms(const uint64_t* __restrict__ pmask,
                                             const uint64_t* __restrict__ vwords,
                                             uint64_t* __restrict__ keepw) {
  __shared__ uint64_t tile[2][64 * 64];  // 2 x 32 KB
  const int c = blockIdx.x;
  const int tid = threadIdx.x;
  const int wv = tid >> 6;   // 0..4
  const int ln = tid & 63;
  const uint64_t* pm = pmask + (size_t)c * NPRE * 64;

  // stage tile 0 (staging waves: 256 lanes, 4096 words -> 16 each, coalesced)
  if (wv > 0) {
    int l = tid - 64;  // 0..255
#pragma unroll
    for (int q = 0; q < 16; ++q) tile[0][q * 256 + l] = pm[q * 256 + l];
  }
  __syncthreads();

  uint64_t avail = 0, keepbits = 0;
  if (wv == 0) avail = vwords[c * 64 + ln];

  for (int T = 0; T < 64; ++T) {
    const int cb = T & 1;
    if (wv > 0) {
      if (T + 1 < 64) {
        int l = tid - 64;
        const uint64_t* src = pm + (size_t)(T + 1) * 64 * 64;
        uint64_t* dst = tile[cb ^ 1];
#pragma unroll
        for (int q = 0; q < 16; ++q) dst[q * 256 + l] = src[q * 256 + l];
      }
    } else {
      const uint64_t* tp = tile[cb];
      uint64_t awT = readlane64(avail, T);  // decision word for all rows of this tile
      uint64_t pf[8];
#pragma unroll
      for (int u = 0; u < 8; ++u) pf[u] = tp[u * 64 + ln];
      uint64_t kwT = 0;
#pragma unroll
      for (int r = 0; r < 64; ++r) {
        uint64_t cur = pf[r & 7];
        if (r + 8 < 64) pf[r & 7] = tp[(r + 8) * 64 + ln];  // ds_read prefetch, off-chain
        bool kp = ((awT >> r) & 1ull) != 0ull;  // wave-uniform
        if (kp) {
          avail &= ~cur;                    // suppress in full bitset (future tiles)
          awT &= ~readlane64(cur, T);       // suppress within this tile's word
          kwT |= (1ull << r);
        }
      }
      if (ln == T) keepbits = kwT;  // lane T owns keep word T
    }
    __syncthreads();
  }
  if (wv == 0) keepw[c * 64 + ln] = keepbits;
}

// 9) stable-compact first <=500 kept per class (sorted order == score-descending)
__global__ void k_collect(const uint64_t* __restrict__ keepw, const uint32_t* __restrict__ ord,
                          const float* __restrict__ sc3, uint64_t* __restrict__ outk) {
  int c = blockIdx.x, t = threadIdx.x;
  __shared__ uint32_t ps[1024];
  uint32_t bits4 = 0;
#pragma unroll
  for (int q = 0; q < 4; ++q) {
    int i = t * 4 + q;
    uint32_t b = (uint32_t)((keepw[c * 64 + (i >> 6)] >> (i & 63)) & 1ull);
    bits4 |= b << q;
  }
  uint32_t cnt = __popc(bits4);
  ps[t] = cnt;
  __syncthreads();
  for (int off = 1; off < 1024; off <<= 1) {
    uint32_t v = (t >= off) ? ps[t - off] : 0;
    __syncthreads();
    ps[t] += v;
    __syncthreads();
  }
  uint32_t excl = ps[t] - cnt;
  if (t < MAXNUM) outk[c * MAXNUM + t] = ~0ull;  // pad
  __syncthreads();
  uint32_t r = excl;
#pragma unroll
  for (int q = 0; q < 4; ++q) {
    if ((bits4 >> q) & 1u) {
      int i = t * 4 + q;
      if (r < (uint32_t)MAXNUM) {
        uint32_t pos = ord[c * NPRE + i];
        uint32_t sb = __float_as_uint(sc3[pos * 3 + c]);
        outk[c * MAXNUM + r] = (((uint64_t)(~sb)) << 32) | (uint32_t)(c * NPRE + pos);
      }
      ++r;
    }
  }
}

// 10) merge-sort the <=1500 union, emit top-500 boxes/scores/labels
__global__ void k_final(const uint64_t* __restrict__ outk, const float* __restrict__ bb7,
                        const uint32_t* __restrict__ dsc, float* __restrict__ out) {
  __shared__ uint64_t sh[2048];  // 16 KB
  int t = threadIdx.x;
  for (int i = t; i < 2048; i += 1024) sh[i] = (i < 3 * MAXNUM) ? outk[i] : ~0ull;
  bitonic_sort_lds<2048, 1024>(sh);
  if (t < MAXNUM) {
    uint64_t key = sh[t];
    if (key != ~0ull) {
      uint32_t flat = (uint32_t)key;
      float score = __uint_as_float(~((uint32_t)(key >> 32)));
      int cc = (int)(flat >> 12);
      int pos = (int)(flat & 4095u);
      const float* b = bb7 + (size_t)pos * 7;
      float r = b[6];
      float dir_rot = r + HPIF - floorf(r + 0.5f) * PIF;
      float rr = dir_rot - HPIF + PIF * (float)dsc[pos];
#pragma unroll
      for (int q = 0; q < 6; ++q) out[t * 7 + q] = b[q];
      out[t * 7 + 6] = rr;
      out[7 * MAXNUM + t] = score;
      out[8 * MAXNUM + t] = (float)cc;
    } else {
#pragma unroll
      for (int q = 0; q < 7; ++q) out[t * 7 + q] = 0.0f;
      out[7 * MAXNUM + t] = 0.0f;
      out[8 * MAXNUM + t] = -1.0f;
    }
  }
}

// ---------------- launcher ----------------
extern "C" void kernel_launch(void* const* d_in, const int* in_sizes, int n_in,
                              void* d_out, int out_size, void* d_ws, size_t ws_size,
                              hipStream_t stream) {
  (void)in_sizes; (void)n_in; (void)out_size; (void)ws_size;
  const float* cls    = (const float*)d_in[0];
  const float* bbp    = (const float*)d_in[1];
  const float* dirp   = (const float*)d_in[2];
  const float* priors = (const float*)d_in[3];
  char* ws = (char*)d_ws;

  uint32_t* hist   = (uint32_t*)(ws + HIST_OFF);
  uint32_t* misc   = (uint32_t*)(ws + MISC_OFF);
  float*    ms     = (float*)(ws + MS_OFF);
  uint64_t* cand   = (uint64_t*)(ws + CAND_OFF);
  uint32_t* sel    = (uint32_t*)(ws + SEL_OFF);
  float*    sc3    = (float*)(ws + SC3_OFF);
  uint32_t* dsc    = (uint32_t*)(ws + DSC_OFF);
  float*    bb7    = (float*)(ws + BB7_OFF);
  float*    box4   = (float*)(ws + BOX4_OFF);
  float*    areaA  = (float*)(ws + AREA_OFF);
  uint32_t* ord    = (uint32_t*)(ws + ORD_OFF);
  uint64_t* vwords = (uint64_t*)(ws + VW_OFF);
  uint64_t* pmask  = (uint64_t*)(ws + PMASK_OFF);
  uint64_t* keepw  = (uint64_t*)(ws + KEEPW_OFF);
  uint64_t* outk   = (uint64_t*)(ws + OUTK_OFF);

  hipMemsetAsync(ws, 0, ZERO_BYTES, stream);
  k_score<<<HWSZ / 256, 256, 0, stream>>>(cls, ms, hist);
  k_scanhist<<<1, 256, 0, stream>>>(hist, misc);
  k_compact<<<NANCH / 256, 256, 0, stream>>>(ms, misc, cand);
  k_sortcand<<<1, 1024, 0, stream>>>(cand, misc, sel);
  k_gather<<<NPRE / 256, 256, 0, stream>>>(sel, cls, bbp, dirp, priors, sc3, dsc, bb7, box4, areaA);
  k_sortclass<<<3, 1024, 0, stream>>>(sc3, ord, vwords);
  k_mask<<<dim3(64, 64, 3), 64, 0, stream>>>(ord, box4, areaA, pmask);
  k_nms<<<3, 320, 0, stream>>>(pmask, vwords, keepw);
  k_collect<<<3, 1024, 0, stream>>>(keepw, ord, sc3, outk);
  k_final<<<1, 1024, 0, stream>>>(outk, bb7, dsc, (float*)d_out);
}

// Round 3
// 592.140 us; speedup vs baseline: 3.9706x; 2.0962x over previous
//
#include <hip/hip_runtime.h>
#include <stdint.h>
#include <stddef.h>

// ---------------- problem constants ----------------
constexpr int kH = 496, kW = 432;
constexpr int HWSZ = kH * kW;          // 214272
constexpr int NANCH = HWSZ * 6;        // 1285632 anchors
constexpr int NPRE = 4096;             // nms_pre
constexpr int MAXNUM = 500;
constexpr int CAND_CAP = 8192;
constexpr float SCORE_THR_F = 0.1f;
constexpr float PIF  = 3.14159265358979323846f;  // rounds to f32 pi
constexpr float HPIF = 1.57079632679489661923f;  // rounds to f32 pi/2

// histogram: bin = float_bits >> 15. scores are sigmoids in (0,1] so
// bits <= 0x3F800000 -> bin <= 32512 < 32768. 32768 bins always suffice.
constexpr int NBINS  = 32768;
constexpr int NPAIR  = NBINS / 2;      // packed u16 pairs = 16384 u32 = 64 KB
constexpr int NB_H   = 128;            // histogram blocks (private slices)

// ---------------- workspace layout (bytes) ----------------
constexpr size_t HIST_OFF  = 0;                                   // u32[32768] = 128 KB
constexpr size_t MISC_OFF  = 131072;                              // u32[64]: [0]=cand_cnt [1]=binB [2]=count_above
constexpr size_t MS_OFF    = 131328;                              // f32[NANCH]
constexpr size_t CAND_OFF  = MS_OFF + 4ull * NANCH;               // u64[8192]
// SLICES overlay cand..pmask: live only during k_score/k_reduce, dead after.
constexpr size_t SLICE_OFF = CAND_OFF;                            // u32[NB_H * NPAIR] = 8 MB
constexpr size_t SEL_OFF   = CAND_OFF + 8ull * CAND_CAP;          // u32[NPRE]
constexpr size_t SC3_OFF   = SEL_OFF + 4ull * NPRE;               // f32[NPRE*3]
constexpr size_t DSC_OFF   = SC3_OFF + 4ull * NPRE * 3;           // u32[NPRE]
constexpr size_t BB7_OFF   = DSC_OFF + 4ull * NPRE;               // f32[NPRE*7]
constexpr size_t BOX4_OFF  = BB7_OFF + 4ull * NPRE * 7;           // f32[NPRE*4]
constexpr size_t AREA_OFF  = BOX4_OFF + 4ull * NPRE * 4;          // f32[NPRE]
constexpr size_t ORD_OFF   = AREA_OFF + 4ull * NPRE;              // u32[3*NPRE]
constexpr size_t VW_OFF    = ORD_OFF + 4ull * 3 * NPRE;           // u64[3*64]
constexpr size_t PMASK_OFF = VW_OFF + 8ull * 3 * 64;              // u64[3*NPRE*64]  (6 MB)
constexpr size_t KEEPW_OFF = PMASK_OFF + 8ull * 3 * NPRE * 64;    // u64[3*64]
constexpr size_t OUTK_OFF  = KEEPW_OFF + 8ull * 3 * 64;           // u64[3*MAXNUM]
// total ~13.7 MB of d_ws (slices end at ~13.66 MB)

// ---------------- helpers ----------------
__device__ __forceinline__ float sigmoidf_(float x) { return 1.0f / (1.0f + expf(-x)); }

__device__ __forceinline__ uint64_t readlane64(uint64_t v, int lane) {
  uint32_t lo = (uint32_t)__builtin_amdgcn_readlane((int)(uint32_t)(v & 0xffffffffull), lane);
  uint32_t hi = (uint32_t)__builtin_amdgcn_readlane((int)(uint32_t)(v >> 32), lane);
  return (((uint64_t)hi) << 32) | (uint64_t)lo;
}

// ascending bitonic sort of NTOT u64 keys in LDS, NTHR threads
template <int NTOT, int NTHR>
__device__ void bitonic_sort_lds(uint64_t* s) {
  const int tid = threadIdx.x;
  for (int k = 2; k <= NTOT; k <<= 1) {
    for (int j = k >> 1; j > 0; j >>= 1) {
      __syncthreads();
      for (int idx = tid; idx < NTOT; idx += NTHR) {
        int ixj = idx ^ j;
        if (ixj > idx) {
          uint64_t a = s[idx], b = s[ixj];
          bool up = ((idx & k) == 0);
          if ((a > b) == up) { s[idx] = b; s[ixj] = a; }
        }
      }
    }
  }
  __syncthreads();
}

// ---------------- kernels ----------------

// 1) per-anchor max-of-3-sigmoids + PRIVATE per-block LDS histogram.
//    No global atomics: each block writes its own 64 KB slice (fully
//    overwritten every launch -> no zeroing needed).
__global__ __launch_bounds__(256) void k_score(const float* __restrict__ cls,
                                               float* __restrict__ ms,
                                               uint32_t* __restrict__ slices) {
  __shared__ uint32_t h[NPAIR];  // 32768 u16 counters packed in 16384 u32
  const int t = threadIdx.x, blk = blockIdx.x;
  for (int i = t; i < NPAIR; i += 256) h[i] = 0;
  __syncthreads();
  for (int p = blk * 256 + t; p < HWSZ; p += NB_H * 256) {
#pragma unroll
    for (int k = 0; k < 6; ++k) {
      float s0 = sigmoidf_(cls[(k * 3 + 0) * HWSZ + p]);
      float s1 = sigmoidf_(cls[(k * 3 + 1) * HWSZ + p]);
      float s2 = sigmoidf_(cls[(k * 3 + 2) * HWSZ + p]);
      float m = fmaxf(s0, fmaxf(s1, s2));
      ms[p * 6 + k] = m;
      uint32_t bin = __float_as_uint(m) >> 15;  // < 32768 (scores < 2.0)
      atomicAdd(&h[bin >> 1], 1u << ((bin & 1) * 16));  // LDS atomic only
    }
  }
  __syncthreads();
  uint32_t* myslice = slices + (size_t)blk * NPAIR;
  for (int i = t; i < NPAIR; i += 256) myslice[i] = h[i];
}

// 1b) column-reduce the NB_H slices into the u32 histogram (writes every bin)
__global__ void k_reduce(const uint32_t* __restrict__ slices, uint32_t* __restrict__ hist) {
  int i = blockIdx.x * 256 + threadIdx.x;  // pair index, grid covers NPAIR
  uint32_t lo = 0, hi = 0;
  for (int b = 0; b < NB_H; ++b) {
    uint32_t v = slices[(size_t)b * NPAIR + i];
    lo += v & 0xFFFFu;
    hi += v >> 16;
  }
  hist[2 * i]     = lo;
  hist[2 * i + 1] = hi;
}

// 2) find threshold bin B such that count(bin > B) < 4096 <= count(bin >= B)
__global__ void k_scanhist(const uint32_t* __restrict__ hist, uint32_t* __restrict__ misc) {
  __shared__ uint32_t part[256];
  __shared__ uint32_t suf[257];
  int t = threadIdx.x;
  int base = t * 128;  // 32768 bins / 256 threads
  uint32_t s = 0;
  for (int b = 0; b < 128; ++b) s += hist[base + b];
  part[t] = s;
  __syncthreads();
  if (t == 0) {
    uint32_t acc = 0;
    suf[256] = 0;
    for (int q = 255; q >= 0; --q) { suf[q] = acc + part[q]; acc = suf[q]; }
  }
  __syncthreads();
  uint32_t above = suf[t + 1];  // count in chunks with higher bins
  if (above < (uint32_t)NPRE && above + part[t] >= (uint32_t)NPRE) {
    uint32_t acc = above;
    for (int b = base + 127; b >= base; --b) {
      uint32_t h = hist[b];
      if (acc + h >= (uint32_t)NPRE) { misc[1] = (uint32_t)b; misc[2] = acc; break; }
      acc += h;
    }
  }
}

// 3) compact all anchors with bin >= B as sort keys (~score desc, idx asc)
__global__ void k_compact(const float* __restrict__ ms, uint32_t* __restrict__ misc,
                          uint64_t* __restrict__ cand) {
  int a = blockIdx.x * 256 + threadIdx.x;
  if (a >= NANCH) return;
  uint32_t bits = __float_as_uint(ms[a]);
  uint32_t B = misc[1];
  if ((bits >> 15) >= B) {
    uint32_t slot = atomicAdd(&misc[0], 1u);
    if (slot < (uint32_t)CAND_CAP)
      cand[slot] = (((uint64_t)(~bits)) << 32) | (uint32_t)a;
  }
}

// 4) sort candidates, take top-4096 => exact lax.top_k set & order
__global__ void k_sortcand(const uint64_t* __restrict__ cand, const uint32_t* __restrict__ misc,
                           uint32_t* __restrict__ sel) {
  __shared__ uint64_t sh[CAND_CAP];  // 64 KB
  int t = threadIdx.x;
  uint32_t cnt = misc[0];
  if (cnt > (uint32_t)CAND_CAP) cnt = CAND_CAP;
  for (int i = t; i < CAND_CAP; i += 1024) sh[i] = (i < (int)cnt) ? cand[i] : ~0ull;
  bitonic_sort_lds<CAND_CAP, 1024>(sh);
  for (int i = t; i < NPRE; i += 1024) sel[i] = (uint32_t)sh[i];
}

// 5) gather per-anchor data + decode boxes
__global__ void k_gather(const uint32_t* __restrict__ sel, const float* __restrict__ cls,
                         const float* __restrict__ bbp, const float* __restrict__ dirp,
                         const float* __restrict__ priors, float* __restrict__ sc3,
                         uint32_t* __restrict__ dsc, float* __restrict__ bb7,
                         float* __restrict__ box4, float* __restrict__ areaA) {
  int i = blockIdx.x * 256 + threadIdx.x;
  if (i >= NPRE) return;
  uint32_t a = sel[i];
  uint32_t p = a / 6u;
  uint32_t k = a - p * 6u;
#pragma unroll
  for (int c = 0; c < 3; ++c) sc3[i * 3 + c] = sigmoidf_(cls[(k * 3 + c) * HWSZ + p]);
  float d0 = dirp[(k * 2 + 0) * HWSZ + p];
  float d1 = dirp[(k * 2 + 1) * HWSZ + p];
  dsc[i] = (d1 > d0) ? 1u : 0u;  // jnp.argmax first-max semantics
  float dt[7], pr[7];
#pragma unroll
  for (int q = 0; q < 7; ++q) dt[q] = bbp[(k * 7 + q) * HWSZ + p];
#pragma unroll
  for (int q = 0; q < 7; ++q) pr[q] = priors[(size_t)a * 7 + q];
  // decode (mirrors reference op-for-op)
  float za = pr[2] + pr[5] * 0.5f;
  float diag = sqrtf(pr[4] * pr[4] + pr[3] * pr[3]);
  float xg = dt[0] * diag + pr[0];
  float yg = dt[1] * diag + pr[1];
  float zg = dt[2] * pr[5] + za;
  float wg = expf(dt[3]) * pr[3];
  float lg = expf(dt[4]) * pr[4];
  float hg = expf(dt[5]) * pr[5];
  float rg = dt[6] + pr[6];
  zg = zg - hg * 0.5f;
  bb7[i * 7 + 0] = xg; bb7[i * 7 + 1] = yg; bb7[i * 7 + 2] = zg;
  bb7[i * 7 + 3] = wg; bb7[i * 7 + 4] = lg; bb7[i * 7 + 5] = hg; bb7[i * 7 + 6] = rg;
  float x1 = xg - wg * 0.5f, y1 = yg - lg * 0.5f;
  float x2 = xg + wg * 0.5f, y2 = yg + lg * 0.5f;
  box4[i * 4 + 0] = x1; box4[i * 4 + 1] = y1; box4[i * 4 + 2] = x2; box4[i * 4 + 3] = y2;
  areaA[i] = (x2 - x1 + 1.0f) * (y2 - y1 + 1.0f);
}

// 6) per-class sort by (score desc, pos asc); also build valid bitset in sorted space
__global__ void k_sortclass(const float* __restrict__ sc3, uint32_t* __restrict__ ord,
                            uint64_t* __restrict__ vwords) {
  __shared__ uint64_t sh[NPRE];  // 32 KB
  int c = blockIdx.x, t = threadIdx.x;
  for (int i = t; i < NPRE; i += 1024) {
    uint32_t sb = __float_as_uint(sc3[i * 3 + c]);
    sh[i] = (((uint64_t)(~sb)) << 32) | (uint32_t)i;
  }
  bitonic_sort_lds<NPRE, 1024>(sh);
  for (int i = t; i < NPRE; i += 1024) ord[c * NPRE + i] = (uint32_t)sh[i];
  if (t < 64) {
    uint64_t w = 0;
    for (int b = 0; b < 64; ++b) {
      uint32_t pos = (uint32_t)sh[t * 64 + b];
      w |= ((uint64_t)(sc3[pos * 3 + c] > SCORE_THR_F)) << b;
    }
    vwords[c * 64 + t] = w;
  }
}

// 7) suppression bitmask in per-class sorted order: bit j of pmask[c][i][jt] = iou>thr
__global__ void k_mask(const uint32_t* __restrict__ ord, const float* __restrict__ box4,
                       const float* __restrict__ areaA, uint64_t* __restrict__ pmask) {
  int c = blockIdx.z, it = blockIdx.y, jt = blockIdx.x, t = threadIdx.x;
  __shared__ float jx1[64], jy1[64], jx2[64], jy2[64], jar[64];
  int j = ord[c * NPRE + jt * 64 + t];
  jx1[t] = box4[j * 4 + 0]; jy1[t] = box4[j * 4 + 1];
  jx2[t] = box4[j * 4 + 2]; jy2[t] = box4[j * 4 + 3];
  jar[t] = areaA[j];
  __syncthreads();
  int I = it * 64 + t;
  int i = ord[c * NPRE + I];
  float x1 = box4[i * 4 + 0], y1 = box4[i * 4 + 1];
  float x2 = box4[i * 4 + 2], y2 = box4[i * 4 + 3];
  float ar = areaA[i];
  uint64_t bits = 0;
  for (int b = 0; b < 64; ++b) {
    float xx1 = fmaxf(x1, jx1[b]), yy1 = fmaxf(y1, jy1[b]);
    float xx2 = fminf(x2, jx2[b]), yy2 = fminf(y2, jy2[b]);
    float iw = fmaxf(0.0f, xx2 - xx1 + 1.0f);
    float ih = fmaxf(0.0f, yy2 - yy1 + 1.0f);
    float inter = iw * ih;
    float iou = inter / (ar + jar[b] - inter);
    bits |= ((uint64_t)(iou > 0.5f)) << b;
  }
  pmask[((size_t)(c * NPRE + I)) * 64 + (size_t)jt] = bits;
}

// 8) tiled serial greedy NMS cascade: one block (320 thr) per class.
//    Wave 0 runs the serial scan out of LDS; waves 1..4 double-buffer the next
//    64-row x 64-word pmask tile (32 KB) global->LDS, overlapping the scan.
__global__ __launch_bounds__(320) void k_nms(const uint64_t* __restrict__ pmask,
                                             const uint64_t* __restrict__ vwords,
                                             uint64_t* __restrict__ keepw) {
  __shared__ uint64_t tile[2][64 * 64];  // 2 x 32 KB
  const int c = blockIdx.x;
  const int tid = threadIdx.x;
  const int wv = tid >> 6;   // 0..4
  const int ln = tid & 63;
  const uint64_t* pm = pmask + (size_t)c * NPRE * 64;

  if (wv > 0) {
    int l = tid - 64;  // 0..255
#pragma unroll
    for (int q = 0; q < 16; ++q) tile[0][q * 256 + l] = pm[q * 256 + l];
  }
  __syncthreads();

  uint64_t avail = 0, keepbits = 0;
  if (wv == 0) avail = vwords[c * 64 + ln];

  for (int T = 0; T < 64; ++T) {
    const int cb = T & 1;
    if (wv > 0) {
      if (T + 1 < 64) {
        int l = tid - 64;
        const uint64_t* src = pm + (size_t)(T + 1) * 64 * 64;
        uint64_t* dst = tile[cb ^ 1];
#pragma unroll
        for (int q = 0; q < 16; ++q) dst[q * 256 + l] = src[q * 256 + l];
      }
    } else {
      const uint64_t* tp = tile[cb];
      uint64_t awT = readlane64(avail, T);  // decision word for all rows of this tile
      uint64_t pf[8];
#pragma unroll
      for (int u = 0; u < 8; ++u) pf[u] = tp[u * 64 + ln];
      uint64_t kwT = 0;
#pragma unroll
      for (int r = 0; r < 64; ++r) {
        uint64_t cur = pf[r & 7];
        if (r + 8 < 64) pf[r & 7] = tp[(r + 8) * 64 + ln];  // ds_read prefetch, off-chain
        bool kp = ((awT >> r) & 1ull) != 0ull;  // wave-uniform
        if (kp) {
          avail &= ~cur;                    // suppress in full bitset (future tiles)
          awT &= ~readlane64(cur, T);       // suppress within this tile's word
          kwT |= (1ull << r);
        }
      }
      if (ln == T) keepbits = kwT;  // lane T owns keep word T
    }
    __syncthreads();
  }
  if (wv == 0) keepw[c * 64 + ln] = keepbits;
}

// 9) stable-compact first <=500 kept per class (sorted order == score-descending)
__global__ void k_collect(const uint64_t* __restrict__ keepw, const uint32_t* __restrict__ ord,
                          const float* __restrict__ sc3, uint64_t* __restrict__ outk) {
  int c = blockIdx.x, t = threadIdx.x;
  __shared__ uint32_t ps[1024];
  uint32_t bits4 = 0;
#pragma unroll
  for (int q = 0; q < 4; ++q) {
    int i = t * 4 + q;
    uint32_t b = (uint32_t)((keepw[c * 64 + (i >> 6)] >> (i & 63)) & 1ull);
    bits4 |= b << q;
  }
  uint32_t cnt = __popc(bits4);
  ps[t] = cnt;
  __syncthreads();
  for (int off = 1; off < 1024; off <<= 1) {
    uint32_t v = (t >= off) ? ps[t - off] : 0;
    __syncthreads();
    ps[t] += v;
    __syncthreads();
  }
  uint32_t excl = ps[t] - cnt;
  if (t < MAXNUM) outk[c * MAXNUM + t] = ~0ull;  // pad
  __syncthreads();
  uint32_t r = excl;
#pragma unroll
  for (int q = 0; q < 4; ++q) {
    if ((bits4 >> q) & 1u) {
      int i = t * 4 + q;
      if (r < (uint32_t)MAXNUM) {
        uint32_t pos = ord[c * NPRE + i];
        uint32_t sb = __float_as_uint(sc3[pos * 3 + c]);
        outk[c * MAXNUM + r] = (((uint64_t)(~sb)) << 32) | (uint32_t)(c * NPRE + pos);
      }
      ++r;
    }
  }
}

// 10) merge-sort the <=1500 union, emit top-500 boxes/scores/labels
__global__ void k_final(const uint64_t* __restrict__ outk, const float* __restrict__ bb7,
                        const uint32_t* __restrict__ dsc, float* __restrict__ out) {
  __shared__ uint64_t sh[2048];  // 16 KB
  int t = threadIdx.x;
  for (int i = t; i < 2048; i += 1024) sh[i] = (i < 3 * MAXNUM) ? outk[i] : ~0ull;
  bitonic_sort_lds<2048, 1024>(sh);
  if (t < MAXNUM) {
    uint64_t key = sh[t];
    if (key != ~0ull) {
      uint32_t flat = (uint32_t)key;
      float score = __uint_as_float(~((uint32_t)(key >> 32)));
      int cc = (int)(flat >> 12);
      int pos = (int)(flat & 4095u);
      const float* b = bb7 + (size_t)pos * 7;
      float r = b[6];
      float dir_rot = r + HPIF - floorf(r + 0.5f) * PIF;
      float rr = dir_rot - HPIF + PIF * (float)dsc[pos];
#pragma unroll
      for (int q = 0; q < 6; ++q) out[t * 7 + q] = b[q];
      out[t * 7 + 6] = rr;
      out[7 * MAXNUM + t] = score;
      out[8 * MAXNUM + t] = (float)cc;
    } else {
#pragma unroll
      for (int q = 0; q < 7; ++q) out[t * 7 + q] = 0.0f;
      out[7 * MAXNUM + t] = 0.0f;
      out[8 * MAXNUM + t] = -1.0f;
    }
  }
}

// ---------------- launcher ----------------
extern "C" void kernel_launch(void* const* d_in, const int* in_sizes, int n_in,
                              void* d_out, int out_size, void* d_ws, size_t ws_size,
                              hipStream_t stream) {
  (void)in_sizes; (void)n_in; (void)out_size; (void)ws_size;
  const float* cls    = (const float*)d_in[0];
  const float* bbp    = (const float*)d_in[1];
  const float* dirp   = (const float*)d_in[2];
  const float* priors = (const float*)d_in[3];
  char* ws = (char*)d_ws;

  uint32_t* hist   = (uint32_t*)(ws + HIST_OFF);
  uint32_t* misc   = (uint32_t*)(ws + MISC_OFF);
  float*    ms     = (float*)(ws + MS_OFF);
  uint32_t* slices = (uint32_t*)(ws + SLICE_OFF);
  uint64_t* cand   = (uint64_t*)(ws + CAND_OFF);
  uint32_t* sel    = (uint32_t*)(ws + SEL_OFF);
  float*    sc3    = (float*)(ws + SC3_OFF);
  uint32_t* dsc    = (uint32_t*)(ws + DSC_OFF);
  float*    bb7    = (float*)(ws + BB7_OFF);
  float*    box4   = (float*)(ws + BOX4_OFF);
  float*    areaA  = (float*)(ws + AREA_OFF);
  uint32_t* ord    = (uint32_t*)(ws + ORD_OFF);
  uint64_t* vwords = (uint64_t*)(ws + VW_OFF);
  uint64_t* pmask  = (uint64_t*)(ws + PMASK_OFF);
  uint64_t* keepw  = (uint64_t*)(ws + KEEPW_OFF);
  uint64_t* outk   = (uint64_t*)(ws + OUTK_OFF);

  hipMemsetAsync(misc, 0, 256, stream);  // only misc needs zeroing now
  k_score<<<NB_H, 256, 0, stream>>>(cls, ms, slices);
  k_reduce<<<NPAIR / 256, 256, 0, stream>>>(slices, hist);
  k_scanhist<<<1, 256, 0, stream>>>(hist, misc);
  k_compact<<<NANCH / 256, 256, 0, stream>>>(ms, misc, cand);
  k_sortcand<<<1, 1024, 0, stream>>>(cand, misc, sel);
  k_gather<<<NPRE / 256, 256, 0, stream>>>(sel, cls, bbp, dirp, priors, sc3, dsc, bb7, box4, areaA);
  k_sortclass<<<3, 1024, 0, stream>>>(sc3, ord, vwords);
  k_mask<<<dim3(64, 64, 3), 64, 0, stream>>>(ord, box4, areaA, pmask);
  k_nms<<<3, 320, 0, stream>>>(pmask, vwords, keepw);
  k_collect<<<3, 1024, 0, stream>>>(keepw, ord, sc3, outk);
  k_final<<<1, 1024, 0, stream>>>(outk, bb7, dsc, (float*)d_out);
}

// Round 4
// 471.045 us; speedup vs baseline: 4.9913x; 1.2571x over previous
//
#include <hip/hip_runtime.h>
#include <stdint.h>
#include <stddef.h>

// ---------------- problem constants ----------------
constexpr int kH = 496, kW = 432;
constexpr int HWSZ = kH * kW;          // 214272
constexpr int NANCH = HWSZ * 6;        // 1285632 anchors
constexpr int NPRE = 4096;             // nms_pre
constexpr int MAXNUM = 500;
constexpr int CAND_CAP = 8192;
constexpr float SCORE_THR_F = 0.1f;
constexpr float PIF  = 3.14159265358979323846f;  // rounds to f32 pi
constexpr float HPIF = 1.57079632679489661923f;  // rounds to f32 pi/2

// histogram: bin = float_bits >> 15. scores are sigmoids in (0,1] so
// bits <= 0x3F800000 -> bin <= 32512 < 32768. 32768 bins always suffice.
constexpr int NBINS  = 32768;
constexpr int NPAIR  = NBINS / 2;      // packed u16 pairs = 16384 u32 = 64 KB
constexpr int NB_H   = 128;            // histogram blocks (private slices)

// ---------------- workspace layout (bytes) ----------------
constexpr size_t HIST_OFF  = 0;                                   // u32[32768] = 128 KB
constexpr size_t MISC_OFF  = 131072;                              // u32[64]: [0]=cand_cnt [1]=binB [2]=count_above
constexpr size_t MS_OFF    = 131328;                              // f32[NANCH]
constexpr size_t CAND_OFF  = MS_OFF + 4ull * NANCH;               // u64[8192]
// SLICES overlay cand..pmask: live only during k_score/k_reduce, dead after.
constexpr size_t SLICE_OFF = CAND_OFF;                            // u32[NB_H * NPAIR] = 8 MB
constexpr size_t SEL_OFF   = CAND_OFF + 8ull * CAND_CAP;          // u32[NPRE]
constexpr size_t SC3_OFF   = SEL_OFF + 4ull * NPRE;               // f32[NPRE*3]
constexpr size_t DSC_OFF   = SC3_OFF + 4ull * NPRE * 3;           // u32[NPRE]
constexpr size_t BB7_OFF   = DSC_OFF + 4ull * NPRE;               // f32[NPRE*7]
constexpr size_t BOX4_OFF  = BB7_OFF + 4ull * NPRE * 7;           // f32[NPRE*4]
constexpr size_t AREA_OFF  = BOX4_OFF + 4ull * NPRE * 4;          // f32[NPRE]
constexpr size_t ORD_OFF   = AREA_OFF + 4ull * NPRE;              // u32[3*NPRE]
constexpr size_t VW_OFF    = ORD_OFF + 4ull * 3 * NPRE;           // u64[3*64]
constexpr size_t PMASK_OFF = VW_OFF + 8ull * 3 * 64;              // u64[3*NPRE*64]  (6 MB)
constexpr size_t KEEPW_OFF = PMASK_OFF + 8ull * 3 * NPRE * 64;    // u64[3*64]
// total ~13.7 MB of d_ws

// ---------------- helpers ----------------
__device__ __forceinline__ float sigmoidf_(float x) { return 1.0f / (1.0f + expf(-x)); }

__device__ __forceinline__ uint64_t readlane64(uint64_t v, int lane) {
  uint32_t lo = (uint32_t)__builtin_amdgcn_readlane((int)(uint32_t)(v & 0xffffffffull), lane);
  uint32_t hi = (uint32_t)__builtin_amdgcn_readlane((int)(uint32_t)(v >> 32), lane);
  return (((uint64_t)hi) << 32) | (uint64_t)lo;
}

// ascending bitonic sort of NTOT u64 keys in LDS, NTHR threads
template <int NTOT, int NTHR>
__device__ void bitonic_sort_lds(uint64_t* s) {
  const int tid = threadIdx.x;
  for (int k = 2; k <= NTOT; k <<= 1) {
    for (int j = k >> 1; j > 0; j >>= 1) {
      __syncthreads();
      for (int idx = tid; idx < NTOT; idx += NTHR) {
        int ixj = idx ^ j;
        if (ixj > idx) {
          uint64_t a = s[idx], b = s[ixj];
          bool up = ((idx & k) == 0);
          if ((a > b) == up) { s[idx] = b; s[ixj] = a; }
        }
      }
    }
  }
  __syncthreads();
}

// ---------------- kernels ----------------

// 1) per-anchor max-of-3-sigmoids + PRIVATE per-block LDS histogram.
__global__ __launch_bounds__(256) void k_score(const float* __restrict__ cls,
                                               float* __restrict__ ms,
                                               uint32_t* __restrict__ slices) {
  __shared__ uint32_t h[NPAIR];  // 32768 u16 counters packed in 16384 u32
  const int t = threadIdx.x, blk = blockIdx.x;
  for (int i = t; i < NPAIR; i += 256) h[i] = 0;
  __syncthreads();
  for (int p = blk * 256 + t; p < HWSZ; p += NB_H * 256) {
#pragma unroll
    for (int k = 0; k < 6; ++k) {
      float s0 = sigmoidf_(cls[(k * 3 + 0) * HWSZ + p]);
      float s1 = sigmoidf_(cls[(k * 3 + 1) * HWSZ + p]);
      float s2 = sigmoidf_(cls[(k * 3 + 2) * HWSZ + p]);
      float m = fmaxf(s0, fmaxf(s1, s2));
      ms[p * 6 + k] = m;
      uint32_t bin = __float_as_uint(m) >> 15;  // < 32768 (scores < 2.0)
      atomicAdd(&h[bin >> 1], 1u << ((bin & 1) * 16));  // LDS atomic only
    }
  }
  __syncthreads();
  uint32_t* myslice = slices + (size_t)blk * NPAIR;
  for (int i = t; i < NPAIR; i += 256) myslice[i] = h[i];
}

// 1b) column-reduce the NB_H slices into the u32 histogram (writes every bin)
__global__ void k_reduce(const uint32_t* __restrict__ slices, uint32_t* __restrict__ hist) {
  int i = blockIdx.x * 256 + threadIdx.x;  // pair index, grid covers NPAIR
  uint32_t lo = 0, hi = 0;
  for (int b = 0; b < NB_H; ++b) {
    uint32_t v = slices[(size_t)b * NPAIR + i];
    lo += v & 0xFFFFu;
    hi += v >> 16;
  }
  hist[2 * i]     = lo;
  hist[2 * i + 1] = hi;
}

// 2) find threshold bin B such that count(bin > B) < 4096 <= count(bin >= B)
__global__ void k_scanhist(const uint32_t* __restrict__ hist, uint32_t* __restrict__ misc) {
  __shared__ uint32_t part[256];
  __shared__ uint32_t suf[257];
  int t = threadIdx.x;
  int base = t * 128;  // 32768 bins / 256 threads
  uint32_t s = 0;
  for (int b = 0; b < 128; ++b) s += hist[base + b];
  part[t] = s;
  __syncthreads();
  if (t == 0) {
    uint32_t acc = 0;
    suf[256] = 0;
    for (int q = 255; q >= 0; --q) { suf[q] = acc + part[q]; acc = suf[q]; }
  }
  __syncthreads();
  uint32_t above = suf[t + 1];  // count in chunks with higher bins
  if (above < (uint32_t)NPRE && above + part[t] >= (uint32_t)NPRE) {
    uint32_t acc = above;
    for (int b = base + 127; b >= base; --b) {
      uint32_t h = hist[b];
      if (acc + h >= (uint32_t)NPRE) { misc[1] = (uint32_t)b; misc[2] = acc; break; }
      acc += h;
    }
  }
}

// 3) compact all anchors with bin >= B as sort keys (~score desc, idx asc)
__global__ void k_compact(const float* __restrict__ ms, uint32_t* __restrict__ misc,
                          uint64_t* __restrict__ cand) {
  int a = blockIdx.x * 256 + threadIdx.x;
  if (a >= NANCH) return;
  uint32_t bits = __float_as_uint(ms[a]);
  uint32_t B = misc[1];
  if ((bits >> 15) >= B) {
    uint32_t slot = atomicAdd(&misc[0], 1u);
    if (slot < (uint32_t)CAND_CAP)
      cand[slot] = (((uint64_t)(~bits)) << 32) | (uint32_t)a;
  }
}

// 4) sort candidates, take top-4096 => exact lax.top_k set & order
__global__ void k_sortcand(const uint64_t* __restrict__ cand, const uint32_t* __restrict__ misc,
                           uint32_t* __restrict__ sel) {
  __shared__ uint64_t sh[CAND_CAP];  // 64 KB
  int t = threadIdx.x;
  uint32_t cnt = misc[0];
  if (cnt > (uint32_t)CAND_CAP) cnt = CAND_CAP;
  for (int i = t; i < CAND_CAP; i += 1024) sh[i] = (i < (int)cnt) ? cand[i] : ~0ull;
  bitonic_sort_lds<CAND_CAP, 1024>(sh);
  for (int i = t; i < NPRE; i += 1024) sel[i] = (uint32_t)sh[i];
}

// 5) gather per-anchor data + decode boxes
__global__ void k_gather(const uint32_t* __restrict__ sel, const float* __restrict__ cls,
                         const float* __restrict__ bbp, const float* __restrict__ dirp,
                         const float* __restrict__ priors, float* __restrict__ sc3,
                         uint32_t* __restrict__ dsc, float* __restrict__ bb7,
                         float* __restrict__ box4, float* __restrict__ areaA) {
  int i = blockIdx.x * 256 + threadIdx.x;
  if (i >= NPRE) return;
  uint32_t a = sel[i];
  uint32_t p = a / 6u;
  uint32_t k = a - p * 6u;
#pragma unroll
  for (int c = 0; c < 3; ++c) sc3[i * 3 + c] = sigmoidf_(cls[(k * 3 + c) * HWSZ + p]);
  float d0 = dirp[(k * 2 + 0) * HWSZ + p];
  float d1 = dirp[(k * 2 + 1) * HWSZ + p];
  dsc[i] = (d1 > d0) ? 1u : 0u;  // jnp.argmax first-max semantics
  float dt[7], pr[7];
#pragma unroll
  for (int q = 0; q < 7; ++q) dt[q] = bbp[(k * 7 + q) * HWSZ + p];
#pragma unroll
  for (int q = 0; q < 7; ++q) pr[q] = priors[(size_t)a * 7 + q];
  // decode (mirrors reference op-for-op)
  float za = pr[2] + pr[5] * 0.5f;
  float diag = sqrtf(pr[4] * pr[4] + pr[3] * pr[3]);
  float xg = dt[0] * diag + pr[0];
  float yg = dt[1] * diag + pr[1];
  float zg = dt[2] * pr[5] + za;
  float wg = expf(dt[3]) * pr[3];
  float lg = expf(dt[4]) * pr[4];
  float hg = expf(dt[5]) * pr[5];
  float rg = dt[6] + pr[6];
  zg = zg - hg * 0.5f;
  bb7[i * 7 + 0] = xg; bb7[i * 7 + 1] = yg; bb7[i * 7 + 2] = zg;
  bb7[i * 7 + 3] = wg; bb7[i * 7 + 4] = lg; bb7[i * 7 + 5] = hg; bb7[i * 7 + 6] = rg;
  float x1 = xg - wg * 0.5f, y1 = yg - lg * 0.5f;
  float x2 = xg + wg * 0.5f, y2 = yg + lg * 0.5f;
  box4[i * 4 + 0] = x1; box4[i * 4 + 1] = y1; box4[i * 4 + 2] = x2; box4[i * 4 + 3] = y2;
  areaA[i] = (x2 - x1 + 1.0f) * (y2 - y1 + 1.0f);
}

// 6) per-class sort by (score desc, pos asc); also build valid bitset in sorted space
__global__ void k_sortclass(const float* __restrict__ sc3, uint32_t* __restrict__ ord,
                            uint64_t* __restrict__ vwords) {
  __shared__ uint64_t sh[NPRE];  // 32 KB
  int c = blockIdx.x, t = threadIdx.x;
  for (int i = t; i < NPRE; i += 1024) {
    uint32_t sb = __float_as_uint(sc3[i * 3 + c]);
    sh[i] = (((uint64_t)(~sb)) << 32) | (uint32_t)i;
  }
  bitonic_sort_lds<NPRE, 1024>(sh);
  for (int i = t; i < NPRE; i += 1024) ord[c * NPRE + i] = (uint32_t)sh[i];
  if (t < 64) {
    uint64_t w = 0;
    for (int b = 0; b < 64; ++b) {
      uint32_t pos = (uint32_t)sh[t * 64 + b];
      w |= ((uint64_t)(sc3[pos * 3 + c] > SCORE_THR_F)) << b;
    }
    vwords[c * 64 + t] = w;
  }
}

// 7) suppression bitmask in per-class sorted order; UPPER TRIANGLE ONLY.
//    Words jt < it are never observably read by the cascade (they cover
//    already-decided positions), so skip those blocks entirely.
__global__ void k_mask(const uint32_t* __restrict__ ord, const float* __restrict__ box4,
                       const float* __restrict__ areaA, uint64_t* __restrict__ pmask) {
  int c = blockIdx.z, it = blockIdx.y, jt = blockIdx.x, t = threadIdx.x;
  if (jt < it) return;  // lower triangle unread
  __shared__ float jx1[64], jy1[64], jx2[64], jy2[64], jar[64];
  int j = ord[c * NPRE + jt * 64 + t];
  jx1[t] = box4[j * 4 + 0]; jy1[t] = box4[j * 4 + 1];
  jx2[t] = box4[j * 4 + 2]; jy2[t] = box4[j * 4 + 3];
  jar[t] = areaA[j];
  __syncthreads();
  int I = it * 64 + t;
  int i = ord[c * NPRE + I];
  float x1 = box4[i * 4 + 0], y1 = box4[i * 4 + 1];
  float x2 = box4[i * 4 + 2], y2 = box4[i * 4 + 3];
  float ar = areaA[i];
  uint64_t bits = 0;
  for (int b = 0; b < 64; ++b) {
    float xx1 = fmaxf(x1, jx1[b]), yy1 = fmaxf(y1, jy1[b]);
    float xx2 = fminf(x2, jx2[b]), yy2 = fminf(y2, jy2[b]);
    float iw = fmaxf(0.0f, xx2 - xx1 + 1.0f);
    float ih = fmaxf(0.0f, yy2 - yy1 + 1.0f);
    float inter = iw * ih;
    float iou = inter / (ar + jar[b] - inter);
    bits |= ((uint64_t)(iou > 0.5f)) << b;
  }
  pmask[((size_t)(c * NPRE + I)) * 64 + (size_t)jt] = bits;
}

// 8) tiled serial greedy NMS cascade with EARLY EXIT at 500 keeps.
//    Only the first MAXNUM kept rows per class are observable downstream
//    (k_final takes the first <=500 in score order), so once cnt>=500 the
//    remaining tiles are dead work. Parity-double-buffered stop flags avoid
//    a laggard-wave race on the flag across phases.
__global__ __launch_bounds__(320) void k_nms(const uint64_t* __restrict__ pmask,
                                             const uint64_t* __restrict__ vwords,
                                             uint64_t* __restrict__ keepw) {
  __shared__ uint64_t tile[2][64 * 64];  // 2 x 32 KB
  __shared__ int s_stop[2];
  const int c = blockIdx.x;
  const int tid = threadIdx.x;
  const int wv = tid >> 6;   // 0..4
  const int ln = tid & 63;
  const uint64_t* pm = pmask + (size_t)c * NPRE * 64;

  if (tid == 0) { s_stop[0] = 0; s_stop[1] = 0; }
  if (wv > 0) {
    int l = tid - 64;  // 0..255
    const ulonglong2* src2 = (const ulonglong2*)pm;
    ulonglong2* dst2 = (ulonglong2*)tile[0];
#pragma unroll
    for (int q = 0; q < 8; ++q) dst2[q * 256 + l] = src2[q * 256 + l];
  }
  __syncthreads();

  uint64_t avail = 0, keepbits = 0;
  int cnt = 0;
  if (wv == 0) avail = vwords[c * 64 + ln];

  for (int T = 0; T < 64; ++T) {
    const int cb = T & 1;
    if (wv > 0) {
      if (T + 1 < 64) {
        int l = tid - 64;
        const ulonglong2* src2 = (const ulonglong2*)(pm + (size_t)(T + 1) * 64 * 64);
        ulonglong2* dst2 = (ulonglong2*)tile[cb ^ 1];
#pragma unroll
        for (int q = 0; q < 8; ++q) dst2[q * 256 + l] = src2[q * 256 + l];
      }
    } else {
      const uint64_t* tp = tile[cb];
      uint64_t awT = readlane64(avail, T);  // decision word for all rows of this tile
      uint64_t pf[8];
#pragma unroll
      for (int u = 0; u < 8; ++u) pf[u] = tp[u * 64 + ln];
      uint64_t kwT = 0;
#pragma unroll
      for (int r = 0; r < 64; ++r) {
        uint64_t cur = pf[r & 7];
        if (r + 8 < 64) pf[r & 7] = tp[(r + 8) * 64 + ln];  // ds_read prefetch, off-chain
        bool kp = ((awT >> r) & 1ull) != 0ull;  // wave-uniform
        if (kp) {
          avail &= ~cur;                    // suppress in full bitset (future tiles)
          awT &= ~readlane64(cur, T);       // suppress within this tile's word
          kwT |= (1ull << r);
        }
      }
      if (ln == T) keepbits = kwT;  // lane T owns keep word T
      cnt += (int)__popcll(kwT);
      if (ln == 0 && cnt >= MAXNUM) s_stop[cb] = 1;
    }
    __syncthreads();
    if (s_stop[cb]) break;  // uniform: set before the barrier of this phase
  }
  if (wv == 0) keepw[c * 64 + ln] = keepbits;
}

// 9) fused: per-class stable-compact first <=500 kept, then merge-sort the
//    <=1500 union and emit top-500 boxes/scores/labels. One block.
__global__ void k_final(const uint64_t* __restrict__ keepw, const uint32_t* __restrict__ ord,
                        const float* __restrict__ sc3, const float* __restrict__ bb7,
                        const uint32_t* __restrict__ dsc, float* __restrict__ out) {
  __shared__ uint64_t sh[2048];  // 16 KB
  __shared__ uint32_t ps[1024];
  int t = threadIdx.x;
  for (int i = t; i < 2048; i += 1024) sh[i] = ~0ull;
  __syncthreads();
  for (int c = 0; c < 3; ++c) {
    uint32_t bits4 = 0;
#pragma unroll
    for (int q = 0; q < 4; ++q) {
      int i = t * 4 + q;
      uint32_t b = (uint32_t)((keepw[c * 64 + (i >> 6)] >> (i & 63)) & 1ull);
      bits4 |= b << q;
    }
    uint32_t cnt = __popc(bits4);
    ps[t] = cnt;
    __syncthreads();
    for (int off = 1; off < 1024; off <<= 1) {
      uint32_t v = (t >= off) ? ps[t - off] : 0;
      __syncthreads();
      ps[t] += v;
      __syncthreads();
    }
    uint32_t r = ps[t] - cnt;  // exclusive prefix
#pragma unroll
    for (int q = 0; q < 4; ++q) {
      if ((bits4 >> q) & 1u) {
        if (r < (uint32_t)MAXNUM) {
          uint32_t pos = ord[c * NPRE + t * 4 + q];
          uint32_t sb = __float_as_uint(sc3[pos * 3 + c]);
          sh[c * MAXNUM + r] = (((uint64_t)(~sb)) << 32) | (uint32_t)(c * NPRE + pos);
        }
        ++r;
      }
    }
    __syncthreads();
  }
  bitonic_sort_lds<2048, 1024>(sh);
  if (t < MAXNUM) {
    uint64_t key = sh[t];
    if (key != ~0ull) {
      uint32_t flat = (uint32_t)key;
      float score = __uint_as_float(~((uint32_t)(key >> 32)));
      int cc = (int)(flat >> 12);
      int pos = (int)(flat & 4095u);
      const float* b = bb7 + (size_t)pos * 7;
      float r = b[6];
      float dir_rot = r + HPIF - floorf(r + 0.5f) * PIF;
      float rr = dir_rot - HPIF + PIF * (float)dsc[pos];
#pragma unroll
      for (int q = 0; q < 6; ++q) out[t * 7 + q] = b[q];
      out[t * 7 + 6] = rr;
      out[7 * MAXNUM + t] = score;
      out[8 * MAXNUM + t] = (float)cc;
    } else {
#pragma unroll
      for (int q = 0; q < 7; ++q) out[t * 7 + q] = 0.0f;
      out[7 * MAXNUM + t] = 0.0f;
      out[8 * MAXNUM + t] = -1.0f;
    }
  }
}

// ---------------- launcher ----------------
extern "C" void kernel_launch(void* const* d_in, const int* in_sizes, int n_in,
                              void* d_out, int out_size, void* d_ws, size_t ws_size,
                              hipStream_t stream) {
  (void)in_sizes; (void)n_in; (void)out_size; (void)ws_size;
  const float* cls    = (const float*)d_in[0];
  const float* bbp    = (const float*)d_in[1];
  const float* dirp   = (const float*)d_in[2];
  const float* priors = (const float*)d_in[3];
  char* ws = (char*)d_ws;

  uint32_t* hist   = (uint32_t*)(ws + HIST_OFF);
  uint32_t* misc   = (uint32_t*)(ws + MISC_OFF);
  float*    ms     = (float*)(ws + MS_OFF);
  uint32_t* slices = (uint32_t*)(ws + SLICE_OFF);
  uint64_t* cand   = (uint64_t*)(ws + CAND_OFF);
  uint32_t* sel    = (uint32_t*)(ws + SEL_OFF);
  float*    sc3    = (float*)(ws + SC3_OFF);
  uint32_t* dsc    = (uint32_t*)(ws + DSC_OFF);
  float*    bb7    = (float*)(ws + BB7_OFF);
  float*    box4   = (float*)(ws + BOX4_OFF);
  float*    areaA  = (float*)(ws + AREA_OFF);
  uint32_t* ord    = (uint32_t*)(ws + ORD_OFF);
  uint64_t* vwords = (uint64_t*)(ws + VW_OFF);
  uint64_t* pmask  = (uint64_t*)(ws + PMASK_OFF);
  uint64_t* keepw  = (uint64_t*)(ws + KEEPW_OFF);

  hipMemsetAsync(misc, 0, 256, stream);  // only misc needs zeroing
  k_score<<<NB_H, 256, 0, stream>>>(cls, ms, slices);
  k_reduce<<<NPAIR / 256, 256, 0, stream>>>(slices, hist);
  k_scanhist<<<1, 256, 0, stream>>>(hist, misc);
  k_compact<<<NANCH / 256, 256, 0, stream>>>(ms, misc, cand);
  k_sortcand<<<1, 1024, 0, stream>>>(cand, misc, sel);
  k_gather<<<NPRE / 256, 256, 0, stream>>>(sel, cls, bbp, dirp, priors, sc3, dsc, bb7, box4, areaA);
  k_sortclass<<<3, 1024, 0, stream>>>(sc3, ord, vwords);
  k_mask<<<dim3(64, 64, 3), 64, 0, stream>>>(ord, box4, areaA, pmask);
  k_nms<<<3, 320, 0, stream>>>(pmask, vwords, keepw);
  k_final<<<1, 1024, 0, stream>>>(keepw, ord, sc3, bb7, dsc, (float*)d_out);
}

// Round 6
// 440.594 us; speedup vs baseline: 5.3363x; 1.0691x over previous
//
#include <hip/hip_runtime.h>
#include <stdint.h>
#include <stddef.h>

// ---------------- problem constants ----------------
constexpr int kH = 496, kW = 432;
constexpr int HWSZ = kH * kW;          // 214272
constexpr int NANCH = HWSZ * 6;        // 1285632 anchors
constexpr int NPRE = 4096;             // nms_pre
constexpr int MAXNUM = 500;
constexpr int CAND_CAP = 8192;
constexpr float SCORE_THR_F = 0.1f;
constexpr float PIF  = 3.14159265358979323846f;  // rounds to f32 pi
constexpr float HPIF = 1.57079632679489661923f;  // rounds to f32 pi/2

// histogram: bin = float_bits >> 15. scores are sigmoids in (0,1] so
// bits <= 0x3F800000 -> bin <= 32512 < 32768. 32768 bins always suffice.
constexpr int NBINS  = 32768;
constexpr int NPAIR  = NBINS / 2;      // packed u16 pairs = 16384 u32 = 64 KB
constexpr int NB_H   = 128;            // histogram blocks (private slices)

// pad key: sorts AFTER every real key (real high32 = ~bits <= 0xFFFFFFFE).
constexpr uint64_t PADKEY = 0xFFFFFFFF00000000ull;

// ---------------- workspace layout (bytes) ----------------
constexpr size_t HIST_OFF  = 0;                                   // u32[32768] = 128 KB
constexpr size_t MISC_OFF  = 131072;                              // u32[64]
constexpr size_t MS_OFF    = 131328;                              // f32[NANCH]
constexpr size_t CAND_OFF  = MS_OFF + 4ull * NANCH;               // u64[8192]
// SLICES overlay cand..end: live only during k_score/k_reduce, dead after.
constexpr size_t SLICE_OFF = CAND_OFF;                            // u32[NB_H * NPAIR] = 8 MB
constexpr size_t SEL_OFF   = CAND_OFF + 8ull * CAND_CAP;          // u32[NPRE]
constexpr size_t SC3_OFF   = SEL_OFF + 4ull * NPRE;               // f32[NPRE*3]
constexpr size_t DSC_OFF   = SC3_OFF + 4ull * NPRE * 3;           // u32[NPRE]
constexpr size_t BB7_OFF   = DSC_OFF + 4ull * NPRE;               // f32[NPRE*7]
constexpr size_t BOX4_OFF  = BB7_OFF + 4ull * NPRE * 7;           // f32[NPRE*4]
constexpr size_t AREA_OFF  = BOX4_OFF + 4ull * NPRE * 4;          // f32[NPRE]
constexpr size_t ORD_OFF   = AREA_OFF + 4ull * NPRE;              // u32[3*NPRE]
constexpr size_t VW_OFF    = ORD_OFF + 4ull * 3 * NPRE;           // u64[3*64]
constexpr size_t PMASK_OFF = VW_OFF + 8ull * 3 * 64;              // u64[3*NPRE*64]  (6 MB)
constexpr size_t KEEPW_OFF = PMASK_OFF + 8ull * 3 * NPRE * 64;    // u64[3*64]
// radix ping-pong buffers (global, L2-resident); dead outside the sorts
constexpr size_t SORTA_OFF = KEEPW_OFF + 8ull * 3 * 64;           // u64[8192]
constexpr size_t SORTB_OFF = SORTA_OFF + 8ull * CAND_CAP;         // u64[8192]
constexpr size_t SCLS_OFF  = SORTB_OFF + 8ull * CAND_CAP;         // u64[3*2*NPRE]
// ends ~12.3 MB < slice end ~13.66 MB (already provisioned)

// ---------------- helpers ----------------
__device__ __forceinline__ float sigmoidf_(float x) { return 1.0f / (1.0f + expf(-x)); }

__device__ __forceinline__ uint64_t readlane64(uint64_t v, int lane) {
  uint32_t lo = (uint32_t)__builtin_amdgcn_readlane((int)(uint32_t)(v & 0xffffffffull), lane);
  uint32_t hi = (uint32_t)__builtin_amdgcn_readlane((int)(uint32_t)(v >> 32), lane);
  return (((uint64_t)hi) << 32) | (uint64_t)lo;
}

// lanes-with-equal-8-bit-digit mask (match-any via 8 ballots)
__device__ __forceinline__ uint64_t match_digit(uint32_t d) {
  uint64_t m = ~0ull;
#pragma unroll
  for (int b = 0; b < 8; ++b) {
    uint64_t bb = __ballot((d >> b) & 1u);
    m &= ((d >> b) & 1u) ? bb : ~bb;
  }
  return m;
}

// ---------------- stable LSD radix sort, u64 keys, 1024 threads -------------
// src/dst may live in global or LDS (inlined -> address space inferred).
// hist: LDS u32[16*256]; counts via LDS atomics (per-wave rows, leader-only).
// Stability: ballot-ranked scatter, leader atomicAdd + shfl broadcast.
template <int N>
__device__ __forceinline__ void radix_pass_u64(const uint64_t* src, uint64_t* dst, int sh,
                                               uint32_t* hist, uint32_t* wscan) {
  constexpr int NW = 16, CH = N / NW, STEPS = CH / 64;
  const int t = threadIdx.x, w = t >> 6, ln = t & 63;
  const uint64_t ltmask = (1ull << ln) - 1ull;
  for (int i = t; i < NW * 256; i += 1024) hist[i] = 0;
  __syncthreads();
  for (int s = 0; s < STEPS; ++s) {
    uint32_t d = (uint32_t)(src[w * CH + s * 64 + ln] >> sh) & 0xFFu;
    uint64_t m = match_digit(d);
    if ((m & ltmask) == 0)  // leader of its digit-group
      atomicAdd(&hist[w * 256 + d], (uint32_t)__popcll(m));
  }
  __syncthreads();
  // exclusive scan over digit-major (d, w) cells: idx = d*16 + w
  uint32_t v[4], sum = 0;
  const int base = t * 4;
#pragma unroll
  for (int q = 0; q < 4; ++q) {
    int idx = base + q;
    v[q] = hist[(idx & 15) * 256 + (idx >> 4)];
    sum += v[q];
  }
  uint32_t inc = sum;
#pragma unroll
  for (int dd = 1; dd < 64; dd <<= 1) { uint32_t u = __shfl_up(inc, dd, 64); if (ln >= dd) inc += u; }
  if (ln == 63) wscan[w] = inc;
  __syncthreads();
  uint32_t wbase = 0;
  for (int i = 0; i < w; ++i) wbase += wscan[i];
  uint32_t excl = wbase + inc - sum;
#pragma unroll
  for (int q = 0; q < 4; ++q) {
    int idx = base + q;
    hist[(idx & 15) * 256 + (idx >> 4)] = excl;  // count -> global offset
    excl += v[q];
  }
  __syncthreads();
  // stable scatter: index order = wave chunk / step / lane
  for (int s = 0; s < STEPS; ++s) {
    uint64_t key = src[w * CH + s * 64 + ln];
    uint32_t d = (uint32_t)(key >> sh) & 0xFFu;
    uint64_t m = match_digit(d);
    uint32_t mr = (uint32_t)__popcll(m & ltmask);
    int leader = (int)(__ffsll((unsigned long long)m) - 1);
    uint32_t b0 = 0;
    if (mr == 0) b0 = atomicAdd(&hist[w * 256 + d], (uint32_t)__popcll(m));
    b0 = __shfl(b0, leader, 64);
    dst[b0 + mr] = key;
  }
  __syncthreads();
}

template <int N>
__device__ __forceinline__ uint64_t* radix_sort_u64(uint64_t* bufA, uint64_t* bufB,
                                                    uint32_t* hist, uint32_t* wscan,
                                                    uint64_t* red /*LDS u64[32]*/) {
  const int t = threadIdx.x, w = t >> 6, ln = t & 63;
  // probe varying bytes (AND/OR reduce over all keys)
  uint64_t ov = 0, av = ~0ull;
  for (int i = t; i < N; i += 1024) { uint64_t k = bufA[i]; ov |= k; av &= k; }
#pragma unroll
  for (int dd = 1; dd < 64; dd <<= 1) { ov |= __shfl_xor(ov, dd, 64); av &= __shfl_xor(av, dd, 64); }
  if (ln == 0) { red[w] = ov; red[16 + w] = av; }
  __syncthreads();
  uint64_t o2 = 0, a2 = ~0ull;
  for (int i = 0; i < 16; ++i) { o2 |= red[i]; a2 &= red[16 + i]; }
  const uint64_t diff = o2 ^ a2;  // uniform
  __syncthreads();
  uint64_t* src = bufA;
  uint64_t* dst = bufB;
  for (int p = 0; p < 8; ++p) {
    if (!((diff >> (8 * p)) & 0xFFull)) continue;  // constant byte -> skip
    radix_pass_u64<N>(src, dst, 8 * p, hist, wscan);
    uint64_t* tmp = src; src = dst; dst = tmp;
  }
  return src;
}

// ---------------- kernels ----------------

// 1) per-anchor max-of-3-sigmoids + PRIVATE per-block LDS histogram.
__global__ __launch_bounds__(256) void k_score(const float* __restrict__ cls,
                                               float* __restrict__ ms,
                                               uint32_t* __restrict__ slices) {
  __shared__ uint32_t h[NPAIR];  // 64 KB
  const int t = threadIdx.x, blk = blockIdx.x;
  for (int i = t; i < NPAIR; i += 256) h[i] = 0;
  __syncthreads();
  for (int p = blk * 256 + t; p < HWSZ; p += NB_H * 256) {
#pragma unroll
    for (int k = 0; k < 6; ++k) {
      float s0 = sigmoidf_(cls[(k * 3 + 0) * HWSZ + p]);
      float s1 = sigmoidf_(cls[(k * 3 + 1) * HWSZ + p]);
      float s2 = sigmoidf_(cls[(k * 3 + 2) * HWSZ + p]);
      float m = fmaxf(s0, fmaxf(s1, s2));
      ms[p * 6 + k] = m;
      uint32_t bin = __float_as_uint(m) >> 15;  // < 32768 (scores < 2.0)
      atomicAdd(&h[bin >> 1], 1u << ((bin & 1) * 16));  // LDS atomic only
    }
  }
  __syncthreads();
  uint32_t* myslice = slices + (size_t)blk * NPAIR;
  for (int i = t; i < NPAIR; i += 256) myslice[i] = h[i];
}

// 1b) column-reduce the NB_H slices into the u32 histogram
__global__ void k_reduce(const uint32_t* __restrict__ slices, uint32_t* __restrict__ hist) {
  int i = blockIdx.x * 256 + threadIdx.x;
  uint32_t lo = 0, hi = 0;
  for (int b = 0; b < NB_H; ++b) {
    uint32_t v = slices[(size_t)b * NPAIR + i];
    lo += v & 0xFFFFu;
    hi += v >> 16;
  }
  hist[2 * i]     = lo;
  hist[2 * i + 1] = hi;
}

// 2) find threshold bin B such that count(bin > B) < 4096 <= count(bin >= B)
__global__ void k_scanhist(const uint32_t* __restrict__ hist, uint32_t* __restrict__ misc) {
  __shared__ uint32_t part[256];
  __shared__ uint32_t suf[257];
  int t = threadIdx.x;
  int base = t * 128;
  uint32_t s = 0;
  for (int b = 0; b < 128; ++b) s += hist[base + b];
  part[t] = s;
  __syncthreads();
  if (t == 0) {
    uint32_t acc = 0;
    suf[256] = 0;
    for (int q = 255; q >= 0; --q) { suf[q] = acc + part[q]; acc = suf[q]; }
  }
  __syncthreads();
  uint32_t above = suf[t + 1];
  if (above < (uint32_t)NPRE && above + part[t] >= (uint32_t)NPRE) {
    uint32_t acc = above;
    for (int b = base + 127; b >= base; --b) {
      uint32_t h = hist[b];
      if (acc + h >= (uint32_t)NPRE) { misc[1] = (uint32_t)b; misc[2] = acc; break; }
      acc += h;
    }
  }
}

// 3) compact all anchors with bin >= B as sort keys (~score desc, idx asc)
__global__ void k_compact(const float* __restrict__ ms, uint32_t* __restrict__ misc,
                          uint64_t* __restrict__ cand) {
  int a = blockIdx.x * 256 + threadIdx.x;
  if (a >= NANCH) return;
  uint32_t bits = __float_as_uint(ms[a]);
  uint32_t B = misc[1];
  if ((bits >> 15) >= B) {
    uint32_t slot = atomicAdd(&misc[0], 1u);
    if (slot < (uint32_t)CAND_CAP)
      cand[slot] = (((uint64_t)(~bits)) << 32) | (uint32_t)a;
  }
}

// 4) radix-sort candidates (global ping-pong), take top-4096
__global__ __launch_bounds__(1024) void k_sortcand(const uint64_t* __restrict__ cand,
                                                   const uint32_t* __restrict__ misc,
                                                   uint64_t* __restrict__ bufA,
                                                   uint64_t* __restrict__ bufB,
                                                   uint32_t* __restrict__ sel) {
  __shared__ uint32_t hist[16 * 256];  // 16 KB
  __shared__ uint32_t wscan[16];
  __shared__ uint64_t red[32];
  int t = threadIdx.x;
  uint32_t cnt = misc[0];
  if (cnt > (uint32_t)CAND_CAP) cnt = CAND_CAP;
  for (int i = t; i < CAND_CAP; i += 1024) bufA[i] = (i < (int)cnt) ? cand[i] : PADKEY;
  __syncthreads();
  uint64_t* sorted = radix_sort_u64<CAND_CAP>(bufA, bufB, hist, wscan, red);
  for (int i = t; i < NPRE; i += 1024) sel[i] = (uint32_t)sorted[i];
}

// 5) gather per-anchor data + decode boxes
__global__ void k_gather(const uint32_t* __restrict__ sel, const float* __restrict__ cls,
                         const float* __restrict__ bbp, const float* __restrict__ dirp,
                         const float* __restrict__ priors, float* __restrict__ sc3,
                         uint32_t* __restrict__ dsc, float* __restrict__ bb7,
                         float* __restrict__ box4, float* __restrict__ areaA) {
  int i = blockIdx.x * 256 + threadIdx.x;
  if (i >= NPRE) return;
  uint32_t a = sel[i];
  uint32_t p = a / 6u;
  uint32_t k = a - p * 6u;
#pragma unroll
  for (int c = 0; c < 3; ++c) sc3[i * 3 + c] = sigmoidf_(cls[(k * 3 + c) * HWSZ + p]);
  float d0 = dirp[(k * 2 + 0) * HWSZ + p];
  float d1 = dirp[(k * 2 + 1) * HWSZ + p];
  dsc[i] = (d1 > d0) ? 1u : 0u;
  float dt[7], pr[7];
#pragma unroll
  for (int q = 0; q < 7; ++q) dt[q] = bbp[(k * 7 + q) * HWSZ + p];
#pragma unroll
  for (int q = 0; q < 7; ++q) pr[q] = priors[(size_t)a * 7 + q];
  float za = pr[2] + pr[5] * 0.5f;
  float diag = sqrtf(pr[4] * pr[4] + pr[3] * pr[3]);
  float xg = dt[0] * diag + pr[0];
  float yg = dt[1] * diag + pr[1];
  float zg = dt[2] * pr[5] + za;
  float wg = expf(dt[3]) * pr[3];
  float lg = expf(dt[4]) * pr[4];
  float hg = expf(dt[5]) * pr[5];
  float rg = dt[6] + pr[6];
  zg = zg - hg * 0.5f;
  bb7[i * 7 + 0] = xg; bb7[i * 7 + 1] = yg; bb7[i * 7 + 2] = zg;
  bb7[i * 7 + 3] = wg; bb7[i * 7 + 4] = lg; bb7[i * 7 + 5] = hg; bb7[i * 7 + 6] = rg;
  float x1 = xg - wg * 0.5f, y1 = yg - lg * 0.5f;
  float x2 = xg + wg * 0.5f, y2 = yg + lg * 0.5f;
  box4[i * 4 + 0] = x1; box4[i * 4 + 1] = y1; box4[i * 4 + 2] = x2; box4[i * 4 + 3] = y2;
  areaA[i] = (x2 - x1 + 1.0f) * (y2 - y1 + 1.0f);
}

// 6) per-class radix sort (global ping-pong per class); build valid bitset
__global__ __launch_bounds__(1024) void k_sortclass(const float* __restrict__ sc3,
                                                    uint64_t* __restrict__ scls,
                                                    uint32_t* __restrict__ ord,
                                                    uint64_t* __restrict__ vwords) {
  __shared__ uint32_t hist[16 * 256];  // 16 KB
  __shared__ uint32_t wscan[16];
  __shared__ uint64_t red[32];
  int c = blockIdx.x, t = threadIdx.x;
  uint64_t* bufA = scls + (size_t)c * 2 * NPRE;
  uint64_t* bufB = bufA + NPRE;
  for (int i = t; i < NPRE; i += 1024) {
    uint32_t sb = __float_as_uint(sc3[i * 3 + c]);
    bufA[i] = (((uint64_t)(~sb)) << 32) | (uint32_t)i;
  }
  __syncthreads();
  uint64_t* sorted = radix_sort_u64<NPRE>(bufA, bufB, hist, wscan, red);
  for (int i = t; i < NPRE; i += 1024) ord[c * NPRE + i] = (uint32_t)sorted[i];
  if (t < 64) {
    uint64_t w = 0;
    for (int b = 0; b < 64; ++b) {
      uint32_t pos = (uint32_t)sorted[t * 64 + b];
      w |= ((uint64_t)(sc3[pos * 3 + c] > SCORE_THR_F)) << b;
    }
    vwords[c * 64 + t] = w;
  }
}

// 7) suppression bitmask in per-class sorted order; UPPER TRIANGLE ONLY.
__global__ void k_mask(const uint32_t* __restrict__ ord, const float* __restrict__ box4,
                       const float* __restrict__ areaA, uint64_t* __restrict__ pmask) {
  int c = blockIdx.z, it = blockIdx.y, jt = blockIdx.x, t = threadIdx.x;
  if (jt < it) return;
  __shared__ float jx1[64], jy1[64], jx2[64], jy2[64], jar[64];
  int j = ord[c * NPRE + jt * 64 + t];
  jx1[t] = box4[j * 4 + 0]; jy1[t] = box4[j * 4 + 1];
  jx2[t] = box4[j * 4 + 2]; jy2[t] = box4[j * 4 + 3];
  jar[t] = areaA[j];
  __syncthreads();
  int I = it * 64 + t;
  int i = ord[c * NPRE + I];
  float x1 = box4[i * 4 + 0], y1 = box4[i * 4 + 1];
  float x2 = box4[i * 4 + 2], y2 = box4[i * 4 + 3];
  float ar = areaA[i];
  uint64_t bits = 0;
  for (int b = 0; b < 64; ++b) {
    float xx1 = fmaxf(x1, jx1[b]), yy1 = fmaxf(y1, jy1[b]);
    float xx2 = fminf(x2, jx2[b]), yy2 = fminf(y2, jy2[b]);
    float iw = fmaxf(0.0f, xx2 - xx1 + 1.0f);
    float ih = fmaxf(0.0f, yy2 - yy1 + 1.0f);
    float inter = iw * ih;
    float iou = inter / (ar + jar[b] - inter);
    bits |= ((uint64_t)(iou > 0.5f)) << b;
  }
  pmask[((size_t)(c * NPRE + I)) * 64 + (size_t)jt] = bits;
}

// 8) tiled serial greedy NMS cascade with EARLY EXIT at 500 keeps.
__global__ __launch_bounds__(320) void k_nms(const uint64_t* __restrict__ pmask,
                                             const uint64_t* __restrict__ vwords,
                                             uint64_t* __restrict__ keepw) {
  __shared__ uint64_t tile[2][64 * 64];  // 2 x 32 KB
  __shared__ int s_stop[2];
  const int c = blockIdx.x;
  const int tid = threadIdx.x;
  const int wv = tid >> 6;
  const int ln = tid & 63;
  const uint64_t* pm = pmask + (size_t)c * NPRE * 64;

  if (tid == 0) { s_stop[0] = 0; s_stop[1] = 0; }
  if (wv > 0) {
    int l = tid - 64;
    const ulonglong2* src2 = (const ulonglong2*)pm;
    ulonglong2* dst2 = (ulonglong2*)tile[0];
#pragma unroll
    for (int q = 0; q < 8; ++q) dst2[q * 256 + l] = src2[q * 256 + l];
  }
  __syncthreads();

  uint64_t avail = 0, keepbits = 0;
  int cnt = 0;
  if (wv == 0) avail = vwords[c * 64 + ln];

  for (int T = 0; T < 64; ++T) {
    const int cb = T & 1;
    if (wv > 0) {
      if (T + 1 < 64) {
        int l = tid - 64;
        const ulonglong2* src2 = (const ulonglong2*)(pm + (size_t)(T + 1) * 64 * 64);
        ulonglong2* dst2 = (ulonglong2*)tile[cb ^ 1];
#pragma unroll
        for (int q = 0; q < 8; ++q) dst2[q * 256 + l] = src2[q * 256 + l];
      }
    } else {
      const uint64_t* tp = tile[cb];
      uint64_t awT = readlane64(avail, T);
      uint64_t pf[8];
#pragma unroll
      for (int u = 0; u < 8; ++u) pf[u] = tp[u * 64 + ln];
      uint64_t kwT = 0;
#pragma unroll
      for (int r = 0; r < 64; ++r) {
        uint64_t cur = pf[r & 7];
        if (r + 8 < 64) pf[r & 7] = tp[(r + 8) * 64 + ln];
        bool kp = ((awT >> r) & 1ull) != 0ull;
        if (kp) {
          avail &= ~cur;
          awT &= ~readlane64(cur, T);
          kwT |= (1ull << r);
        }
      }
      if (ln == T) keepbits = kwT;
      cnt += (int)__popcll(kwT);
      if (ln == 0 && cnt >= MAXNUM) s_stop[cb] = 1;
    }
    __syncthreads();
    if (s_stop[cb]) break;
  }
  if (wv == 0) keepw[c * 64 + ln] = keepbits;
}

// 9) fused: per-class stable-compact first <=500 kept, LDS radix-sort the
//    <=1500 union, emit top-500 boxes/scores/labels. One block, 52 KB LDS.
__global__ __launch_bounds__(1024) void k_final(const uint64_t* __restrict__ keepw,
                                                const uint32_t* __restrict__ ord,
                                                const float* __restrict__ sc3,
                                                const float* __restrict__ bb7,
                                                const uint32_t* __restrict__ dsc,
                                                float* __restrict__ out) {
  __shared__ uint64_t bufA[2048];       // 16 KB
  __shared__ uint64_t bufB[2048];       // 16 KB
  __shared__ uint32_t hist[16 * 256];   // 16 KB
  __shared__ uint32_t wscan[16];
  __shared__ uint64_t red[32];
  __shared__ uint32_t ps[1024];         // 4 KB
  int t = threadIdx.x;
  for (int i = t; i < 2048; i += 1024) bufA[i] = PADKEY;
  __syncthreads();
  for (int c = 0; c < 3; ++c) {
    uint32_t bits4 = 0;
#pragma unroll
    for (int q = 0; q < 4; ++q) {
      int i = t * 4 + q;
      uint32_t b = (uint32_t)((keepw[c * 64 + (i >> 6)] >> (i & 63)) & 1ull);
      bits4 |= b << q;
    }
    uint32_t cnt = __popc(bits4);
    ps[t] = cnt;
    __syncthreads();
    for (int off = 1; off < 1024; off <<= 1) {
      uint32_t v = (t >= off) ? ps[t - off] : 0;
      __syncthreads();
      ps[t] += v;
      __syncthreads();
    }
    uint32_t r = ps[t] - cnt;
#pragma unroll
    for (int q = 0; q < 4; ++q) {
      if ((bits4 >> q) & 1u) {
        if (r < (uint32_t)MAXNUM) {
          uint32_t pos = ord[c * NPRE + t * 4 + q];
          uint32_t sb = __float_as_uint(sc3[pos * 3 + c]);
          bufA[c * MAXNUM + r] = (((uint64_t)(~sb)) << 32) | (uint32_t)(c * NPRE + pos);
        }
        ++r;
      }
    }
    __syncthreads();
  }
  uint64_t* sorted = radix_sort_u64<2048>(bufA, bufB, hist, wscan, red);
  if (t < MAXNUM) {
    uint64_t key = sorted[t];
    if ((uint32_t)(key >> 32) != 0xFFFFFFFFu) {
      uint32_t flat = (uint32_t)key;
      float score = __uint_as_float(~((uint32_t)(key >> 32)));
      int cc = (int)(flat >> 12);
      int pos = (int)(flat & 4095u);
      const float* b = bb7 + (size_t)pos * 7;
      float r = b[6];
      float dir_rot = r + HPIF - floorf(r + 0.5f) * PIF;
      float rr = dir_rot - HPIF + PIF * (float)dsc[pos];
#pragma unroll
      for (int q = 0; q < 6; ++q) out[t * 7 + q] = b[q];
      out[t * 7 + 6] = rr;
      out[7 * MAXNUM + t] = score;
      out[8 * MAXNUM + t] = (float)cc;
    } else {
#pragma unroll
      for (int q = 0; q < 7; ++q) out[t * 7 + q] = 0.0f;
      out[7 * MAXNUM + t] = 0.0f;
      out[8 * MAXNUM + t] = -1.0f;
    }
  }
}

// ---------------- launcher ----------------
extern "C" void kernel_launch(void* const* d_in, const int* in_sizes, int n_in,
                              void* d_out, int out_size, void* d_ws, size_t ws_size,
                              hipStream_t stream) {
  (void)in_sizes; (void)n_in; (void)out_size; (void)ws_size;
  const float* cls    = (const float*)d_in[0];
  const float* bbp    = (const float*)d_in[1];
  const float* dirp   = (const float*)d_in[2];
  const float* priors = (const float*)d_in[3];
  char* ws = (char*)d_ws;

  uint32_t* hist   = (uint32_t*)(ws + HIST_OFF);
  uint32_t* misc   = (uint32_t*)(ws + MISC_OFF);
  float*    ms     = (float*)(ws + MS_OFF);
  uint32_t* slices = (uint32_t*)(ws + SLICE_OFF);
  uint64_t* cand   = (uint64_t*)(ws + CAND_OFF);
  uint32_t* sel    = (uint32_t*)(ws + SEL_OFF);
  float*    sc3    = (float*)(ws + SC3_OFF);
  uint32_t* dsc    = (uint32_t*)(ws + DSC_OFF);
  float*    bb7    = (float*)(ws + BB7_OFF);
  float*    box4   = (float*)(ws + BOX4_OFF);
  float*    areaA  = (float*)(ws + AREA_OFF);
  uint32_t* ord    = (uint32_t*)(ws + ORD_OFF);
  uint64_t* vwords = (uint64_t*)(ws + VW_OFF);
  uint64_t* pmask  = (uint64_t*)(ws + PMASK_OFF);
  uint64_t* keepw  = (uint64_t*)(ws + KEEPW_OFF);
  uint64_t* sortA  = (uint64_t*)(ws + SORTA_OFF);
  uint64_t* sortB  = (uint64_t*)(ws + SORTB_OFF);
  uint64_t* scls   = (uint64_t*)(ws + SCLS_OFF);

  hipMemsetAsync(misc, 0, 256, stream);
  k_score<<<NB_H, 256, 0, stream>>>(cls, ms, slices);
  k_reduce<<<NPAIR / 256, 256, 0, stream>>>(slices, hist);
  k_scanhist<<<1, 256, 0, stream>>>(hist, misc);
  k_compact<<<NANCH / 256, 256, 0, stream>>>(ms, misc, cand);
  k_sortcand<<<1, 1024, 0, stream>>>(cand, misc, sortA, sortB, sel);
  k_gather<<<NPRE / 256, 256, 0, stream>>>(sel, cls, bbp, dirp, priors, sc3, dsc, bb7, box4, areaA);
  k_sortclass<<<3, 1024, 0, stream>>>(sc3, scls, ord, vwords);
  k_mask<<<dim3(64, 64, 3), 64, 0, stream>>>(ord, box4, areaA, pmask);
  k_nms<<<3, 320, 0, stream>>>(pmask, vwords, keepw);
  k_final<<<1, 1024, 0, stream>>>(keepw, ord, sc3, bb7, dsc, (float*)d_out);
}

// Round 7
// 352.772 us; speedup vs baseline: 6.6648x; 1.2489x over previous
//
#include <hip/hip_runtime.h>
#include <stdint.h>
#include <stddef.h>

// ---------------- problem constants ----------------
constexpr int kH = 496, kW = 432;
constexpr int HWSZ = kH * kW;          // 214272
constexpr int NANCH = HWSZ * 6;        // 1285632 anchors
constexpr int NPRE = 4096;             // nms_pre
constexpr int MAXNUM = 500;
constexpr int CAND_CAP = 8192;
constexpr float SCORE_THR_F = 0.1f;
constexpr float PIF  = 3.14159265358979323846f;  // rounds to f32 pi
constexpr float HPIF = 1.57079632679489661923f;  // rounds to f32 pi/2

// histogram: bin = float_bits >> 15. scores are sigmoids in (0,1] so
// bits <= 0x3F800000 -> bin <= 32512 < 32768. 32768 bins always suffice.
constexpr int NBINS  = 32768;
constexpr int NPAIR  = NBINS / 2;      // packed u16 pairs = 16384 u32 = 64 KB
constexpr int NB_H   = 128;            // histogram blocks (private slices)

// pad key: sorts AFTER every real key (real high32 = ~bits <= 0xFFFFFFFE).
constexpr uint64_t PADKEY = 0xFFFFFFFF00000000ull;

// ---------------- workspace layout (bytes) ----------------
constexpr size_t HIST_OFF  = 0;                                   // u32[32768] = 128 KB
constexpr size_t MISC_OFF  = 131072;                              // u32[64]
constexpr size_t MS_OFF    = 131328;                              // f32[NANCH]
constexpr size_t CAND_OFF  = MS_OFF + 4ull * NANCH;               // u64[8192]
// SLICES overlay cand..end: live only during k_score/k_reduce, dead after.
constexpr size_t SLICE_OFF = CAND_OFF;                            // u32[NB_H * NPAIR] = 8 MB
constexpr size_t SEL_OFF   = CAND_OFF + 8ull * CAND_CAP;          // u32[NPRE]
constexpr size_t SC3_OFF   = SEL_OFF + 4ull * NPRE;               // f32[NPRE*3]
constexpr size_t DSC_OFF   = SC3_OFF + 4ull * NPRE * 3;           // u32[NPRE]
constexpr size_t BB7_OFF   = DSC_OFF + 4ull * NPRE;               // f32[NPRE*7]
constexpr size_t BOX4_OFF  = BB7_OFF + 4ull * NPRE * 7;           // f32[NPRE*4]
constexpr size_t AREA_OFF  = BOX4_OFF + 4ull * NPRE * 4;          // f32[NPRE]
constexpr size_t ORD_OFF   = AREA_OFF + 4ull * NPRE;              // u32[3*NPRE]
constexpr size_t VW_OFF    = ORD_OFF + 4ull * 3 * NPRE;           // u64[3*64]
constexpr size_t PMASK_OFF = VW_OFF + 8ull * 3 * 64;              // u64[3*NPRE*64]  (6 MB)
constexpr size_t KEEPW_OFF = PMASK_OFF + 8ull * 3 * NPRE * 64;    // u64[3*64]

// ---------------- helpers ----------------
__device__ __forceinline__ float sigmoidf_(float x) { return 1.0f / (1.0f + expf(-x)); }

__device__ __forceinline__ uint64_t readlane64(uint64_t v, int lane) {
  uint32_t lo = (uint32_t)__builtin_amdgcn_readlane((int)(uint32_t)(v & 0xffffffffull), lane);
  uint32_t hi = (uint32_t)__builtin_amdgcn_readlane((int)(uint32_t)(v >> 32), lane);
  return (((uint64_t)hi) << 32) | (uint64_t)lo;
}

// lanes-with-equal-8-bit-digit mask (match-any via 8 ballots)
__device__ __forceinline__ uint64_t match_digit(uint32_t d) {
  uint64_t m = ~0ull;
#pragma unroll
  for (int b = 0; b < 8; ++b) {
    uint64_t bb = __ballot((d >> b) & 1u);
    m &= ((d >> b) & 1u) ? bb : ~bb;
  }
  return m;
}

// ---------------- stable LSD radix sort (LDS, used only by k_final) ---------
template <int N>
__device__ __forceinline__ void radix_pass_u64(const uint64_t* src, uint64_t* dst, int sh,
                                               uint32_t* hist, uint32_t* wscan) {
  constexpr int NW = 16, CH = N / NW, STEPS = CH / 64;
  const int t = threadIdx.x, w = t >> 6, ln = t & 63;
  const uint64_t ltmask = (1ull << ln) - 1ull;
  for (int i = t; i < NW * 256; i += 1024) hist[i] = 0;
  __syncthreads();
  for (int s = 0; s < STEPS; ++s) {
    uint32_t d = (uint32_t)(src[w * CH + s * 64 + ln] >> sh) & 0xFFu;
    uint64_t m = match_digit(d);
    if ((m & ltmask) == 0)
      atomicAdd(&hist[w * 256 + d], (uint32_t)__popcll(m));
  }
  __syncthreads();
  uint32_t v[4], sum = 0;
  const int base = t * 4;
#pragma unroll
  for (int q = 0; q < 4; ++q) {
    int idx = base + q;
    v[q] = hist[(idx & 15) * 256 + (idx >> 4)];
    sum += v[q];
  }
  uint32_t inc = sum;
#pragma unroll
  for (int dd = 1; dd < 64; dd <<= 1) { uint32_t u = __shfl_up(inc, dd, 64); if (ln >= dd) inc += u; }
  if (ln == 63) wscan[w] = inc;
  __syncthreads();
  uint32_t wbase = 0;
  for (int i = 0; i < w; ++i) wbase += wscan[i];
  uint32_t excl = wbase + inc - sum;
#pragma unroll
  for (int q = 0; q < 4; ++q) {
    int idx = base + q;
    hist[(idx & 15) * 256 + (idx >> 4)] = excl;
    excl += v[q];
  }
  __syncthreads();
  for (int s = 0; s < STEPS; ++s) {
    uint64_t key = src[w * CH + s * 64 + ln];
    uint32_t d = (uint32_t)(key >> sh) & 0xFFu;
    uint64_t m = match_digit(d);
    uint32_t mr = (uint32_t)__popcll(m & ltmask);
    int leader = (int)(__ffsll((unsigned long long)m) - 1);
    uint32_t b0 = 0;
    if (mr == 0) b0 = atomicAdd(&hist[w * 256 + d], (uint32_t)__popcll(m));
    b0 = __shfl(b0, leader, 64);
    dst[b0 + mr] = key;
  }
  __syncthreads();
}

template <int N>
__device__ __forceinline__ uint64_t* radix_sort_u64(uint64_t* bufA, uint64_t* bufB,
                                                    uint32_t* hist, uint32_t* wscan,
                                                    uint64_t* red /*LDS u64[32]*/) {
  const int t = threadIdx.x, w = t >> 6, ln = t & 63;
  uint64_t ov = 0, av = ~0ull;
  for (int i = t; i < N; i += 1024) { uint64_t k = bufA[i]; ov |= k; av &= k; }
#pragma unroll
  for (int dd = 1; dd < 64; dd <<= 1) { ov |= __shfl_xor(ov, dd, 64); av &= __shfl_xor(av, dd, 64); }
  if (ln == 0) { red[w] = ov; red[16 + w] = av; }
  __syncthreads();
  uint64_t o2 = 0, a2 = ~0ull;
  for (int i = 0; i < 16; ++i) { o2 |= red[i]; a2 &= red[16 + i]; }
  const uint64_t diff = o2 ^ a2;
  __syncthreads();
  uint64_t* src = bufA;
  uint64_t* dst = bufB;
  for (int p = 0; p < 8; ++p) {
    if (!((diff >> (8 * p)) & 0xFFull)) continue;
    radix_pass_u64<N>(src, dst, 8 * p, hist, wscan);
    uint64_t* tmp = src; src = dst; dst = tmp;
  }
  return src;
}

// ---------------- kernels ----------------

// 1) per-anchor max-of-3-sigmoids + PRIVATE per-block LDS histogram.
__global__ __launch_bounds__(256) void k_score(const float* __restrict__ cls,
                                               float* __restrict__ ms,
                                               uint32_t* __restrict__ slices) {
  __shared__ uint32_t h[NPAIR];  // 64 KB
  const int t = threadIdx.x, blk = blockIdx.x;
  for (int i = t; i < NPAIR; i += 256) h[i] = 0;
  __syncthreads();
  for (int p = blk * 256 + t; p < HWSZ; p += NB_H * 256) {
#pragma unroll
    for (int k = 0; k < 6; ++k) {
      float s0 = sigmoidf_(cls[(k * 3 + 0) * HWSZ + p]);
      float s1 = sigmoidf_(cls[(k * 3 + 1) * HWSZ + p]);
      float s2 = sigmoidf_(cls[(k * 3 + 2) * HWSZ + p]);
      float m = fmaxf(s0, fmaxf(s1, s2));
      ms[p * 6 + k] = m;
      uint32_t bin = __float_as_uint(m) >> 15;  // < 32768 (scores < 2.0)
      atomicAdd(&h[bin >> 1], 1u << ((bin & 1) * 16));  // LDS atomic only
    }
  }
  __syncthreads();
  uint32_t* myslice = slices + (size_t)blk * NPAIR;
  for (int i = t; i < NPAIR; i += 256) myslice[i] = h[i];
}

// 1b) column-reduce the NB_H slices into the u32 histogram
__global__ void k_reduce(const uint32_t* __restrict__ slices, uint32_t* __restrict__ hist) {
  int i = blockIdx.x * 256 + threadIdx.x;
  uint32_t lo = 0, hi = 0;
  for (int b = 0; b < NB_H; ++b) {
    uint32_t v = slices[(size_t)b * NPAIR + i];
    lo += v & 0xFFFFu;
    hi += v >> 16;
  }
  hist[2 * i]     = lo;
  hist[2 * i + 1] = hi;
}

// 2) find threshold bin B such that count(bin > B) < 4096 <= count(bin >= B)
__global__ void k_scanhist(const uint32_t* __restrict__ hist, uint32_t* __restrict__ misc) {
  __shared__ uint32_t part[256];
  __shared__ uint32_t suf[257];
  int t = threadIdx.x;
  int base = t * 128;
  uint32_t s = 0;
  for (int b = 0; b < 128; ++b) s += hist[base + b];
  part[t] = s;
  __syncthreads();
  if (t == 0) {
    uint32_t acc = 0;
    suf[256] = 0;
    for (int q = 255; q >= 0; --q) { suf[q] = acc + part[q]; acc = suf[q]; }
  }
  __syncthreads();
  uint32_t above = suf[t + 1];
  if (above < (uint32_t)NPRE && above + part[t] >= (uint32_t)NPRE) {
    uint32_t acc = above;
    for (int b = base + 127; b >= base; --b) {
      uint32_t h = hist[b];
      if (acc + h >= (uint32_t)NPRE) { misc[1] = (uint32_t)b; misc[2] = acc; break; }
      acc += h;
    }
  }
}

// 3) compact all anchors with bin >= B as sort keys (~score desc, idx asc)
__global__ void k_compact(const float* __restrict__ ms, uint32_t* __restrict__ misc,
                          uint64_t* __restrict__ cand) {
  int a = blockIdx.x * 256 + threadIdx.x;
  if (a >= NANCH) return;
  uint32_t bits = __float_as_uint(ms[a]);
  uint32_t B = misc[1];
  if ((bits >> 15) >= B) {
    uint32_t slot = atomicAdd(&misc[0], 1u);
    if (slot < (uint32_t)CAND_CAP)
      cand[slot] = (((uint64_t)(~bits)) << 32) | (uint32_t)a;
  }
}

// 4) EXACT rank-by-count (replaces single-block radix sort).
//    Keys unique (embed anchor id) => rank = #{keys < k} is the exact stable
//    permutation. One v_cmp_u64+ballot+popc does 64 comparisons; each wave
//    owns 16 rows and streams the candidate set 64-wide through lanes.
__global__ __launch_bounds__(256) void k_rank(const uint64_t* __restrict__ cand,
                                              const uint32_t* __restrict__ misc,
                                              uint32_t* __restrict__ sel) {
  const int tid = threadIdx.x, ln = tid & 63;
  const int wave = blockIdx.x * 4 + (tid >> 6);   // 0..511
  const int base = wave * 16;                     // row base, covers CAND_CAP
  uint32_t cnt = misc[0];
  if (cnt > (uint32_t)CAND_CAP) cnt = CAND_CAP;
  uint64_t kr[16];
#pragma unroll
  for (int r = 0; r < 16; ++r) kr[r] = cand[base + r];  // lane-uniform row keys
  uint32_t rnk[16];
#pragma unroll
  for (int r = 0; r < 16; ++r) rnk[r] = 0;
  const int nch = ((int)cnt + 63) >> 6;
  for (int ch = 0; ch < nch; ++ch) {
    uint64_t ck = cand[ch * 64 + ln];             // 64 comparison keys in lanes
    uint64_t vm = __ballot(ch * 64 + ln < (int)cnt);
#pragma unroll
    for (int r = 0; r < 16; ++r)
      rnk[r] += (uint32_t)__popcll(__ballot(ck < kr[r]) & vm);
  }
#pragma unroll
  for (int r = 0; r < 16; ++r) {
    int row = base + r;
    if (ln == 0 && row < (int)cnt && rnk[r] < (uint32_t)NPRE)
      sel[rnk[r]] = (uint32_t)kr[r];
  }
}

// 5) gather per-anchor data + decode boxes
__global__ void k_gather(const uint32_t* __restrict__ sel, const float* __restrict__ cls,
                         const float* __restrict__ bbp, const float* __restrict__ dirp,
                         const float* __restrict__ priors, float* __restrict__ sc3,
                         uint32_t* __restrict__ dsc, float* __restrict__ bb7,
                         float* __restrict__ box4, float* __restrict__ areaA) {
  int i = blockIdx.x * 256 + threadIdx.x;
  if (i >= NPRE) return;
  uint32_t a = sel[i];
  uint32_t p = a / 6u;
  uint32_t k = a - p * 6u;
#pragma unroll
  for (int c = 0; c < 3; ++c) sc3[i * 3 + c] = sigmoidf_(cls[(k * 3 + c) * HWSZ + p]);
  float d0 = dirp[(k * 2 + 0) * HWSZ + p];
  float d1 = dirp[(k * 2 + 1) * HWSZ + p];
  dsc[i] = (d1 > d0) ? 1u : 0u;
  float dt[7], pr[7];
#pragma unroll
  for (int q = 0; q < 7; ++q) dt[q] = bbp[(k * 7 + q) * HWSZ + p];
#pragma unroll
  for (int q = 0; q < 7; ++q) pr[q] = priors[(size_t)a * 7 + q];
  float za = pr[2] + pr[5] * 0.5f;
  float diag = sqrtf(pr[4] * pr[4] + pr[3] * pr[3]);
  float xg = dt[0] * diag + pr[0];
  float yg = dt[1] * diag + pr[1];
  float zg = dt[2] * pr[5] + za;
  float wg = expf(dt[3]) * pr[3];
  float lg = expf(dt[4]) * pr[4];
  float hg = expf(dt[5]) * pr[5];
  float rg = dt[6] + pr[6];
  zg = zg - hg * 0.5f;
  bb7[i * 7 + 0] = xg; bb7[i * 7 + 1] = yg; bb7[i * 7 + 2] = zg;
  bb7[i * 7 + 3] = wg; bb7[i * 7 + 4] = lg; bb7[i * 7 + 5] = hg; bb7[i * 7 + 6] = rg;
  float x1 = xg - wg * 0.5f, y1 = yg - lg * 0.5f;
  float x2 = xg + wg * 0.5f, y2 = yg + lg * 0.5f;
  box4[i * 4 + 0] = x1; box4[i * 4 + 1] = y1; box4[i * 4 + 2] = x2; box4[i * 4 + 3] = y2;
  areaA[i] = (x2 - x1 + 1.0f) * (y2 - y1 + 1.0f);
}

// 6) per-class EXACT rank-by-count on key (~score_bits<<32 | pos).
//    grid (64, 3): 64 blocks x 4 waves x 16 rows = 4096 rows per class.
__global__ __launch_bounds__(256) void k_rankcls(const float* __restrict__ sc3,
                                                 uint32_t* __restrict__ ord) {
  const int tid = threadIdx.x, ln = tid & 63;
  const int c = blockIdx.y;
  const int wave = blockIdx.x * 4 + (tid >> 6);  // 0..255
  const int base = wave * 16;
  uint64_t kr[16];
#pragma unroll
  for (int r = 0; r < 16; ++r) {
    int j = base + r;
    kr[r] = (((uint64_t)(~__float_as_uint(sc3[j * 3 + c]))) << 32) | (uint32_t)j;
  }
  uint32_t rnk[16];
#pragma unroll
  for (int r = 0; r < 16; ++r) rnk[r] = 0;
  for (int ch = 0; ch < NPRE / 64; ++ch) {
    int j = ch * 64 + ln;
    uint64_t ck = (((uint64_t)(~__float_as_uint(sc3[j * 3 + c]))) << 32) | (uint32_t)j;
#pragma unroll
    for (int r = 0; r < 16; ++r)
      rnk[r] += (uint32_t)__popcll(__ballot(ck < kr[r]));
  }
#pragma unroll
  for (int r = 0; r < 16; ++r)
    if (ln == 0) ord[c * NPRE + rnk[r]] = (uint32_t)(base + r);
}

// 6b) valid bitset in sorted space: wave w covers sorted positions w*64..+63
__global__ __launch_bounds__(1024) void k_vwords(const uint32_t* __restrict__ ord,
                                                 const float* __restrict__ sc3,
                                                 uint64_t* __restrict__ vwords) {
  int c = blockIdx.x, t = threadIdx.x, ln = t & 63;
  for (int k = 0; k < 4; ++k) {
    int i = k * 1024 + t;
    uint32_t pos = ord[c * NPRE + i];
    uint64_t m = __ballot(sc3[pos * 3 + c] > SCORE_THR_F);
    if (ln == 0) vwords[c * 64 + (i >> 6)] = m;
  }
}

// 7) suppression bitmask in per-class sorted order; UPPER TRIANGLE ONLY.
__global__ void k_mask(const uint32_t* __restrict__ ord, const float* __restrict__ box4,
                       const float* __restrict__ areaA, uint64_t* __restrict__ pmask) {
  int c = blockIdx.z, it = blockIdx.y, jt = blockIdx.x, t = threadIdx.x;
  if (jt < it) return;
  __shared__ float jx1[64], jy1[64], jx2[64], jy2[64], jar[64];
  int j = ord[c * NPRE + jt * 64 + t];
  jx1[t] = box4[j * 4 + 0]; jy1[t] = box4[j * 4 + 1];
  jx2[t] = box4[j * 4 + 2]; jy2[t] = box4[j * 4 + 3];
  jar[t] = areaA[j];
  __syncthreads();
  int I = it * 64 + t;
  int i = ord[c * NPRE + I];
  float x1 = box4[i * 4 + 0], y1 = box4[i * 4 + 1];
  float x2 = box4[i * 4 + 2], y2 = box4[i * 4 + 3];
  float ar = areaA[i];
  uint64_t bits = 0;
  for (int b = 0; b < 64; ++b) {
    float xx1 = fmaxf(x1, jx1[b]), yy1 = fmaxf(y1, jy1[b]);
    float xx2 = fminf(x2, jx2[b]), yy2 = fminf(y2, jy2[b]);
    float iw = fmaxf(0.0f, xx2 - xx1 + 1.0f);
    float ih = fmaxf(0.0f, yy2 - yy1 + 1.0f);
    float inter = iw * ih;
    float iou = inter / (ar + jar[b] - inter);
    bits |= ((uint64_t)(iou > 0.5f)) << b;
  }
  pmask[((size_t)(c * NPRE + I)) * 64 + (size_t)jt] = bits;
}

// 8) tiled serial greedy NMS cascade with EARLY EXIT at 500 keeps.
__global__ __launch_bounds__(320) void k_nms(const uint64_t* __restrict__ pmask,
                                             const uint64_t* __restrict__ vwords,
                                             uint64_t* __restrict__ keepw) {
  __shared__ uint64_t tile[2][64 * 64];  // 2 x 32 KB
  __shared__ int s_stop[2];
  const int c = blockIdx.x;
  const int tid = threadIdx.x;
  const int wv = tid >> 6;
  const int ln = tid & 63;
  const uint64_t* pm = pmask + (size_t)c * NPRE * 64;

  if (tid == 0) { s_stop[0] = 0; s_stop[1] = 0; }
  if (wv > 0) {
    int l = tid - 64;
    const ulonglong2* src2 = (const ulonglong2*)pm;
    ulonglong2* dst2 = (ulonglong2*)tile[0];
#pragma unroll
    for (int q = 0; q < 8; ++q) dst2[q * 256 + l] = src2[q * 256 + l];
  }
  __syncthreads();

  uint64_t avail = 0, keepbits = 0;
  int cnt = 0;
  if (wv == 0) avail = vwords[c * 64 + ln];

  for (int T = 0; T < 64; ++T) {
    const int cb = T & 1;
    if (wv > 0) {
      if (T + 1 < 64) {
        int l = tid - 64;
        const ulonglong2* src2 = (const ulonglong2*)(pm + (size_t)(T + 1) * 64 * 64);
        ulonglong2* dst2 = (ulonglong2*)tile[cb ^ 1];
#pragma unroll
        for (int q = 0; q < 8; ++q) dst2[q * 256 + l] = src2[q * 256 + l];
      }
    } else {
      const uint64_t* tp = tile[cb];
      uint64_t awT = readlane64(avail, T);
      uint64_t pf[8];
#pragma unroll
      for (int u = 0; u < 8; ++u) pf[u] = tp[u * 64 + ln];
      uint64_t kwT = 0;
#pragma unroll
      for (int r = 0; r < 64; ++r) {
        uint64_t cur = pf[r & 7];
        if (r + 8 < 64) pf[r & 7] = tp[(r + 8) * 64 + ln];
        bool kp = ((awT >> r) & 1ull) != 0ull;
        if (kp) {
          avail &= ~cur;
          awT &= ~readlane64(cur, T);
          kwT |= (1ull << r);
        }
      }
      if (ln == T) keepbits = kwT;
      cnt += (int)__popcll(kwT);
      if (ln == 0 && cnt >= MAXNUM) s_stop[cb] = 1;
    }
    __syncthreads();
    if (s_stop[cb]) break;
  }
  if (wv == 0) keepw[c * 64 + ln] = keepbits;
}

// 9) fused: per-class stable-compact first <=500 kept, LDS radix-sort the
//    <=1500 union, emit top-500 boxes/scores/labels. One block, 52 KB LDS.
__global__ __launch_bounds__(1024) void k_final(const uint64_t* __restrict__ keepw,
                                                const uint32_t* __restrict__ ord,
                                                const float* __restrict__ sc3,
                                                const float* __restrict__ bb7,
                                                const uint32_t* __restrict__ dsc,
                                                float* __restrict__ out) {
  __shared__ uint64_t bufA[2048];       // 16 KB
  __shared__ uint64_t bufB[2048];       // 16 KB
  __shared__ uint32_t hist[16 * 256];   // 16 KB
  __shared__ uint32_t wscan[16];
  __shared__ uint64_t red[32];
  __shared__ uint32_t ps[1024];         // 4 KB
  int t = threadIdx.x;
  for (int i = t; i < 2048; i += 1024) bufA[i] = PADKEY;
  __syncthreads();
  for (int c = 0; c < 3; ++c) {
    uint32_t bits4 = 0;
#pragma unroll
    for (int q = 0; q < 4; ++q) {
      int i = t * 4 + q;
      uint32_t b = (uint32_t)((keepw[c * 64 + (i >> 6)] >> (i & 63)) & 1ull);
      bits4 |= b << q;
    }
    uint32_t cnt = __popc(bits4);
    ps[t] = cnt;
    __syncthreads();
    for (int off = 1; off < 1024; off <<= 1) {
      uint32_t v = (t >= off) ? ps[t - off] : 0;
      __syncthreads();
      ps[t] += v;
      __syncthreads();
    }
    uint32_t r = ps[t] - cnt;
#pragma unroll
    for (int q = 0; q < 4; ++q) {
      if ((bits4 >> q) & 1u) {
        if (r < (uint32_t)MAXNUM) {
          uint32_t pos = ord[c * NPRE + t * 4 + q];
          uint32_t sb = __float_as_uint(sc3[pos * 3 + c]);
          bufA[c * MAXNUM + r] = (((uint64_t)(~sb)) << 32) | (uint32_t)(c * NPRE + pos);
        }
        ++r;
      }
    }
    __syncthreads();
  }
  uint64_t* sorted = radix_sort_u64<2048>(bufA, bufB, hist, wscan, red);
  if (t < MAXNUM) {
    uint64_t key = sorted[t];
    if ((uint32_t)(key >> 32) != 0xFFFFFFFFu) {
      uint32_t flat = (uint32_t)key;
      float score = __uint_as_float(~((uint32_t)(key >> 32)));
      int cc = (int)(flat >> 12);
      int pos = (int)(flat & 4095u);
      const float* b = bb7 + (size_t)pos * 7;
      float r = b[6];
      float dir_rot = r + HPIF - floorf(r + 0.5f) * PIF;
      float rr = dir_rot - HPIF + PIF * (float)dsc[pos];
#pragma unroll
      for (int q = 0; q < 6; ++q) out[t * 7 + q] = b[q];
      out[t * 7 + 6] = rr;
      out[7 * MAXNUM + t] = score;
      out[8 * MAXNUM + t] = (float)cc;
    } else {
#pragma unroll
      for (int q = 0; q < 7; ++q) out[t * 7 + q] = 0.0f;
      out[7 * MAXNUM + t] = 0.0f;
      out[8 * MAXNUM + t] = -1.0f;
    }
  }
}

// ---------------- launcher ----------------
extern "C" void kernel_launch(void* const* d_in, const int* in_sizes, int n_in,
                              void* d_out, int out_size, void* d_ws, size_t ws_size,
                              hipStream_t stream) {
  (void)in_sizes; (void)n_in; (void)out_size; (void)ws_size;
  const float* cls    = (const float*)d_in[0];
  const float* bbp    = (const float*)d_in[1];
  const float* dirp   = (const float*)d_in[2];
  const float* priors = (const float*)d_in[3];
  char* ws = (char*)d_ws;

  uint32_t* hist   = (uint32_t*)(ws + HIST_OFF);
  uint32_t* misc   = (uint32_t*)(ws + MISC_OFF);
  float*    ms     = (float*)(ws + MS_OFF);
  uint32_t* slices = (uint32_t*)(ws + SLICE_OFF);
  uint64_t* cand   = (uint64_t*)(ws + CAND_OFF);
  uint32_t* sel    = (uint32_t*)(ws + SEL_OFF);
  float*    sc3    = (float*)(ws + SC3_OFF);
  uint32_t* dsc    = (uint32_t*)(ws + DSC_OFF);
  float*    bb7    = (float*)(ws + BB7_OFF);
  float*    box4   = (float*)(ws + BOX4_OFF);
  float*    areaA  = (float*)(ws + AREA_OFF);
  uint32_t* ord    = (uint32_t*)(ws + ORD_OFF);
  uint64_t* vwords = (uint64_t*)(ws + VW_OFF);
  uint64_t* pmask  = (uint64_t*)(ws + PMASK_OFF);
  uint64_t* keepw  = (uint64_t*)(ws + KEEPW_OFF);

  hipMemsetAsync(misc, 0, 256, stream);
  k_score<<<NB_H, 256, 0, stream>>>(cls, ms, slices);
  k_reduce<<<NPAIR / 256, 256, 0, stream>>>(slices, hist);
  k_scanhist<<<1, 256, 0, stream>>>(hist, misc);
  k_compact<<<NANCH / 256, 256, 0, stream>>>(ms, misc, cand);
  k_rank<<<CAND_CAP / (4 * 16), 256, 0, stream>>>(cand, misc, sel);
  k_gather<<<NPRE / 256, 256, 0, stream>>>(sel, cls, bbp, dirp, priors, sc3, dsc, bb7, box4, areaA);
  k_rankcls<<<dim3(NPRE / (4 * 16), 3), 256, 0, stream>>>(sc3, ord);
  k_vwords<<<3, 1024, 0, stream>>>(ord, sc3, vwords);
  k_mask<<<dim3(64, 64, 3), 64, 0, stream>>>(ord, box4, areaA, pmask);
  k_nms<<<3, 320, 0, stream>>>(pmask, vwords, keepw);
  k_final<<<1, 1024, 0, stream>>>(keepw, ord, sc3, bb7, dsc, (float*)d_out);
}

// Round 8
// 316.610 us; speedup vs baseline: 7.4260x; 1.1142x over previous
//
#include <hip/hip_runtime.h>
#include <stdint.h>
#include <stddef.h>

// ---------------- problem constants ----------------
constexpr int kH = 496, kW = 432;
constexpr int HWSZ = kH * kW;          // 214272
constexpr int NANCH = HWSZ * 6;        // 1285632 anchors
constexpr int NPRE = 4096;             // nms_pre
constexpr int MAXNUM = 500;
constexpr int CAND_CAP = 8192;
constexpr float SCORE_THR_F = 0.1f;
constexpr float PIF  = 3.14159265358979323846f;  // rounds to f32 pi
constexpr float HPIF = 1.57079632679489661923f;  // rounds to f32 pi/2

// histogram: bin = float_bits >> 15. scores are sigmoids in (0,1] so
// bits <= 0x3F800000 -> bin <= 32512 < 32768. 32768 bins always suffice.
constexpr int NBINS  = 32768;
constexpr int NPAIR  = NBINS / 2;      // packed u16 pairs = 16384 u32 = 64 KB
constexpr int NB_H   = 128;            // histogram blocks (private slices)

// pad key: sorts AFTER every real key (real high32 = ~bits <= 0xFFFFFFFE).
constexpr uint64_t PADKEY = 0xFFFFFFFF00000000ull;

// ---------------- workspace layout (bytes) ----------------
constexpr size_t HIST_OFF  = 0;                                   // u32[32768] = 128 KB
constexpr size_t MISC_OFF  = 131072;                              // u32[64]
constexpr size_t MS_OFF    = 131328;                              // f32[NANCH]
constexpr size_t CAND_OFF  = MS_OFF + 4ull * NANCH;               // u64[8192]
// SLICES overlay cand..end: live only during k_score/k_reduce, dead after.
constexpr size_t SLICE_OFF = CAND_OFF;                            // u32[NB_H * NPAIR] = 8 MB
constexpr size_t SEL_OFF   = CAND_OFF + 8ull * CAND_CAP;          // u32[NPRE]
constexpr size_t SC3_OFF   = SEL_OFF + 4ull * NPRE;               // f32[NPRE*3]
constexpr size_t DSC_OFF   = SC3_OFF + 4ull * NPRE * 3;           // u32[NPRE]
constexpr size_t BB7_OFF   = DSC_OFF + 4ull * NPRE;               // f32[NPRE*7]
constexpr size_t BOX4_OFF  = BB7_OFF + 4ull * NPRE * 7;           // f32[NPRE*4]
constexpr size_t AREA_OFF  = BOX4_OFF + 4ull * NPRE * 4;          // f32[NPRE]
constexpr size_t ORD_OFF   = AREA_OFF + 4ull * NPRE;              // u32[3*NPRE]
constexpr size_t VW_OFF    = ORD_OFF + 4ull * 3 * NPRE;           // u64[3*64]
constexpr size_t PMASK_OFF = VW_OFF + 8ull * 3 * 64;              // u64[3*NPRE*64]  (6 MB)
constexpr size_t KEEPW_OFF = PMASK_OFF + 8ull * 3 * NPRE * 64;    // u64[3*64]

// ---------------- helpers ----------------
__device__ __forceinline__ float sigmoidf_(float x) { return 1.0f / (1.0f + expf(-x)); }

__device__ __forceinline__ uint64_t readlane64(uint64_t v, int lane) {
  uint32_t lo = (uint32_t)__builtin_amdgcn_readlane((int)(uint32_t)(v & 0xffffffffull), lane);
  uint32_t hi = (uint32_t)__builtin_amdgcn_readlane((int)(uint32_t)(v >> 32), lane);
  return (((uint64_t)hi) << 32) | (uint64_t)lo;
}

// lanes-with-equal-8-bit-digit mask (match-any via 8 ballots)
__device__ __forceinline__ uint64_t match_digit(uint32_t d) {
  uint64_t m = ~0ull;
#pragma unroll
  for (int b = 0; b < 8; ++b) {
    uint64_t bb = __ballot((d >> b) & 1u);
    m &= ((d >> b) & 1u) ? bb : ~bb;
  }
  return m;
}

// ---------------- stable LSD radix sort (LDS, used only by k_final) ---------
template <int N>
__device__ __forceinline__ void radix_pass_u64(const uint64_t* src, uint64_t* dst, int sh,
                                               uint32_t* hist, uint32_t* wscan) {
  constexpr int NW = 16, CH = N / NW, STEPS = CH / 64;
  const int t = threadIdx.x, w = t >> 6, ln = t & 63;
  const uint64_t ltmask = (1ull << ln) - 1ull;
  for (int i = t; i < NW * 256; i += 1024) hist[i] = 0;
  __syncthreads();
  for (int s = 0; s < STEPS; ++s) {
    uint32_t d = (uint32_t)(src[w * CH + s * 64 + ln] >> sh) & 0xFFu;
    uint64_t m = match_digit(d);
    if ((m & ltmask) == 0)
      atomicAdd(&hist[w * 256 + d], (uint32_t)__popcll(m));
  }
  __syncthreads();
  uint32_t v[4], sum = 0;
  const int base = t * 4;
#pragma unroll
  for (int q = 0; q < 4; ++q) {
    int idx = base + q;
    v[q] = hist[(idx & 15) * 256 + (idx >> 4)];
    sum += v[q];
  }
  uint32_t inc = sum;
#pragma unroll
  for (int dd = 1; dd < 64; dd <<= 1) { uint32_t u = __shfl_up(inc, dd, 64); if (ln >= dd) inc += u; }
  if (ln == 63) wscan[w] = inc;
  __syncthreads();
  uint32_t wbase = 0;
  for (int i = 0; i < w; ++i) wbase += wscan[i];
  uint32_t excl = wbase + inc - sum;
#pragma unroll
  for (int q = 0; q < 4; ++q) {
    int idx = base + q;
    hist[(idx & 15) * 256 + (idx >> 4)] = excl;
    excl += v[q];
  }
  __syncthreads();
  for (int s = 0; s < STEPS; ++s) {
    uint64_t key = src[w * CH + s * 64 + ln];
    uint32_t d = (uint32_t)(key >> sh) & 0xFFu;
    uint64_t m = match_digit(d);
    uint32_t mr = (uint32_t)__popcll(m & ltmask);
    int leader = (int)(__ffsll((unsigned long long)m) - 1);
    uint32_t b0 = 0;
    if (mr == 0) b0 = atomicAdd(&hist[w * 256 + d], (uint32_t)__popcll(m));
    b0 = __shfl(b0, leader, 64);
    dst[b0 + mr] = key;
  }
  __syncthreads();
}

template <int N>
__device__ __forceinline__ uint64_t* radix_sort_u64(uint64_t* bufA, uint64_t* bufB,
                                                    uint32_t* hist, uint32_t* wscan,
                                                    uint64_t* red /*LDS u64[32]*/) {
  const int t = threadIdx.x, w = t >> 6, ln = t & 63;
  uint64_t ov = 0, av = ~0ull;
  for (int i = t; i < N; i += 1024) { uint64_t k = bufA[i]; ov |= k; av &= k; }
#pragma unroll
  for (int dd = 1; dd < 64; dd <<= 1) { ov |= __shfl_xor(ov, dd, 64); av &= __shfl_xor(av, dd, 64); }
  if (ln == 0) { red[w] = ov; red[16 + w] = av; }
  __syncthreads();
  uint64_t o2 = 0, a2 = ~0ull;
  for (int i = 0; i < 16; ++i) { o2 |= red[i]; a2 &= red[16 + i]; }
  const uint64_t diff = o2 ^ a2;
  __syncthreads();
  uint64_t* src = bufA;
  uint64_t* dst = bufB;
  for (int p = 0; p < 8; ++p) {
    if (!((diff >> (8 * p)) & 0xFFull)) continue;
    radix_pass_u64<N>(src, dst, 8 * p, hist, wscan);
    uint64_t* tmp = src; src = dst; dst = tmp;
  }
  return src;
}

// ---------------- kernels ----------------

// 1) per-anchor max-of-3-sigmoids + PRIVATE per-block LDS histogram.
__global__ __launch_bounds__(256) void k_score(const float* __restrict__ cls,
                                               float* __restrict__ ms,
                                               uint32_t* __restrict__ slices) {
  __shared__ uint32_t h[NPAIR];  // 64 KB
  const int t = threadIdx.x, blk = blockIdx.x;
  for (int i = t; i < NPAIR; i += 256) h[i] = 0;
  __syncthreads();
  for (int p = blk * 256 + t; p < HWSZ; p += NB_H * 256) {
#pragma unroll
    for (int k = 0; k < 6; ++k) {
      float s0 = sigmoidf_(cls[(k * 3 + 0) * HWSZ + p]);
      float s1 = sigmoidf_(cls[(k * 3 + 1) * HWSZ + p]);
      float s2 = sigmoidf_(cls[(k * 3 + 2) * HWSZ + p]);
      float m = fmaxf(s0, fmaxf(s1, s2));
      ms[p * 6 + k] = m;
      uint32_t bin = __float_as_uint(m) >> 15;  // < 32768 (scores < 2.0)
      atomicAdd(&h[bin >> 1], 1u << ((bin & 1) * 16));  // LDS atomic only
    }
  }
  __syncthreads();
  uint32_t* myslice = slices + (size_t)blk * NPAIR;
  for (int i = t; i < NPAIR; i += 256) myslice[i] = h[i];
}

// 1b) column-reduce the NB_H slices into the u32 histogram
__global__ void k_reduce(const uint32_t* __restrict__ slices, uint32_t* __restrict__ hist) {
  int i = blockIdx.x * 256 + threadIdx.x;
  uint32_t lo = 0, hi = 0;
  for (int b = 0; b < NB_H; ++b) {
    uint32_t v = slices[(size_t)b * NPAIR + i];
    lo += v & 0xFFFFu;
    hi += v >> 16;
  }
  hist[2 * i]     = lo;
  hist[2 * i + 1] = hi;
}

// 2) find threshold bin B such that count(bin > B) < 4096 <= count(bin >= B)
__global__ void k_scanhist(const uint32_t* __restrict__ hist, uint32_t* __restrict__ misc) {
  __shared__ uint32_t part[256];
  __shared__ uint32_t suf[257];
  int t = threadIdx.x;
  int base = t * 128;
  uint32_t s = 0;
  for (int b = 0; b < 128; ++b) s += hist[base + b];
  part[t] = s;
  __syncthreads();
  if (t == 0) {
    uint32_t acc = 0;
    suf[256] = 0;
    for (int q = 255; q >= 0; --q) { suf[q] = acc + part[q]; acc = suf[q]; }
  }
  __syncthreads();
  uint32_t above = suf[t + 1];
  if (above < (uint32_t)NPRE && above + part[t] >= (uint32_t)NPRE) {
    uint32_t acc = above;
    for (int b = base + 127; b >= base; --b) {
      uint32_t h = hist[b];
      if (acc + h >= (uint32_t)NPRE) { misc[1] = (uint32_t)b; misc[2] = acc; break; }
      acc += h;
    }
  }
}

// 3) block-aggregated compaction: stage candidates in LDS, ONE global atomic
//    per block (314 total vs ~4700 per-wave RMWs -> kills the hot-address
//    serialization). Output order is block-batched/nondeterministic, which is
//    fine: k_rank's rank-by-count is order-independent and misc[0] is only a
//    count.
__global__ __launch_bounds__(256) void k_compact(const float* __restrict__ ms,
                                                 uint32_t* __restrict__ misc,
                                                 uint64_t* __restrict__ cand) {
  constexpr int APB = 4096;            // anchors per block
  __shared__ uint64_t lbuf[APB];       // 32 KB (cannot overflow: <= APB cands)
  __shared__ uint32_t lcnt, lbase;
  const int t = threadIdx.x;
  const int base = blockIdx.x * APB;
  if (t == 0) lcnt = 0;
  __syncthreads();
  const uint32_t B = misc[1];
#pragma unroll
  for (int q = 0; q < 16; ++q) {
    int a = base + q * 256 + t;        // coalesced
    if (a < NANCH) {
      uint32_t bits = __float_as_uint(ms[a]);
      if ((bits >> 15) >= B) {
        uint32_t s = atomicAdd(&lcnt, 1u);  // LDS atomic, ~15/block
        lbuf[s] = (((uint64_t)(~bits)) << 32) | (uint32_t)a;
      }
    }
  }
  __syncthreads();
  const uint32_t n = lcnt;
  if (t == 0 && n > 0) lbase = atomicAdd(&misc[0], n);  // one RMW per block
  __syncthreads();
  if (n > 0) {
    const uint32_t b0 = lbase;
    for (uint32_t i = t; i < n; i += 256) {
      uint32_t slot = b0 + i;
      if (slot < (uint32_t)CAND_CAP) cand[slot] = lbuf[i];
    }
  }
}

// 4) EXACT rank-by-count. Keys unique (embed anchor id) => rank = #{keys < k}
//    is the exact stable permutation; order-independent over cand[].
__global__ __launch_bounds__(256) void k_rank(const uint64_t* __restrict__ cand,
                                              const uint32_t* __restrict__ misc,
                                              uint32_t* __restrict__ sel) {
  const int tid = threadIdx.x, ln = tid & 63;
  const int wave = blockIdx.x * 4 + (tid >> 6);   // 0..511
  const int base = wave * 16;                     // row base, covers CAND_CAP
  uint32_t cnt = misc[0];
  if (cnt > (uint32_t)CAND_CAP) cnt = CAND_CAP;
  uint64_t kr[16];
#pragma unroll
  for (int r = 0; r < 16; ++r) kr[r] = cand[base + r];  // lane-uniform row keys
  uint32_t rnk[16];
#pragma unroll
  for (int r = 0; r < 16; ++r) rnk[r] = 0;
  const int nch = ((int)cnt + 63) >> 6;
  for (int ch = 0; ch < nch; ++ch) {
    uint64_t ck = cand[ch * 64 + ln];             // 64 comparison keys in lanes
    uint64_t vm = __ballot(ch * 64 + ln < (int)cnt);
#pragma unroll
    for (int r = 0; r < 16; ++r)
      rnk[r] += (uint32_t)__popcll(__ballot(ck < kr[r]) & vm);
  }
#pragma unroll
  for (int r = 0; r < 16; ++r) {
    int row = base + r;
    if (ln == 0 && row < (int)cnt && rnk[r] < (uint32_t)NPRE)
      sel[rnk[r]] = (uint32_t)kr[r];
  }
}

// 5) gather per-anchor data + decode boxes
__global__ void k_gather(const uint32_t* __restrict__ sel, const float* __restrict__ cls,
                         const float* __restrict__ bbp, const float* __restrict__ dirp,
                         const float* __restrict__ priors, float* __restrict__ sc3,
                         uint32_t* __restrict__ dsc, float* __restrict__ bb7,
                         float* __restrict__ box4, float* __restrict__ areaA) {
  int i = blockIdx.x * 256 + threadIdx.x;
  if (i >= NPRE) return;
  uint32_t a = sel[i];
  uint32_t p = a / 6u;
  uint32_t k = a - p * 6u;
#pragma unroll
  for (int c = 0; c < 3; ++c) sc3[i * 3 + c] = sigmoidf_(cls[(k * 3 + c) * HWSZ + p]);
  float d0 = dirp[(k * 2 + 0) * HWSZ + p];
  float d1 = dirp[(k * 2 + 1) * HWSZ + p];
  dsc[i] = (d1 > d0) ? 1u : 0u;
  float dt[7], pr[7];
#pragma unroll
  for (int q = 0; q < 7; ++q) dt[q] = bbp[(k * 7 + q) * HWSZ + p];
#pragma unroll
  for (int q = 0; q < 7; ++q) pr[q] = priors[(size_t)a * 7 + q];
  float za = pr[2] + pr[5] * 0.5f;
  float diag = sqrtf(pr[4] * pr[4] + pr[3] * pr[3]);
  float xg = dt[0] * diag + pr[0];
  float yg = dt[1] * diag + pr[1];
  float zg = dt[2] * pr[5] + za;
  float wg = expf(dt[3]) * pr[3];
  float lg = expf(dt[4]) * pr[4];
  float hg = expf(dt[5]) * pr[5];
  float rg = dt[6] + pr[6];
  zg = zg - hg * 0.5f;
  bb7[i * 7 + 0] = xg; bb7[i * 7 + 1] = yg; bb7[i * 7 + 2] = zg;
  bb7[i * 7 + 3] = wg; bb7[i * 7 + 4] = lg; bb7[i * 7 + 5] = hg; bb7[i * 7 + 6] = rg;
  float x1 = xg - wg * 0.5f, y1 = yg - lg * 0.5f;
  float x2 = xg + wg * 0.5f, y2 = yg + lg * 0.5f;
  box4[i * 4 + 0] = x1; box4[i * 4 + 1] = y1; box4[i * 4 + 2] = x2; box4[i * 4 + 3] = y2;
  areaA[i] = (x2 - x1 + 1.0f) * (y2 - y1 + 1.0f);
}

// 6) per-class EXACT rank-by-count on key (~score_bits<<32 | pos).
__global__ __launch_bounds__(256) void k_rankcls(const float* __restrict__ sc3,
                                                 uint32_t* __restrict__ ord) {
  const int tid = threadIdx.x, ln = tid & 63;
  const int c = blockIdx.y;
  const int wave = blockIdx.x * 4 + (tid >> 6);  // 0..255
  const int base = wave * 16;
  uint64_t kr[16];
#pragma unroll
  for (int r = 0; r < 16; ++r) {
    int j = base + r;
    kr[r] = (((uint64_t)(~__float_as_uint(sc3[j * 3 + c]))) << 32) | (uint32_t)j;
  }
  uint32_t rnk[16];
#pragma unroll
  for (int r = 0; r < 16; ++r) rnk[r] = 0;
  for (int ch = 0; ch < NPRE / 64; ++ch) {
    int j = ch * 64 + ln;
    uint64_t ck = (((uint64_t)(~__float_as_uint(sc3[j * 3 + c]))) << 32) | (uint32_t)j;
#pragma unroll
    for (int r = 0; r < 16; ++r)
      rnk[r] += (uint32_t)__popcll(__ballot(ck < kr[r]));
  }
#pragma unroll
  for (int r = 0; r < 16; ++r)
    if (ln == 0) ord[c * NPRE + rnk[r]] = (uint32_t)(base + r);
}

// 6b) valid bitset in sorted space
__global__ __launch_bounds__(1024) void k_vwords(const uint32_t* __restrict__ ord,
                                                 const float* __restrict__ sc3,
                                                 uint64_t* __restrict__ vwords) {
  int c = blockIdx.x, t = threadIdx.x, ln = t & 63;
  for (int k = 0; k < 4; ++k) {
    int i = k * 1024 + t;
    uint32_t pos = ord[c * NPRE + i];
    uint64_t m = __ballot(sc3[pos * 3 + c] > SCORE_THR_F);
    if (ln == 0) vwords[c * 64 + (i >> 6)] = m;
  }
}

// 7) suppression bitmask in per-class sorted order; UPPER TRIANGLE ONLY.
__global__ void k_mask(const uint32_t* __restrict__ ord, const float* __restrict__ box4,
                       const float* __restrict__ areaA, uint64_t* __restrict__ pmask) {
  int c = blockIdx.z, it = blockIdx.y, jt = blockIdx.x, t = threadIdx.x;
  if (jt < it) return;
  __shared__ float jx1[64], jy1[64], jx2[64], jy2[64], jar[64];
  int j = ord[c * NPRE + jt * 64 + t];
  jx1[t] = box4[j * 4 + 0]; jy1[t] = box4[j * 4 + 1];
  jx2[t] = box4[j * 4 + 2]; jy2[t] = box4[j * 4 + 3];
  jar[t] = areaA[j];
  __syncthreads();
  int I = it * 64 + t;
  int i = ord[c * NPRE + I];
  float x1 = box4[i * 4 + 0], y1 = box4[i * 4 + 1];
  float x2 = box4[i * 4 + 2], y2 = box4[i * 4 + 3];
  float ar = areaA[i];
  uint64_t bits = 0;
  for (int b = 0; b < 64; ++b) {
    float xx1 = fmaxf(x1, jx1[b]), yy1 = fmaxf(y1, jy1[b]);
    float xx2 = fminf(x2, jx2[b]), yy2 = fminf(y2, jy2[b]);
    float iw = fmaxf(0.0f, xx2 - xx1 + 1.0f);
    float ih = fmaxf(0.0f, yy2 - yy1 + 1.0f);
    float inter = iw * ih;
    float iou = inter / (ar + jar[b] - inter);
    bits |= ((uint64_t)(iou > 0.5f)) << b;
  }
  pmask[((size_t)(c * NPRE + I)) * 64 + (size_t)jt] = bits;
}

// 8) tiled serial greedy NMS cascade with EARLY EXIT at 500 keeps.
__global__ __launch_bounds__(320) void k_nms(const uint64_t* __restrict__ pmask,
                                             const uint64_t* __restrict__ vwords,
                                             uint64_t* __restrict__ keepw) {
  __shared__ uint64_t tile[2][64 * 64];  // 2 x 32 KB
  __shared__ int s_stop[2];
  const int c = blockIdx.x;
  const int tid = threadIdx.x;
  const int wv = tid >> 6;
  const int ln = tid & 63;
  const uint64_t* pm = pmask + (size_t)c * NPRE * 64;

  if (tid == 0) { s_stop[0] = 0; s_stop[1] = 0; }
  if (wv > 0) {
    int l = tid - 64;
    const ulonglong2* src2 = (const ulonglong2*)pm;
    ulonglong2* dst2 = (ulonglong2*)tile[0];
#pragma unroll
    for (int q = 0; q < 8; ++q) dst2[q * 256 + l] = src2[q * 256 + l];
  }
  __syncthreads();

  uint64_t avail = 0, keepbits = 0;
  int cnt = 0;
  if (wv == 0) avail = vwords[c * 64 + ln];

  for (int T = 0; T < 64; ++T) {
    const int cb = T & 1;
    if (wv > 0) {
      if (T + 1 < 64) {
        int l = tid - 64;
        const ulonglong2* src2 = (const ulonglong2*)(pm + (size_t)(T + 1) * 64 * 64);
        ulonglong2* dst2 = (ulonglong2*)tile[cb ^ 1];
#pragma unroll
        for (int q = 0; q < 8; ++q) dst2[q * 256 + l] = src2[q * 256 + l];
      }
    } else {
      const uint64_t* tp = tile[cb];
      uint64_t awT = readlane64(avail, T);
      uint64_t pf[8];
#pragma unroll
      for (int u = 0; u < 8; ++u) pf[u] = tp[u * 64 + ln];
      uint64_t kwT = 0;
#pragma unroll
      for (int r = 0; r < 64; ++r) {
        uint64_t cur = pf[r & 7];
        if (r + 8 < 64) pf[r & 7] = tp[(r + 8) * 64 + ln];
        bool kp = ((awT >> r) & 1ull) != 0ull;
        if (kp) {
          avail &= ~cur;
          awT &= ~readlane64(cur, T);
          kwT |= (1ull << r);
        }
      }
      if (ln == T) keepbits = kwT;
      cnt += (int)__popcll(kwT);
      if (ln == 0 && cnt >= MAXNUM) s_stop[cb] = 1;
    }
    __syncthreads();
    if (s_stop[cb]) break;
  }
  if (wv == 0) keepw[c * 64 + ln] = keepbits;
}

// 9) fused: per-class stable-compact first <=500 kept, LDS radix-sort the
//    <=1500 union, emit top-500 boxes/scores/labels. One block, 52 KB LDS.
__global__ __launch_bounds__(1024) void k_final(const uint64_t* __restrict__ keepw,
                                                const uint32_t* __restrict__ ord,
                                                const float* __restrict__ sc3,
                                                const float* __restrict__ bb7,
                                                const uint32_t* __restrict__ dsc,
                                                float* __restrict__ out) {
  __shared__ uint64_t bufA[2048];       // 16 KB
  __shared__ uint64_t bufB[2048];       // 16 KB
  __shared__ uint32_t hist[16 * 256];   // 16 KB
  __shared__ uint32_t wscan[16];
  __shared__ uint64_t red[32];
  __shared__ uint32_t ps[1024];         // 4 KB
  int t = threadIdx.x;
  for (int i = t; i < 2048; i += 1024) bufA[i] = PADKEY;
  __syncthreads();
  for (int c = 0; c < 3; ++c) {
    uint32_t bits4 = 0;
#pragma unroll
    for (int q = 0; q < 4; ++q) {
      int i = t * 4 + q;
      uint32_t b = (uint32_t)((keepw[c * 64 + (i >> 6)] >> (i & 63)) & 1ull);
      bits4 |= b << q;
    }
    uint32_t cnt = __popc(bits4);
    ps[t] = cnt;
    __syncthreads();
    for (int off = 1; off < 1024; off <<= 1) {
      uint32_t v = (t >= off) ? ps[t - off] : 0;
      __syncthreads();
      ps[t] += v;
      __syncthreads();
    }
    uint32_t r = ps[t] - cnt;
#pragma unroll
    for (int q = 0; q < 4; ++q) {
      if ((bits4 >> q) & 1u) {
        if (r < (uint32_t)MAXNUM) {
          uint32_t pos = ord[c * NPRE + t * 4 + q];
          uint32_t sb = __float_as_uint(sc3[pos * 3 + c]);
          bufA[c * MAXNUM + r] = (((uint64_t)(~sb)) << 32) | (uint32_t)(c * NPRE + pos);
        }
        ++r;
      }
    }
    __syncthreads();
  }
  uint64_t* sorted = radix_sort_u64<2048>(bufA, bufB, hist, wscan, red);
  if (t < MAXNUM) {
    uint64_t key = sorted[t];
    if ((uint32_t)(key >> 32) != 0xFFFFFFFFu) {
      uint32_t flat = (uint32_t)key;
      float score = __uint_as_float(~((uint32_t)(key >> 32)));
      int cc = (int)(flat >> 12);
      int pos = (int)(flat & 4095u);
      const float* b = bb7 + (size_t)pos * 7;
      float r = b[6];
      float dir_rot = r + HPIF - floorf(r + 0.5f) * PIF;
      float rr = dir_rot - HPIF + PIF * (float)dsc[pos];
#pragma unroll
      for (int q = 0; q < 6; ++q) out[t * 7 + q] = b[q];
      out[t * 7 + 6] = rr;
      out[7 * MAXNUM + t] = score;
      out[8 * MAXNUM + t] = (float)cc;
    } else {
#pragma unroll
      for (int q = 0; q < 7; ++q) out[t * 7 + q] = 0.0f;
      out[7 * MAXNUM + t] = 0.0f;
      out[8 * MAXNUM + t] = -1.0f;
    }
  }
}

// ---------------- launcher ----------------
extern "C" void kernel_launch(void* const* d_in, const int* in_sizes, int n_in,
                              void* d_out, int out_size, void* d_ws, size_t ws_size,
                              hipStream_t stream) {
  (void)in_sizes; (void)n_in; (void)out_size; (void)ws_size;
  const float* cls    = (const float*)d_in[0];
  const float* bbp    = (const float*)d_in[1];
  const float* dirp   = (const float*)d_in[2];
  const float* priors = (const float*)d_in[3];
  char* ws = (char*)d_ws;

  uint32_t* hist   = (uint32_t*)(ws + HIST_OFF);
  uint32_t* misc   = (uint32_t*)(ws + MISC_OFF);
  float*    ms     = (float*)(ws + MS_OFF);
  uint32_t* slices = (uint32_t*)(ws + SLICE_OFF);
  uint64_t* cand   = (uint64_t*)(ws + CAND_OFF);
  uint32_t* sel    = (uint32_t*)(ws + SEL_OFF);
  float*    sc3    = (float*)(ws + SC3_OFF);
  uint32_t* dsc    = (uint32_t*)(ws + DSC_OFF);
  float*    bb7    = (float*)(ws + BB7_OFF);
  float*    box4   = (float*)(ws + BOX4_OFF);
  float*    areaA  = (float*)(ws + AREA_OFF);
  uint32_t* ord    = (uint32_t*)(ws + ORD_OFF);
  uint64_t* vwords = (uint64_t*)(ws + VW_OFF);
  uint64_t* pmask  = (uint64_t*)(ws + PMASK_OFF);
  uint64_t* keepw  = (uint64_t*)(ws + KEEPW_OFF);

  hipMemsetAsync(misc, 0, 256, stream);
  k_score<<<NB_H, 256, 0, stream>>>(cls, ms, slices);
  k_reduce<<<NPAIR / 256, 256, 0, stream>>>(slices, hist);
  k_scanhist<<<1, 256, 0, stream>>>(hist, misc);
  k_compact<<<(NANCH + 4095) / 4096, 256, 0, stream>>>(ms, misc, cand);
  k_rank<<<CAND_CAP / (4 * 16), 256, 0, stream>>>(cand, misc, sel);
  k_gather<<<NPRE / 256, 256, 0, stream>>>(sel, cls, bbp, dirp, priors, sc3, dsc, bb7, box4, areaA);
  k_rankcls<<<dim3(NPRE / (4 * 16), 3), 256, 0, stream>>>(sc3, ord);
  k_vwords<<<3, 1024, 0, stream>>>(ord, sc3, vwords);
  k_mask<<<dim3(64, 64, 3), 64, 0, stream>>>(ord, box4, areaA, pmask);
  k_nms<<<3, 320, 0, stream>>>(pmask, vwords, keepw);
  k_final<<<1, 1024, 0, stream>>>(keepw, ord, sc3, bb7, dsc, (float*)d_out);
}

// Round 10
// 295.284 us; speedup vs baseline: 7.9623x; 1.0722x over previous
//
#include <hip/hip_runtime.h>
#include <stdint.h>
#include <stddef.h>

// ---------------- problem constants ----------------
constexpr int kH = 496, kW = 432;
constexpr int HWSZ = kH * kW;          // 214272
constexpr int NANCH = HWSZ * 6;        // 1285632 anchors
constexpr int NPRE = 4096;             // nms_pre
constexpr int MAXNUM = 500;
constexpr int CAND_CAP = 8192;
constexpr float SCORE_THR_F = 0.1f;
constexpr float PIF  = 3.14159265358979323846f;  // rounds to f32 pi
constexpr float HPIF = 1.57079632679489661923f;  // rounds to f32 pi/2

// histogram: bin = float_bits >> 15; sigmoids < 2.0 -> bin < 32768.
constexpr int NBINS  = 32768;
constexpr int NPAIR  = NBINS / 2;      // packed u16 pairs = 16384 u32 = 64 KB
constexpr int NB_H   = 256;            // histogram blocks (private slices)

// pad key: sorts AFTER every real key (real high32 = ~bits <= 0xFFFFFFFE).
constexpr uint64_t PADKEY = 0xFFFFFFFF00000000ull;

// ---------------- workspace layout (bytes) ----------------
constexpr size_t HIST_OFF  = 0;                                   // u32[32768] = 128 KB
constexpr size_t MISC_OFF  = 131072;                              // u32[64]: 0=cand_cnt 1=binB 2=above 8..10=Vc
constexpr size_t MS_OFF    = 131328;                              // f32[NANCH]
constexpr size_t CAND_OFF  = MS_OFF + 4ull * NANCH;               // u64[8192]
// SLICES overlay everything after cand: live only during k_score/k_reduce.
constexpr size_t SLICE_OFF = CAND_OFF;                            // u32[NB_H*NPAIR] = 16 MB
constexpr size_t SEL_OFF   = CAND_OFF + 8ull * CAND_CAP;          // u32[NPRE]
constexpr size_t SC3_OFF   = SEL_OFF + 4ull * NPRE;               // f32[NPRE*3]
constexpr size_t DSC_OFF   = SC3_OFF + 4ull * NPRE * 3;           // u32[NPRE]
constexpr size_t BB7_OFF   = DSC_OFF + 4ull * NPRE;               // f32[NPRE*7]
constexpr size_t BOX4_OFF  = BB7_OFF + 4ull * NPRE * 7;           // f32[NPRE*4]
constexpr size_t AREA_OFF  = BOX4_OFF + 4ull * NPRE * 4;          // f32[NPRE]
constexpr size_t ORD_OFF   = AREA_OFF + 4ull * NPRE;              // u32[3*NPRE]
constexpr size_t VW_OFF    = ORD_OFF + 4ull * 3 * NPRE;           // u64[3*64]
constexpr size_t PMASK_OFF = VW_OFF + 8ull * 3 * 64;              // u64[3*NPRE*64]  (6 MB)
constexpr size_t KEEPW_OFF = PMASK_OFF + 8ull * 3 * NPRE * 64;    // u64[3*64]
constexpr size_t OUTK_OFF  = KEEPW_OFF + 8ull * 3 * 64;           // u64[2048]

// ---------------- helpers ----------------
__device__ __forceinline__ float sigmoidf_(float x) { return 1.0f / (1.0f + expf(-x)); }

__device__ __forceinline__ uint64_t readlane64(uint64_t v, int lane) {
  uint32_t lo = (uint32_t)__builtin_amdgcn_readlane((int)(uint32_t)(v & 0xffffffffull), lane);
  uint32_t hi = (uint32_t)__builtin_amdgcn_readlane((int)(uint32_t)(v >> 32), lane);
  return (((uint64_t)hi) << 32) | (uint64_t)lo;
}

// ---------------- kernels ----------------

// 1) per-anchor max-of-3-sigmoids + PRIVATE per-block LDS histogram.
__global__ __launch_bounds__(256) void k_score(const float* __restrict__ cls,
                                               float* __restrict__ ms,
                                               uint32_t* __restrict__ slices) {
  __shared__ uint32_t h[NPAIR];  // 64 KB
  const int t = threadIdx.x, blk = blockIdx.x;
  for (int i = t; i < NPAIR; i += 256) h[i] = 0;
  __syncthreads();
  for (int p = blk * 256 + t; p < HWSZ; p += NB_H * 256) {
#pragma unroll
    for (int k = 0; k < 6; ++k) {
      float s0 = sigmoidf_(cls[(k * 3 + 0) * HWSZ + p]);
      float s1 = sigmoidf_(cls[(k * 3 + 1) * HWSZ + p]);
      float s2 = sigmoidf_(cls[(k * 3 + 2) * HWSZ + p]);
      float m = fmaxf(s0, fmaxf(s1, s2));
      ms[p * 6 + k] = m;
      uint32_t bin = __float_as_uint(m) >> 15;  // < 32768 (scores < 2.0)
      atomicAdd(&h[bin >> 1], 1u << ((bin & 1) * 16));  // LDS atomic only
    }
  }
  __syncthreads();
  uint32_t* myslice = slices + (size_t)blk * NPAIR;
  for (int i = t; i < NPAIR; i += 256) myslice[i] = h[i];
}

// 1b) column-reduce the NB_H slices into the u32 histogram
__global__ void k_reduce(const uint32_t* __restrict__ slices, uint32_t* __restrict__ hist) {
  int i = blockIdx.x * 256 + threadIdx.x;  // pair index, grid covers NPAIR
  uint32_t lo = 0, hi = 0;
  for (int b = 0; b < NB_H; ++b) {
    uint32_t v = slices[(size_t)b * NPAIR + i];
    lo += v & 0xFFFFu;
    hi += v >> 16;
  }
  hist[2 * i]     = lo;
  hist[2 * i + 1] = hi;
}

// 2) find threshold bin B such that count(bin > B) < 4096 <= count(bin >= B)
__global__ void k_scanhist(const uint32_t* __restrict__ hist, uint32_t* __restrict__ misc) {
  __shared__ uint32_t part[256];
  __shared__ uint32_t suf[257];
  int t = threadIdx.x;
  int base = t * 128;
  uint32_t s = 0;
  for (int b = 0; b < 128; ++b) s += hist[base + b];
  part[t] = s;
  __syncthreads();
  if (t == 0) {
    uint32_t acc = 0;
    suf[256] = 0;
    for (int q = 255; q >= 0; --q) { suf[q] = acc + part[q]; acc = suf[q]; }
  }
  __syncthreads();
  uint32_t above = suf[t + 1];
  if (above < (uint32_t)NPRE && above + part[t] >= (uint32_t)NPRE) {
    uint32_t acc = above;
    for (int b = base + 127; b >= base; --b) {
      uint32_t h = hist[b];
      if (acc + h >= (uint32_t)NPRE) { misc[1] = (uint32_t)b; misc[2] = acc; break; }
      acc += h;
    }
  }
}

// 3) block-aggregated compaction: LDS staging, ONE global atomic per block.
__global__ __launch_bounds__(256) void k_compact(const float* __restrict__ ms,
                                                 uint32_t* __restrict__ misc,
                                                 uint64_t* __restrict__ cand) {
  constexpr int APB = 4096;
  __shared__ uint64_t lbuf[APB];       // 32 KB
  __shared__ uint32_t lcnt, lbase;
  const int t = threadIdx.x;
  const int base = blockIdx.x * APB;
  if (t == 0) lcnt = 0;
  __syncthreads();
  const uint32_t B = misc[1];
#pragma unroll
  for (int q = 0; q < 16; ++q) {
    int a = base + q * 256 + t;        // coalesced
    if (a < NANCH) {
      uint32_t bits = __float_as_uint(ms[a]);
      if ((bits >> 15) >= B) {
        uint32_t s = atomicAdd(&lcnt, 1u);  // LDS atomic, ~15/block
        lbuf[s] = (((uint64_t)(~bits)) << 32) | (uint32_t)a;
      }
    }
  }
  __syncthreads();
  const uint32_t n = lcnt;
  if (t == 0 && n > 0) lbase = atomicAdd(&misc[0], n);  // one RMW per block
  __syncthreads();
  if (n > 0) {
    const uint32_t b0 = lbase;
    for (uint32_t i = t; i < n; i += 256) {
      uint32_t slot = b0 + i;
      if (slot < (uint32_t)CAND_CAP) cand[slot] = lbuf[i];
    }
  }
}

// 4) EXACT rank-by-count (order-independent over cand[]; keys unique).
__global__ __launch_bounds__(256) void k_rank(const uint64_t* __restrict__ cand,
                                              const uint32_t* __restrict__ misc,
                                              uint32_t* __restrict__ sel) {
  const int tid = threadIdx.x, ln = tid & 63;
  const int wave = blockIdx.x * 4 + (tid >> 6);   // 0..511
  const int base = wave * 16;
  uint32_t cnt = misc[0];
  if (cnt > (uint32_t)CAND_CAP) cnt = CAND_CAP;
  uint64_t kr[16];
#pragma unroll
  for (int r = 0; r < 16; ++r) kr[r] = cand[base + r];
  uint32_t rnk[16];
#pragma unroll
  for (int r = 0; r < 16; ++r) rnk[r] = 0;
  const int nch = ((int)cnt + 63) >> 6;
  for (int ch = 0; ch < nch; ++ch) {
    uint64_t ck = cand[ch * 64 + ln];
    uint64_t vm = __ballot(ch * 64 + ln < (int)cnt);
#pragma unroll
    for (int r = 0; r < 16; ++r)
      rnk[r] += (uint32_t)__popcll(__ballot(ck < kr[r]) & vm);
  }
#pragma unroll
  for (int r = 0; r < 16; ++r) {
    int row = base + r;
    if (ln == 0 && row < (int)cnt && rnk[r] < (uint32_t)NPRE)
      sel[rnk[r]] = (uint32_t)kr[r];
  }
}

// 5) gather per-anchor data + decode boxes
__global__ void k_gather(const uint32_t* __restrict__ sel, const float* __restrict__ cls,
                         const float* __restrict__ bbp, const float* __restrict__ dirp,
                         const float* __restrict__ priors, float* __restrict__ sc3,
                         uint32_t* __restrict__ dsc, float* __restrict__ bb7,
                         float* __restrict__ box4, float* __restrict__ areaA) {
  int i = blockIdx.x * 256 + threadIdx.x;
  if (i >= NPRE) return;
  uint32_t a = sel[i];
  uint32_t p = a / 6u;
  uint32_t k = a - p * 6u;
#pragma unroll
  for (int c = 0; c < 3; ++c) sc3[i * 3 + c] = sigmoidf_(cls[(k * 3 + c) * HWSZ + p]);
  float d0 = dirp[(k * 2 + 0) * HWSZ + p];
  float d1 = dirp[(k * 2 + 1) * HWSZ + p];
  dsc[i] = (d1 > d0) ? 1u : 0u;
  float dt[7], pr[7];
#pragma unroll
  for (int q = 0; q < 7; ++q) dt[q] = bbp[(k * 7 + q) * HWSZ + p];
#pragma unroll
  for (int q = 0; q < 7; ++q) pr[q] = priors[(size_t)a * 7 + q];
  float za = pr[2] + pr[5] * 0.5f;
  float diag = sqrtf(pr[4] * pr[4] + pr[3] * pr[3]);
  float xg = dt[0] * diag + pr[0];
  float yg = dt[1] * diag + pr[1];
  float zg = dt[2] * pr[5] + za;
  float wg = expf(dt[3]) * pr[3];
  float lg = expf(dt[4]) * pr[4];
  float hg = expf(dt[5]) * pr[5];
  float rg = dt[6] + pr[6];
  zg = zg - hg * 0.5f;
  bb7[i * 7 + 0] = xg; bb7[i * 7 + 1] = yg; bb7[i * 7 + 2] = zg;
  bb7[i * 7 + 3] = wg; bb7[i * 7 + 4] = lg; bb7[i * 7 + 5] = hg; bb7[i * 7 + 6] = rg;
  float x1 = xg - wg * 0.5f, y1 = yg - lg * 0.5f;
  float x2 = xg + wg * 0.5f, y2 = yg + lg * 0.5f;
  box4[i * 4 + 0] = x1; box4[i * 4 + 1] = y1; box4[i * 4 + 2] = x2; box4[i * 4 + 3] = y2;
  areaA[i] = (x2 - x1 + 1.0f) * (y2 - y1 + 1.0f);
}

// 6) per-class EXACT rank-by-count on key (~score_bits<<32 | pos).
__global__ __launch_bounds__(256) void k_rankcls(const float* __restrict__ sc3,
                                                 uint32_t* __restrict__ ord) {
  const int tid = threadIdx.x, ln = tid & 63;
  const int c = blockIdx.y;
  const int wave = blockIdx.x * 4 + (tid >> 6);  // 0..255
  const int base = wave * 16;
  uint64_t kr[16];
#pragma unroll
  for (int r = 0; r < 16; ++r) {
    int j = base + r;
    kr[r] = (((uint64_t)(~__float_as_uint(sc3[j * 3 + c]))) << 32) | (uint32_t)j;
  }
  uint32_t rnk[16];
#pragma unroll
  for (int r = 0; r < 16; ++r) rnk[r] = 0;
  for (int ch = 0; ch < NPRE / 64; ++ch) {
    int j = ch * 64 + ln;
    uint64_t ck = (((uint64_t)(~__float_as_uint(sc3[j * 3 + c]))) << 32) | (uint32_t)j;
#pragma unroll
    for (int r = 0; r < 16; ++r)
      rnk[r] += (uint32_t)__popcll(__ballot(ck < kr[r]));
  }
#pragma unroll
  for (int r = 0; r < 16; ++r)
    if (ln == 0) ord[c * NPRE + rnk[r]] = (uint32_t)(base + r);
}

// 6b) valid bitset in sorted space
__global__ __launch_bounds__(1024) void k_vwords(const uint32_t* __restrict__ ord,
                                                 const float* __restrict__ sc3,
                                                 uint64_t* __restrict__ vwords) {
  int c = blockIdx.x, t = threadIdx.x, ln = t & 63;
  for (int k = 0; k < 4; ++k) {
    int i = k * 1024 + t;
    uint32_t pos = ord[c * NPRE + i];
    uint64_t m = __ballot(sc3[pos * 3 + c] > SCORE_THR_F);
    if (ln == 0) vwords[c * 64 + (i >> 6)] = m;
  }
}

// 7) suppression bitmask in per-class sorted order; UPPER TRIANGLE ONLY.
__global__ void k_mask(const uint32_t* __restrict__ ord, const float* __restrict__ box4,
                       const float* __restrict__ areaA, uint64_t* __restrict__ pmask) {
  int c = blockIdx.z, it = blockIdx.y, jt = blockIdx.x, t = threadIdx.x;
  if (jt < it) return;
  __shared__ float jx1[64], jy1[64], jx2[64], jy2[64], jar[64];
  int j = ord[c * NPRE + jt * 64 + t];
  jx1[t] = box4[j * 4 + 0]; jy1[t] = box4[j * 4 + 1];
  jx2[t] = box4[j * 4 + 2]; jy2[t] = box4[j * 4 + 3];
  jar[t] = areaA[j];
  __syncthreads();
  int I = it * 64 + t;
  int i = ord[c * NPRE + I];
  float x1 = box4[i * 4 + 0], y1 = box4[i * 4 + 1];
  float x2 = box4[i * 4 + 2], y2 = box4[i * 4 + 3];
  float ar = areaA[i];
  uint64_t bits = 0;
  for (int b = 0; b < 64; ++b) {
    float xx1 = fmaxf(x1, jx1[b]), yy1 = fmaxf(y1, jy1[b]);
    float xx2 = fminf(x2, jx2[b]), yy2 = fminf(y2, jy2[b]);
    float iw = fmaxf(0.0f, xx2 - xx1 + 1.0f);
    float ih = fmaxf(0.0f, yy2 - yy1 + 1.0f);
    float inter = iw * ih;
    float iou = inter / (ar + jar[b] - inter);
    bits |= ((uint64_t)(iou > 0.5f)) << b;
  }
  pmask[((size_t)(c * NPRE + I)) * 64 + (size_t)jt] = bits;
}

// 8) tiled serial greedy NMS cascade with EARLY EXIT at 500 keeps.
__global__ __launch_bounds__(320) void k_nms(const uint64_t* __restrict__ pmask,
                                             const uint64_t* __restrict__ vwords,
                                             uint64_t* __restrict__ keepw) {
  __shared__ uint64_t tile[2][64 * 64];  // 2 x 32 KB
  __shared__ int s_stop[2];
  const int c = blockIdx.x;
  const int tid = threadIdx.x;
  const int wv = tid >> 6;
  const int ln = tid & 63;
  const uint64_t* pm = pmask + (size_t)c * NPRE * 64;

  if (tid == 0) { s_stop[0] = 0; s_stop[1] = 0; }
  if (wv > 0) {
    int l = tid - 64;
    const ulonglong2* src2 = (const ulonglong2*)pm;
    ulonglong2* dst2 = (ulonglong2*)tile[0];
#pragma unroll
    for (int q = 0; q < 8; ++q) dst2[q * 256 + l] = src2[q * 256 + l];
  }
  __syncthreads();

  uint64_t avail = 0, keepbits = 0;
  int cnt = 0;
  if (wv == 0) avail = vwords[c * 64 + ln];

  for (int T = 0; T < 64; ++T) {
    const int cb = T & 1;
    if (wv > 0) {
      if (T + 1 < 64) {
        int l = tid - 64;
        const ulonglong2* src2 = (const ulonglong2*)(pm + (size_t)(T + 1) * 64 * 64);
        ulonglong2* dst2 = (ulonglong2*)tile[cb ^ 1];
#pragma unroll
        for (int q = 0; q < 8; ++q) dst2[q * 256 + l] = src2[q * 256 + l];
      }
    } else {
      const uint64_t* tp = tile[cb];
      uint64_t awT = readlane64(avail, T);
      uint64_t pf[8];
#pragma unroll
      for (int u = 0; u < 8; ++u) pf[u] = tp[u * 64 + ln];
      uint64_t kwT = 0;
#pragma unroll
      for (int r = 0; r < 64; ++r) {
        uint64_t cur = pf[r & 7];
        if (r + 8 < 64) pf[r & 7] = tp[(r + 8) * 64 + ln];
        bool kp = ((awT >> r) & 1ull) != 0ull;
        if (kp) {
          avail &= ~cur;
          awT &= ~readlane64(cur, T);
          kwT |= (1ull << r);
        }
      }
      if (ln == T) keepbits = kwT;
      cnt += (int)__popcll(kwT);
      if (ln == 0 && cnt >= MAXNUM) s_stop[cb] = 1;
    }
    __syncthreads();
    if (s_stop[cb]) break;
  }
  if (wv == 0) keepw[c * 64 + ln] = keepbits;
}

// 9) per-class stable-compact first <=500 kept keys into outk[2048] (padded).
//    Blocks 0..2 = classes; block 3 pads the tail [1500,2048).
__global__ __launch_bounds__(1024) void k_collect(const uint64_t* __restrict__ keepw,
                                                  const uint32_t* __restrict__ ord,
                                                  const float* __restrict__ sc3,
                                                  uint64_t* __restrict__ outk,
                                                  uint32_t* __restrict__ misc) {
  const int c = blockIdx.x, t = threadIdx.x, w = t >> 6, ln = t & 63;
  if (c == 3) {  // tail pad
    int i = 3 * MAXNUM + t;
    if (i < 2048) outk[i] = PADKEY;
    return;
  }
  __shared__ uint32_t wsum[16];
  uint32_t bits4 = 0;
#pragma unroll
  for (int q = 0; q < 4; ++q) {
    int i = t * 4 + q;
    uint32_t b = (uint32_t)((keepw[c * 64 + (i >> 6)] >> (i & 63)) & 1ull);
    bits4 |= b << q;
  }
  uint32_t cnt = __popc(bits4);
  uint32_t incl = cnt;
#pragma unroll
  for (int d = 1; d < 64; d <<= 1) { uint32_t u = __shfl_up(incl, d, 64); if (ln >= d) incl += u; }
  if (ln == 63) wsum[w] = incl;
  __syncthreads();
  uint32_t wb = 0, total = 0;
#pragma unroll
  for (int i = 0; i < 16; ++i) { uint32_t v = wsum[i]; total += v; if (i < w) wb += v; }
  uint32_t r = wb + incl - cnt;  // exclusive prefix
#pragma unroll
  for (int q = 0; q < 4; ++q) {
    if ((bits4 >> q) & 1u) {
      if (r < (uint32_t)MAXNUM) {
        uint32_t pos = ord[c * NPRE + t * 4 + q];
        uint32_t sb = __float_as_uint(sc3[pos * 3 + c]);
        outk[c * MAXNUM + r] = (((uint64_t)(~sb)) << 32) | (uint32_t)(c * NPRE + pos);
      }
      ++r;
    }
  }
  uint32_t Vc = total < (uint32_t)MAXNUM ? total : (uint32_t)MAXNUM;
  if (t == 0) misc[8 + c] = Vc;
  // pad slots [Vc, 500) of this class (disjoint from scatter writes above)
  for (uint32_t s = Vc + t; s < (uint32_t)MAXNUM; s += 1024)
    outk[c * MAXNUM + s] = PADKEY;
}

// 10) rank the full 2048-key union (32 blocks x 4 waves x 16 rows = 2048
//     rows — MUST cover all keys); emit rank<500; zero-fill [V,500).
__global__ __launch_bounds__(256) void k_emit(const uint64_t* __restrict__ outk,
                                              const uint32_t* __restrict__ misc,
                                              const float* __restrict__ bb7,
                                              const uint32_t* __restrict__ dsc,
                                              float* __restrict__ out) {
  const int tid = threadIdx.x, ln = tid & 63;
  const int wave = blockIdx.x * 4 + (tid >> 6);  // 0..127
  const int base = wave * 16;                    // rows 0..2047
  uint64_t kr[16];
#pragma unroll
  for (int r = 0; r < 16; ++r) kr[r] = outk[base + r];
  uint32_t rnk[16];
#pragma unroll
  for (int r = 0; r < 16; ++r) rnk[r] = 0;
  for (int ch = 0; ch < 2048 / 64; ++ch) {
    uint64_t ck = outk[ch * 64 + ln];
#pragma unroll
    for (int r = 0; r < 16; ++r)
      rnk[r] += (uint32_t)__popcll(__ballot(ck < kr[r]));
  }
  if (ln == 0) {
#pragma unroll
    for (int r = 0; r < 16; ++r) {
      uint64_t key = kr[r];
      uint32_t rk = rnk[r];
      if (key != PADKEY && rk < (uint32_t)MAXNUM) {
        uint32_t flat = (uint32_t)key;
        float score = __uint_as_float(~((uint32_t)(key >> 32)));
        int cc = (int)(flat >> 12);
        int pos = (int)(flat & 4095u);
        const float* b = bb7 + (size_t)pos * 7;
        float rr0 = b[6];
        float dir_rot = rr0 + HPIF - floorf(rr0 + 0.5f) * PIF;
        float rr = dir_rot - HPIF + PIF * (float)dsc[pos];
#pragma unroll
        for (int q = 0; q < 6; ++q) out[rk * 7 + q] = b[q];
        out[rk * 7 + 6] = rr;
        out[7 * MAXNUM + rk] = score;
        out[8 * MAXNUM + rk] = (float)cc;
      }
    }
  }
  // zero-fill invalid slots [V, 500) (block 0 only; disjoint from emits)
  if (blockIdx.x == 0) {
    uint32_t V = misc[8] + misc[9] + misc[10];
    for (uint32_t s = V + tid; s < (uint32_t)MAXNUM; s += 256) {
#pragma unroll
      for (int q = 0; q < 7; ++q) out[s * 7 + q] = 0.0f;
      out[7 * MAXNUM + s] = 0.0f;
      out[8 * MAXNUM + s] = -1.0f;
    }
  }
}

// ---------------- launcher ----------------
extern "C" void kernel_launch(void* const* d_in, const int* in_sizes, int n_in,
                              void* d_out, int out_size, void* d_ws, size_t ws_size,
                              hipStream_t stream) {
  (void)in_sizes; (void)n_in; (void)out_size; (void)ws_size;
  const float* cls    = (const float*)d_in[0];
  const float* bbp    = (const float*)d_in[1];
  const float* dirp   = (const float*)d_in[2];
  const float* priors = (const float*)d_in[3];
  char* ws = (char*)d_ws;

  uint32_t* hist   = (uint32_t*)(ws + HIST_OFF);
  uint32_t* misc   = (uint32_t*)(ws + MISC_OFF);
  float*    ms     = (float*)(ws + MS_OFF);
  uint32_t* slices = (uint32_t*)(ws + SLICE_OFF);
  uint64_t* cand   = (uint64_t*)(ws + CAND_OFF);
  uint32_t* sel    = (uint32_t*)(ws + SEL_OFF);
  float*    sc3    = (float*)(ws + SC3_OFF);
  uint32_t* dsc    = (uint32_t*)(ws + DSC_OFF);
  float*    bb7    = (float*)(ws + BB7_OFF);
  float*    box4   = (float*)(ws + BOX4_OFF);
  float*    areaA  = (float*)(ws + AREA_OFF);
  uint32_t* ord    = (uint32_t*)(ws + ORD_OFF);
  uint64_t* vwords = (uint64_t*)(ws + VW_OFF);
  uint64_t* pmask  = (uint64_t*)(ws + PMASK_OFF);
  uint64_t* keepw  = (uint64_t*)(ws + KEEPW_OFF);
  uint64_t* outk   = (uint64_t*)(ws + OUTK_OFF);

  hipMemsetAsync(misc, 0, 256, stream);
  k_score<<<NB_H, 256, 0, stream>>>(cls, ms, slices);
  k_reduce<<<NPAIR / 256, 256, 0, stream>>>(slices, hist);
  k_scanhist<<<1, 256, 0, stream>>>(hist, misc);
  k_compact<<<(NANCH + 4095) / 4096, 256, 0, stream>>>(ms, misc, cand);
  k_rank<<<CAND_CAP / (4 * 16), 256, 0, stream>>>(cand, misc, sel);
  k_gather<<<NPRE / 256, 256, 0, stream>>>(sel, cls, bbp, dirp, priors, sc3, dsc, bb7, box4, areaA);
  k_rankcls<<<dim3(NPRE / (4 * 16), 3), 256, 0, stream>>>(sc3, ord);
  k_vwords<<<3, 1024, 0, stream>>>(ord, sc3, vwords);
  k_mask<<<dim3(64, 64, 3), 64, 0, stream>>>(ord, box4, areaA, pmask);
  k_nms<<<3, 320, 0, stream>>>(pmask, vwords, keepw);
  k_collect<<<4, 1024, 0, stream>>>(keepw, ord, sc3, outk, misc);
  k_emit<<<2048 / (4 * 16), 256, 0, stream>>>(outk, misc, bb7, dsc, (float*)d_out);
}

// Round 11
// 291.497 us; speedup vs baseline: 8.0658x; 1.0130x over previous
//
#include <hip/hip_runtime.h>
#include <stdint.h>
#include <stddef.h>

// ---------------- problem constants ----------------
constexpr int kH = 496, kW = 432;
constexpr int HWSZ = kH * kW;          // 214272
constexpr int NANCH = HWSZ * 6;        // 1285632 anchors
constexpr int NPRE = 4096;             // nms_pre
constexpr int MAXNUM = 500;
constexpr int CAND_CAP = 8192;
constexpr float SCORE_THR_F = 0.1f;
constexpr float PIF  = 3.14159265358979323846f;  // rounds to f32 pi
constexpr float HPIF = 1.57079632679489661923f;  // rounds to f32 pi/2

// histogram: bin = float_bits >> 15; sigmoids < 2.0 -> bin < 32768.
constexpr int NBINS  = 32768;
constexpr int NPAIR  = NBINS / 2;      // packed u16 pairs in LDS = 64 KB
constexpr int NB_H   = 256;            // histogram blocks

// pad key: sorts AFTER every real key (real high32 = ~bits <= 0xFFFFFFFE).
constexpr uint64_t PADKEY = 0xFFFFFFFF00000000ull;

// ---------------- workspace layout (bytes) ----------------
constexpr size_t HIST_OFF  = 0;                                   // u32[32768] = 128 KB
constexpr size_t MISC_OFF  = 131072;                              // u32[64]: 0=cand_cnt 1=binB 2=above 8..10=Vc
constexpr size_t ZERO_BYTES= 131072 + 256;                        // hist + misc, one memset
constexpr size_t MS_OFF    = 131328;                              // f32[NANCH]
constexpr size_t CAND_OFF  = MS_OFF + 4ull * NANCH;               // u64[8192]
constexpr size_t SEL_OFF   = CAND_OFF + 8ull * CAND_CAP;          // u32[NPRE]
constexpr size_t SC3_OFF   = SEL_OFF + 4ull * NPRE;               // f32[NPRE*3]
constexpr size_t DSC_OFF   = SC3_OFF + 4ull * NPRE * 3;           // u32[NPRE]
constexpr size_t BB7_OFF   = DSC_OFF + 4ull * NPRE;               // f32[NPRE*7]
constexpr size_t BOX4_OFF  = BB7_OFF + 4ull * NPRE * 7;           // f32[NPRE*4]
constexpr size_t AREA_OFF  = BOX4_OFF + 4ull * NPRE * 4;          // f32[NPRE]
constexpr size_t ORD_OFF   = AREA_OFF + 4ull * NPRE;              // u32[3*NPRE]
constexpr size_t VW_OFF    = ORD_OFF + 4ull * 3 * NPRE;           // u64[3*64]
constexpr size_t PMASK_OFF = VW_OFF + 8ull * 3 * 64;              // u64[3*NPRE*64]  (6 MB)
constexpr size_t KEEPW_OFF = PMASK_OFF + 8ull * 3 * NPRE * 64;    // u64[3*64]
constexpr size_t OUTK_OFF  = KEEPW_OFF + 8ull * 3 * 64;           // u64[2048]

// ---------------- helpers ----------------
__device__ __forceinline__ float sigmoidf_(float x) { return 1.0f / (1.0f + expf(-x)); }

__device__ __forceinline__ uint64_t readlane64(uint64_t v, int lane) {
  uint32_t lo = (uint32_t)__builtin_amdgcn_readlane((int)(uint32_t)(v & 0xffffffffull), lane);
  uint32_t hi = (uint32_t)__builtin_amdgcn_readlane((int)(uint32_t)(v >> 32), lane);
  return (((uint64_t)hi) << 32) | (uint64_t)lo;
}

// ---------------- kernels ----------------

// 1) per-anchor max-of-3-sigmoids + per-block LDS histogram, flushed with
//    SCATTERED device atomics on nonzero bins only (~2-4K/block over 32768
//    addresses = all L2 slices; throughput-bound, no hot address). Replaces
//    the 16 MB slice write + 16 MB k_reduce read + one dispatch.
__global__ __launch_bounds__(256) void k_score(const float* __restrict__ cls,
                                               float* __restrict__ ms,
                                               uint32_t* __restrict__ hist) {
  __shared__ uint32_t h[NPAIR];  // 64 KB, packed u16 pairs
  const int t = threadIdx.x, blk = blockIdx.x;
  for (int i = t; i < NPAIR; i += 256) h[i] = 0;
  __syncthreads();
  for (int p = blk * 256 + t; p < HWSZ; p += NB_H * 256) {
#pragma unroll
    for (int k = 0; k < 6; ++k) {
      float s0 = sigmoidf_(cls[(k * 3 + 0) * HWSZ + p]);
      float s1 = sigmoidf_(cls[(k * 3 + 1) * HWSZ + p]);
      float s2 = sigmoidf_(cls[(k * 3 + 2) * HWSZ + p]);
      float m = fmaxf(s0, fmaxf(s1, s2));
      ms[p * 6 + k] = m;
      uint32_t bin = __float_as_uint(m) >> 15;  // < 32768 (scores < 2.0)
      atomicAdd(&h[bin >> 1], 1u << ((bin & 1) * 16));  // LDS atomic only
    }
  }
  __syncthreads();
  for (int i = t; i < NPAIR; i += 256) {
    uint32_t v = h[i];
    if (v) {
      uint32_t lo = v & 0xFFFFu, hi = v >> 16;
      if (lo) atomicAdd(&hist[2 * i],     lo);  // scattered device atomics
      if (hi) atomicAdd(&hist[2 * i + 1], hi);
    }
  }
}

// 2) find threshold bin B such that count(bin > B) < 4096 <= count(bin >= B)
__global__ void k_scanhist(const uint32_t* __restrict__ hist, uint32_t* __restrict__ misc) {
  __shared__ uint32_t part[256];
  __shared__ uint32_t suf[257];
  int t = threadIdx.x;
  int base = t * 128;
  uint32_t s = 0;
  for (int b = 0; b < 128; ++b) s += hist[base + b];
  part[t] = s;
  __syncthreads();
  if (t == 0) {
    uint32_t acc = 0;
    suf[256] = 0;
    for (int q = 255; q >= 0; --q) { suf[q] = acc + part[q]; acc = suf[q]; }
  }
  __syncthreads();
  uint32_t above = suf[t + 1];
  if (above < (uint32_t)NPRE && above + part[t] >= (uint32_t)NPRE) {
    uint32_t acc = above;
    for (int b = base + 127; b >= base; --b) {
      uint32_t h = hist[b];
      if (acc + h >= (uint32_t)NPRE) { misc[1] = (uint32_t)b; misc[2] = acc; break; }
      acc += h;
    }
  }
}

// 3) block-aggregated compaction: LDS staging, ONE global atomic per block.
__global__ __launch_bounds__(256) void k_compact(const float* __restrict__ ms,
                                                 uint32_t* __restrict__ misc,
                                                 uint64_t* __restrict__ cand) {
  constexpr int APB = 4096;
  __shared__ uint64_t lbuf[APB];       // 32 KB
  __shared__ uint32_t lcnt, lbase;
  const int t = threadIdx.x;
  const int base = blockIdx.x * APB;
  if (t == 0) lcnt = 0;
  __syncthreads();
  const uint32_t B = misc[1];
#pragma unroll
  for (int q = 0; q < 16; ++q) {
    int a = base + q * 256 + t;        // coalesced
    if (a < NANCH) {
      uint32_t bits = __float_as_uint(ms[a]);
      if ((bits >> 15) >= B) {
        uint32_t s = atomicAdd(&lcnt, 1u);  // LDS atomic, ~15/block
        lbuf[s] = (((uint64_t)(~bits)) << 32) | (uint32_t)a;
      }
    }
  }
  __syncthreads();
  const uint32_t n = lcnt;
  if (t == 0 && n > 0) lbase = atomicAdd(&misc[0], n);  // one RMW per block
  __syncthreads();
  if (n > 0) {
    const uint32_t b0 = lbase;
    for (uint32_t i = t; i < n; i += 256) {
      uint32_t slot = b0 + i;
      if (slot < (uint32_t)CAND_CAP) cand[slot] = lbuf[i];
    }
  }
}

// 4) EXACT rank-by-count (order-independent over cand[]; keys unique).
__global__ __launch_bounds__(256) void k_rank(const uint64_t* __restrict__ cand,
                                              const uint32_t* __restrict__ misc,
                                              uint32_t* __restrict__ sel) {
  const int tid = threadIdx.x, ln = tid & 63;
  const int wave = blockIdx.x * 4 + (tid >> 6);   // 0..511
  const int base = wave * 16;
  uint32_t cnt = misc[0];
  if (cnt > (uint32_t)CAND_CAP) cnt = CAND_CAP;
  uint64_t kr[16];
#pragma unroll
  for (int r = 0; r < 16; ++r) kr[r] = cand[base + r];
  uint32_t rnk[16];
#pragma unroll
  for (int r = 0; r < 16; ++r) rnk[r] = 0;
  const int nch = ((int)cnt + 63) >> 6;
  for (int ch = 0; ch < nch; ++ch) {
    uint64_t ck = cand[ch * 64 + ln];
    uint64_t vm = __ballot(ch * 64 + ln < (int)cnt);
#pragma unroll
    for (int r = 0; r < 16; ++r)
      rnk[r] += (uint32_t)__popcll(__ballot(ck < kr[r]) & vm);
  }
#pragma unroll
  for (int r = 0; r < 16; ++r) {
    int row = base + r;
    if (ln == 0 && row < (int)cnt && rnk[r] < (uint32_t)NPRE)
      sel[rnk[r]] = (uint32_t)kr[r];
  }
}

// 5) gather per-anchor data + decode boxes
__global__ void k_gather(const uint32_t* __restrict__ sel, const float* __restrict__ cls,
                         const float* __restrict__ bbp, const float* __restrict__ dirp,
                         const float* __restrict__ priors, float* __restrict__ sc3,
                         uint32_t* __restrict__ dsc, float* __restrict__ bb7,
                         float* __restrict__ box4, float* __restrict__ areaA) {
  int i = blockIdx.x * 256 + threadIdx.x;
  if (i >= NPRE) return;
  uint32_t a = sel[i];
  uint32_t p = a / 6u;
  uint32_t k = a - p * 6u;
#pragma unroll
  for (int c = 0; c < 3; ++c) sc3[i * 3 + c] = sigmoidf_(cls[(k * 3 + c) * HWSZ + p]);
  float d0 = dirp[(k * 2 + 0) * HWSZ + p];
  float d1 = dirp[(k * 2 + 1) * HWSZ + p];
  dsc[i] = (d1 > d0) ? 1u : 0u;
  float dt[7], pr[7];
#pragma unroll
  for (int q = 0; q < 7; ++q) dt[q] = bbp[(k * 7 + q) * HWSZ + p];
#pragma unroll
  for (int q = 0; q < 7; ++q) pr[q] = priors[(size_t)a * 7 + q];
  float za = pr[2] + pr[5] * 0.5f;
  float diag = sqrtf(pr[4] * pr[4] + pr[3] * pr[3]);
  float xg = dt[0] * diag + pr[0];
  float yg = dt[1] * diag + pr[1];
  float zg = dt[2] * pr[5] + za;
  float wg = expf(dt[3]) * pr[3];
  float lg = expf(dt[4]) * pr[4];
  float hg = expf(dt[5]) * pr[5];
  float rg = dt[6] + pr[6];
  zg = zg - hg * 0.5f;
  bb7[i * 7 + 0] = xg; bb7[i * 7 + 1] = yg; bb7[i * 7 + 2] = zg;
  bb7[i * 7 + 3] = wg; bb7[i * 7 + 4] = lg; bb7[i * 7 + 5] = hg; bb7[i * 7 + 6] = rg;
  float x1 = xg - wg * 0.5f, y1 = yg - lg * 0.5f;
  float x2 = xg + wg * 0.5f, y2 = yg + lg * 0.5f;
  box4[i * 4 + 0] = x1; box4[i * 4 + 1] = y1; box4[i * 4 + 2] = x2; box4[i * 4 + 3] = y2;
  areaA[i] = (x2 - x1 + 1.0f) * (y2 - y1 + 1.0f);
}

// 6) per-class EXACT rank-by-count on key (~score_bits<<32 | pos).
__global__ __launch_bounds__(256) void k_rankcls(const float* __restrict__ sc3,
                                                 uint32_t* __restrict__ ord) {
  const int tid = threadIdx.x, ln = tid & 63;
  const int c = blockIdx.y;
  const int wave = blockIdx.x * 4 + (tid >> 6);  // 0..255
  const int base = wave * 16;
  uint64_t kr[16];
#pragma unroll
  for (int r = 0; r < 16; ++r) {
    int j = base + r;
    kr[r] = (((uint64_t)(~__float_as_uint(sc3[j * 3 + c]))) << 32) | (uint32_t)j;
  }
  uint32_t rnk[16];
#pragma unroll
  for (int r = 0; r < 16; ++r) rnk[r] = 0;
  for (int ch = 0; ch < NPRE / 64; ++ch) {
    int j = ch * 64 + ln;
    uint64_t ck = (((uint64_t)(~__float_as_uint(sc3[j * 3 + c]))) << 32) | (uint32_t)j;
#pragma unroll
    for (int r = 0; r < 16; ++r)
      rnk[r] += (uint32_t)__popcll(__ballot(ck < kr[r]));
  }
#pragma unroll
  for (int r = 0; r < 16; ++r)
    if (ln == 0) ord[c * NPRE + rnk[r]] = (uint32_t)(base + r);
}

// 6b) valid bitset in sorted space
__global__ __launch_bounds__(1024) void k_vwords(const uint32_t* __restrict__ ord,
                                                 const float* __restrict__ sc3,
                                                 uint64_t* __restrict__ vwords) {
  int c = blockIdx.x, t = threadIdx.x, ln = t & 63;
  for (int k = 0; k < 4; ++k) {
    int i = k * 1024 + t;
    uint32_t pos = ord[c * NPRE + i];
    uint64_t m = __ballot(sc3[pos * 3 + c] > SCORE_THR_F);
    if (ln == 0) vwords[c * 64 + (i >> 6)] = m;
  }
}

// 7) suppression bitmask in per-class sorted order; UPPER TRIANGLE ONLY.
__global__ void k_mask(const uint32_t* __restrict__ ord, const float* __restrict__ box4,
                       const float* __restrict__ areaA, uint64_t* __restrict__ pmask) {
  int c = blockIdx.z, it = blockIdx.y, jt = blockIdx.x, t = threadIdx.x;
  if (jt < it) return;
  __shared__ float jx1[64], jy1[64], jx2[64], jy2[64], jar[64];
  int j = ord[c * NPRE + jt * 64 + t];
  jx1[t] = box4[j * 4 + 0]; jy1[t] = box4[j * 4 + 1];
  jx2[t] = box4[j * 4 + 2]; jy2[t] = box4[j * 4 + 3];
  jar[t] = areaA[j];
  __syncthreads();
  int I = it * 64 + t;
  int i = ord[c * NPRE + I];
  float x1 = box4[i * 4 + 0], y1 = box4[i * 4 + 1];
  float x2 = box4[i * 4 + 2], y2 = box4[i * 4 + 3];
  float ar = areaA[i];
  uint64_t bits = 0;
  for (int b = 0; b < 64; ++b) {
    float xx1 = fmaxf(x1, jx1[b]), yy1 = fmaxf(y1, jy1[b]);
    float xx2 = fminf(x2, jx2[b]), yy2 = fminf(y2, jy2[b]);
    float iw = fmaxf(0.0f, xx2 - xx1 + 1.0f);
    float ih = fmaxf(0.0f, yy2 - yy1 + 1.0f);
    float inter = iw * ih;
    float iou = inter / (ar + jar[b] - inter);
    bits |= ((uint64_t)(iou > 0.5f)) << b;
  }
  pmask[((size_t)(c * NPRE + I)) * 64 + (size_t)jt] = bits;
}

// 8) tiled serial greedy NMS cascade with EARLY EXIT at 500 keeps.
__global__ __launch_bounds__(320) void k_nms(const uint64_t* __restrict__ pmask,
                                             const uint64_t* __restrict__ vwords,
                                             uint64_t* __restrict__ keepw) {
  __shared__ uint64_t tile[2][64 * 64];  // 2 x 32 KB
  __shared__ int s_stop[2];
  const int c = blockIdx.x;
  const int tid = threadIdx.x;
  const int wv = tid >> 6;
  const int ln = tid & 63;
  const uint64_t* pm = pmask + (size_t)c * NPRE * 64;

  if (tid == 0) { s_stop[0] = 0; s_stop[1] = 0; }
  if (wv > 0) {
    int l = tid - 64;
    const ulonglong2* src2 = (const ulonglong2*)pm;
    ulonglong2* dst2 = (ulonglong2*)tile[0];
#pragma unroll
    for (int q = 0; q < 8; ++q) dst2[q * 256 + l] = src2[q * 256 + l];
  }
  __syncthreads();

  uint64_t avail = 0, keepbits = 0;
  int cnt = 0;
  if (wv == 0) avail = vwords[c * 64 + ln];

  for (int T = 0; T < 64; ++T) {
    const int cb = T & 1;
    if (wv > 0) {
      if (T + 1 < 64) {
        int l = tid - 64;
        const ulonglong2* src2 = (const ulonglong2*)(pm + (size_t)(T + 1) * 64 * 64);
        ulonglong2* dst2 = (ulonglong2*)tile[cb ^ 1];
#pragma unroll
        for (int q = 0; q < 8; ++q) dst2[q * 256 + l] = src2[q * 256 + l];
      }
    } else {
      const uint64_t* tp = tile[cb];
      uint64_t awT = readlane64(avail, T);
      uint64_t pf[8];
#pragma unroll
      for (int u = 0; u < 8; ++u) pf[u] = tp[u * 64 + ln];
      uint64_t kwT = 0;
#pragma unroll
      for (int r = 0; r < 64; ++r) {
        uint64_t cur = pf[r & 7];
        if (r + 8 < 64) pf[r & 7] = tp[(r + 8) * 64 + ln];
        bool kp = ((awT >> r) & 1ull) != 0ull;
        if (kp) {
          avail &= ~cur;
          awT &= ~readlane64(cur, T);
          kwT |= (1ull << r);
        }
      }
      if (ln == T) keepbits = kwT;
      cnt += (int)__popcll(kwT);
      if (ln == 0 && cnt >= MAXNUM) s_stop[cb] = 1;
    }
    __syncthreads();
    if (s_stop[cb]) break;
  }
  if (wv == 0) keepw[c * 64 + ln] = keepbits;
}

// 9) per-class stable-compact first <=500 kept keys into outk[2048] (padded).
__global__ __launch_bounds__(1024) void k_collect(const uint64_t* __restrict__ keepw,
                                                  const uint32_t* __restrict__ ord,
                                                  const float* __restrict__ sc3,
                                                  uint64_t* __restrict__ outk,
                                                  uint32_t* __restrict__ misc) {
  const int c = blockIdx.x, t = threadIdx.x, w = t >> 6, ln = t & 63;
  if (c == 3) {  // tail pad
    int i = 3 * MAXNUM + t;
    if (i < 2048) outk[i] = PADKEY;
    return;
  }
  __shared__ uint32_t wsum[16];
  uint32_t bits4 = 0;
#pragma unroll
  for (int q = 0; q < 4; ++q) {
    int i = t * 4 + q;
    uint32_t b = (uint32_t)((keepw[c * 64 + (i >> 6)] >> (i & 63)) & 1ull);
    bits4 |= b << q;
  }
  uint32_t cnt = __popc(bits4);
  uint32_t incl = cnt;
#pragma unroll
  for (int d = 1; d < 64; d <<= 1) { uint32_t u = __shfl_up(incl, d, 64); if (ln >= d) incl += u; }
  if (ln == 63) wsum[w] = incl;
  __syncthreads();
  uint32_t wb = 0, total = 0;
#pragma unroll
  for (int i = 0; i < 16; ++i) { uint32_t v = wsum[i]; total += v; if (i < w) wb += v; }
  uint32_t r = wb + incl - cnt;  // exclusive prefix
#pragma unroll
  for (int q = 0; q < 4; ++q) {
    if ((bits4 >> q) & 1u) {
      if (r < (uint32_t)MAXNUM) {
        uint32_t pos = ord[c * NPRE + t * 4 + q];
        uint32_t sb = __float_as_uint(sc3[pos * 3 + c]);
        outk[c * MAXNUM + r] = (((uint64_t)(~sb)) << 32) | (uint32_t)(c * NPRE + pos);
      }
      ++r;
    }
  }
  uint32_t Vc = total < (uint32_t)MAXNUM ? total : (uint32_t)MAXNUM;
  if (t == 0) misc[8 + c] = Vc;
  for (uint32_t s = Vc + t; s < (uint32_t)MAXNUM; s += 1024)
    outk[c * MAXNUM + s] = PADKEY;
}

// 10) rank the full 2048-key union (32 blocks x 4 waves x 16 rows = 2048);
//     emit rank<500; zero-fill [V,500).
__global__ __launch_bounds__(256) void k_emit(const uint64_t* __restrict__ outk,
                                              const uint32_t* __restrict__ misc,
                                              const float* __restrict__ bb7,
                                              const uint32_t* __restrict__ dsc,
                                              float* __restrict__ out) {
  const int tid = threadIdx.x, ln = tid & 63;
  const int wave = blockIdx.x * 4 + (tid >> 6);  // 0..127
  const int base = wave * 16;                    // rows 0..2047
  uint64_t kr[16];
#pragma unroll
  for (int r = 0; r < 16; ++r) kr[r] = outk[base + r];
  uint32_t rnk[16];
#pragma unroll
  for (int r = 0; r < 16; ++r) rnk[r] = 0;
  for (int ch = 0; ch < 2048 / 64; ++ch) {
    uint64_t ck = outk[ch * 64 + ln];
#pragma unroll
    for (int r = 0; r < 16; ++r)
      rnk[r] += (uint32_t)__popcll(__ballot(ck < kr[r]));
  }
  if (ln == 0) {
#pragma unroll
    for (int r = 0; r < 16; ++r) {
      uint64_t key = kr[r];
      uint32_t rk = rnk[r];
      if (key != PADKEY && rk < (uint32_t)MAXNUM) {
        uint32_t flat = (uint32_t)key;
        float score = __uint_as_float(~((uint32_t)(key >> 32)));
        int cc = (int)(flat >> 12);
        int pos = (int)(flat & 4095u);
        const float* b = bb7 + (size_t)pos * 7;
        float rr0 = b[6];
        float dir_rot = rr0 + HPIF - floorf(rr0 + 0.5f) * PIF;
        float rr = dir_rot - HPIF + PIF * (float)dsc[pos];
#pragma unroll
        for (int q = 0; q < 6; ++q) out[rk * 7 + q] = b[q];
        out[rk * 7 + 6] = rr;
        out[7 * MAXNUM + rk] = score;
        out[8 * MAXNUM + rk] = (float)cc;
      }
    }
  }
  if (blockIdx.x == 0) {
    uint32_t V = misc[8] + misc[9] + misc[10];
    for (uint32_t s = V + tid; s < (uint32_t)MAXNUM; s += 256) {
#pragma unroll
      for (int q = 0; q < 7; ++q) out[s * 7 + q] = 0.0f;
      out[7 * MAXNUM + s] = 0.0f;
      out[8 * MAXNUM + s] = -1.0f;
    }
  }
}

// ---------------- launcher ----------------
extern "C" void kernel_launch(void* const* d_in, const int* in_sizes, int n_in,
                              void* d_out, int out_size, void* d_ws, size_t ws_size,
                              hipStream_t stream) {
  (void)in_sizes; (void)n_in; (void)out_size; (void)ws_size;
  const float* cls    = (const float*)d_in[0];
  const float* bbp    = (const float*)d_in[1];
  const float* dirp   = (const float*)d_in[2];
  const float* priors = (const float*)d_in[3];
  char* ws = (char*)d_ws;

  uint32_t* hist   = (uint32_t*)(ws + HIST_OFF);
  uint32_t* misc   = (uint32_t*)(ws + MISC_OFF);
  float*    ms     = (float*)(ws + MS_OFF);
  uint64_t* cand   = (uint64_t*)(ws + CAND_OFF);
  uint32_t* sel    = (uint32_t*)(ws + SEL_OFF);
  float*    sc3    = (float*)(ws + SC3_OFF);
  uint32_t* dsc    = (uint32_t*)(ws + DSC_OFF);
  float*    bb7    = (float*)(ws + BB7_OFF);
  float*    box4   = (float*)(ws + BOX4_OFF);
  float*    areaA  = (float*)(ws + AREA_OFF);
  uint32_t* ord    = (uint32_t*)(ws + ORD_OFF);
  uint64_t* vwords = (uint64_t*)(ws + VW_OFF);
  uint64_t* pmask  = (uint64_t*)(ws + PMASK_OFF);
  uint64_t* keepw  = (uint64_t*)(ws + KEEPW_OFF);
  uint64_t* outk   = (uint64_t*)(ws + OUTK_OFF);

  hipMemsetAsync(ws, 0, ZERO_BYTES, stream);  // hist + misc in one call
  k_score<<<NB_H, 256, 0, stream>>>(cls, ms, hist);
  k_scanhist<<<1, 256, 0, stream>>>(hist, misc);
  k_compact<<<(NANCH + 4095) / 4096, 256, 0, stream>>>(ms, misc, cand);
  k_rank<<<CAND_CAP / (4 * 16), 256, 0, stream>>>(cand, misc, sel);
  k_gather<<<NPRE / 256, 256, 0, stream>>>(sel, cls, bbp, dirp, priors, sc3, dsc, bb7, box4, areaA);
  k_rankcls<<<dim3(NPRE / (4 * 16), 3), 256, 0, stream>>>(sc3, ord);
  k_vwords<<<3, 1024, 0, stream>>>(ord, sc3, vwords);
  k_mask<<<dim3(64, 64, 3), 64, 0, stream>>>(ord, box4, areaA, pmask);
  k_nms<<<3, 320, 0, stream>>>(pmask, vwords, keepw);
  k_collect<<<4, 1024, 0, stream>>>(keepw, ord, sc3, outk, misc);
  k_emit<<<2048 / (4 * 16), 256, 0, stream>>>(outk, misc, bb7, dsc, (float*)d_out);
}